// Round 1
// baseline (13029.155 us; speedup 1.0000x reference)
//
#include <hip/hip_runtime.h>
#include <cstdint>
#include <cstddef>

// GRAN mixture-Bernoulli forward, fp32 reference-faithful implementation.
// Sizes (fixed by harness): N=50000, M=250000, E=200000, MAXN=512, H=128,
// EF=128, ATT=128, K=20, L=3, S=512, B*C=16.
//
// Key rewrite: diff @ W1[:, :128]^T == proj[src]-proj[dst], proj = state @ W1a^T.
// Edge kernels then only need W1b (ef part) + W2 in LDS (64KB each, phased).

#define H128 128

// ---------------------------------------------------------------------------
// Generic row-per-thread GEMM: out[r][c] = act( sum_k Arow[k]*W[c][k] + bias[c] )
// Arow = A[r] (stride K) or gathered diff A[i0[r]] - A[i1[r]] (GATHER).
// W staged in LDS in K-sections of 128; reads are wave-uniform -> broadcast.
// ---------------------------------------------------------------------------
template<int OUT, int ACT, bool GATHER>
__global__ __launch_bounds__(256)
void gemm_rt(const float* __restrict__ A, const int* __restrict__ idx2,
             const float* __restrict__ W, int wstride,
             const float* __restrict__ bias,
             float* __restrict__ out, int ostride,
             int nrows, int K)
{
    __shared__ float4 Ws[OUT * 32];   // OUT x 128 section (float4 over k)
    const int tid = threadIdx.x;
    const int r = blockIdx.x * 256 + tid;
    const bool ok = r < nrows;

    const float* Arow0 = A;
    const float* Arow1 = A;
    if (ok) {
        if (GATHER) {
            Arow0 = A + (size_t)idx2[2 * r] * K;
            Arow1 = A + (size_t)idx2[2 * r + 1] * K;
        } else {
            Arow0 = A + (size_t)r * K;
        }
    }

    float acc[OUT];
#pragma unroll
    for (int c = 0; c < OUT; ++c) acc[c] = 0.f;

    for (int ks = 0; ks < K; ks += 128) {
        __syncthreads();
        for (int i = tid; i < OUT * 32; i += 256) {
            int c = i >> 5, q = i & 31;
            Ws[i] = *(const float4*)&W[(size_t)c * wstride + ks + q * 4];
        }
        __syncthreads();
        if (ok) {
            for (int q = 0; q < 32; ++q) {
                float a0, a1, a2, a3;
                if (GATHER) {
                    float4 x = *(const float4*)&Arow0[ks + q * 4];
                    float4 y = *(const float4*)&Arow1[ks + q * 4];
                    a0 = x.x - y.x; a1 = x.y - y.y; a2 = x.z - y.z; a3 = x.w - y.w;
                } else {
                    float4 x = *(const float4*)&Arow0[ks + q * 4];
                    a0 = x.x; a1 = x.y; a2 = x.z; a3 = x.w;
                }
#pragma unroll
                for (int c = 0; c < OUT; ++c) {
                    float4 w = Ws[c * 32 + q];
                    acc[c] = fmaf(a0, w.x, fmaf(a1, w.y, fmaf(a2, w.z, fmaf(a3, w.w, acc[c]))));
                }
            }
        }
    }

    if (ok) {
#pragma unroll
        for (int c = 0; c < OUT; ++c) {
            float v = acc[c] + (bias ? bias[c] : 0.f);
            if (ACT == 1) v = fmaxf(v, 0.f);
            acc[c] = v;
        }
#pragma unroll
        for (int c = 0; c < OUT; c += 4) {
            *(float4*)&out[(size_t)r * ostride + c] =
                make_float4(acc[c], acc[c + 1], acc[c + 2], acc[c + 3]);
        }
    }
}

// ---------------------------------------------------------------------------
// Edge MLP (msg pass): hm = relu(projdiff + ef@W1b^T + b1); msg = hm@W2^T + b2
// One edge per thread; acc[128] in registers; weights phased through 64KB LDS.
// ---------------------------------------------------------------------------
__global__ __launch_bounds__(256)
void edge_msg_kernel(const float* __restrict__ proj,
                     const int* __restrict__ edge,
                     const float* __restrict__ ef,
                     const float* __restrict__ W1b,  // rows stride 256 (cols 128..255 of W1)
                     const float* __restrict__ b1,
                     const float* __restrict__ W2,   // 128x128
                     const float* __restrict__ b2,
                     float* __restrict__ msgbuf, int M)
{
    __shared__ float4 Ws[128 * 32]; // 64KB
    const int tid = threadIdx.x;
    const int e = blockIdx.x * 256 + tid;
    const bool ok = e < M;
    int vs = 0, vd = 0;
    if (ok) { vs = edge[2 * e]; vd = edge[2 * e + 1]; }

    for (int i = tid; i < 128 * 32; i += 256) {
        int c = i >> 5, q = i & 31;
        Ws[i] = *(const float4*)&W1b[(size_t)c * 256 + q * 4];
    }
    __syncthreads();

    float acc[128];
    if (ok) {
        const float* ps = proj + (size_t)vs * H128;
        const float* pd = proj + (size_t)vd * H128;
#pragma unroll
        for (int c = 0; c < 128; c += 4) {
            float4 x = *(const float4*)&ps[c];
            float4 y = *(const float4*)&pd[c];
            float4 b = *(const float4*)&b1[c];
            acc[c]     = x.x - y.x + b.x;
            acc[c + 1] = x.y - y.y + b.y;
            acc[c + 2] = x.z - y.z + b.z;
            acc[c + 3] = x.w - y.w + b.w;
        }
        const float* efr = ef + (size_t)e * H128;
        for (int q = 0; q < 32; ++q) {
            float4 x = *(const float4*)&efr[q * 4];
#pragma unroll
            for (int c = 0; c < 128; ++c) {
                float4 w = Ws[c * 32 + q];
                acc[c] = fmaf(x.x, w.x, fmaf(x.y, w.y, fmaf(x.z, w.z, fmaf(x.w, w.w, acc[c]))));
            }
        }
#pragma unroll
        for (int c = 0; c < 128; ++c) acc[c] = fmaxf(acc[c], 0.f);
    }
    __syncthreads();
    for (int i = tid; i < 128 * 32; i += 256) {
        int c = i >> 5, q = i & 31;
        Ws[i] = *(const float4*)&W2[(size_t)c * 128 + q * 4];
    }
    __syncthreads();
    if (ok) {
        float* outr = msgbuf + (size_t)e * H128;
        for (int ch = 0; ch < 16; ++ch) {
            float mm[8];
#pragma unroll
            for (int j = 0; j < 8; ++j) mm[j] = b2[ch * 8 + j];
#pragma unroll
            for (int q = 0; q < 32; ++q) {
#pragma unroll
                for (int j = 0; j < 8; ++j) {
                    float4 w = Ws[(ch * 8 + j) * 32 + q];
                    mm[j] = fmaf(acc[4 * q], w.x, fmaf(acc[4 * q + 1], w.y,
                            fmaf(acc[4 * q + 2], w.z, fmaf(acc[4 * q + 3], w.w, mm[j]))));
                }
            }
            *(float4*)&outr[ch * 8]     = make_float4(mm[0], mm[1], mm[2], mm[3]);
            *(float4*)&outr[ch * 8 + 4] = make_float4(mm[4], mm[5], mm[6], mm[7]);
        }
    }
}

// ---------------------------------------------------------------------------
// Edge MLP (att pass): att = sigmoid(hm@W2^T + b2); agg[dst] += att * msg
// ---------------------------------------------------------------------------
__global__ __launch_bounds__(256)
void edge_att_kernel(const float* __restrict__ proj,
                     const int* __restrict__ edge,
                     const float* __restrict__ ef,
                     const float* __restrict__ W1b,
                     const float* __restrict__ b1,
                     const float* __restrict__ W2,
                     const float* __restrict__ b2,
                     const float* __restrict__ msgbuf,
                     float* __restrict__ agg, int M)
{
    __shared__ float4 Ws[128 * 32];
    const int tid = threadIdx.x;
    const int e = blockIdx.x * 256 + tid;
    const bool ok = e < M;
    int vs = 0, vd = 0;
    if (ok) { vs = edge[2 * e]; vd = edge[2 * e + 1]; }

    for (int i = tid; i < 128 * 32; i += 256) {
        int c = i >> 5, q = i & 31;
        Ws[i] = *(const float4*)&W1b[(size_t)c * 256 + q * 4];
    }
    __syncthreads();

    float acc[128];
    if (ok) {
        const float* ps = proj + (size_t)vs * H128;
        const float* pd = proj + (size_t)vd * H128;
#pragma unroll
        for (int c = 0; c < 128; c += 4) {
            float4 x = *(const float4*)&ps[c];
            float4 y = *(const float4*)&pd[c];
            float4 b = *(const float4*)&b1[c];
            acc[c]     = x.x - y.x + b.x;
            acc[c + 1] = x.y - y.y + b.y;
            acc[c + 2] = x.z - y.z + b.z;
            acc[c + 3] = x.w - y.w + b.w;
        }
        const float* efr = ef + (size_t)e * H128;
        for (int q = 0; q < 32; ++q) {
            float4 x = *(const float4*)&efr[q * 4];
#pragma unroll
            for (int c = 0; c < 128; ++c) {
                float4 w = Ws[c * 32 + q];
                acc[c] = fmaf(x.x, w.x, fmaf(x.y, w.y, fmaf(x.z, w.z, fmaf(x.w, w.w, acc[c]))));
            }
        }
#pragma unroll
        for (int c = 0; c < 128; ++c) acc[c] = fmaxf(acc[c], 0.f);
    }
    __syncthreads();
    for (int i = tid; i < 128 * 32; i += 256) {
        int c = i >> 5, q = i & 31;
        Ws[i] = *(const float4*)&W2[(size_t)c * 128 + q * 4];
    }
    __syncthreads();
    if (ok) {
        const float* msgr = msgbuf + (size_t)e * H128;
        float* aggr = agg + (size_t)vd * H128;
        for (int ch = 0; ch < 16; ++ch) {
            float mm[8];
#pragma unroll
            for (int j = 0; j < 8; ++j) mm[j] = b2[ch * 8 + j];
#pragma unroll
            for (int q = 0; q < 32; ++q) {
#pragma unroll
                for (int j = 0; j < 8; ++j) {
                    float4 w = Ws[(ch * 8 + j) * 32 + q];
                    mm[j] = fmaf(acc[4 * q], w.x, fmaf(acc[4 * q + 1], w.y,
                            fmaf(acc[4 * q + 2], w.z, fmaf(acc[4 * q + 3], w.w, mm[j]))));
                }
            }
            float mg[8];
            *(float4*)&mg[0] = *(const float4*)&msgr[ch * 8];
            *(float4*)&mg[4] = *(const float4*)&msgr[ch * 8 + 4];
#pragma unroll
            for (int j = 0; j < 8; ++j) {
                float att = 1.f / (1.f + expf(-mm[j]));
                atomicAdd(&aggr[ch * 8 + j], att * mg[j]);
            }
        }
    }
}

// ---------------------------------------------------------------------------
// GRU: gh = sIn@Whh^T + bhh (computed here, c-chunks of 16 over 8 phases),
// gi precomputed; elementwise gate update. outState != sIn (no aliasing).
// ---------------------------------------------------------------------------
__global__ __launch_bounds__(256)
void gru_kernel(const float* __restrict__ sIn,
                const float* __restrict__ gi,    // N x 384
                const float* __restrict__ Whh,   // 384 x 128
                const float* __restrict__ bhh,
                float* __restrict__ outState, int N)
{
    __shared__ float4 Ws[48 * 32]; // rows {c0..c0+15, 128+c0.., 256+c0..}, 24KB
    const int tid = threadIdx.x;
    const int n = blockIdx.x * 256 + tid;
    const bool ok = n < N;
    const float* ar  = sIn + (ok ? (size_t)n * H128 : 0);
    const float* gir = gi  + (ok ? (size_t)n * 384  : 0);

    for (int c0 = 0; c0 < 128; c0 += 16) {
        __syncthreads();
        for (int i = tid; i < 48 * 32; i += 256) {
            int lr = i >> 5, q = i & 31;
            int gr = (lr >> 4) * 128 + c0 + (lr & 15);
            Ws[i] = *(const float4*)&Whh[(size_t)gr * 128 + q * 4];
        }
        __syncthreads();
        if (ok) {
            float hacc[48];
#pragma unroll
            for (int j = 0; j < 48; ++j) hacc[j] = bhh[(j >> 4) * 128 + c0 + (j & 15)];
            for (int q = 0; q < 32; ++q) {
                float4 x = *(const float4*)&ar[q * 4];
#pragma unroll
                for (int j = 0; j < 48; ++j) {
                    float4 w = Ws[j * 32 + q];
                    hacc[j] = fmaf(x.x, w.x, fmaf(x.y, w.y, fmaf(x.z, w.z, fmaf(x.w, w.w, hacc[j]))));
                }
            }
#pragma unroll
            for (int j4 = 0; j4 < 4; ++j4) {
                float irv[4], izv[4], inv[4], svv[4], ov[4];
                *(float4*)irv = *(const float4*)&gir[c0 + j4 * 4];
                *(float4*)izv = *(const float4*)&gir[128 + c0 + j4 * 4];
                *(float4*)inv = *(const float4*)&gir[256 + c0 + j4 * 4];
                *(float4*)svv = *(const float4*)&ar[c0 + j4 * 4];
#pragma unroll
                for (int jj = 0; jj < 4; ++jj) {
                    int j = j4 * 4 + jj;
                    float rr = 1.f / (1.f + expf(-(irv[jj] + hacc[j])));
                    float zz = 1.f / (1.f + expf(-(izv[jj] + hacc[16 + j])));
                    float nn = tanhf(inv[jj] + rr * hacc[32 + j]);
                    ov[jj] = (1.f - zz) * nn + zz * svv[jj];
                }
                *(float4*)&outState[(size_t)n * H128 + c0 + j4 * 4] = *(float4*)ov;
            }
        }
    }
}

// ---------------------------------------------------------------------------
__global__ void act_copy_kernel(const float4* __restrict__ in, float4* __restrict__ out,
                                int n4, int dorelu)
{
    int i = blockIdx.x * blockDim.x + threadIdx.x;
    if (i < n4) {
        float4 v = in[i];
        if (dorelu) {
            v.x = fmaxf(v.x, 0.f); v.y = fmaxf(v.y, 0.f);
            v.z = fmaxf(v.z, 0.f); v.w = fmaxf(v.w, 0.f);
        }
        out[i] = v;
    }
}

// ---------------------------------------------------------------------------
// Loss accumulation: adj_loss = softplus(-lt) + (1-y)*lt; segment sums over
// subgraph_idx (sorted -> block spans <=2 subgraphs; LDS-reduce then atomics).
// ---------------------------------------------------------------------------
__global__ __launch_bounds__(256)
void loss_kernel(const float* __restrict__ lt, const float* __restrict__ la,
                 const float* __restrict__ label, const int* __restrict__ sg,
                 float* __restrict__ radj, float* __restrict__ rla,
                 float* __restrict__ cnt, int E, int S)
{
    __shared__ float sadj[4][20];
    __shared__ float sla[4][20];
    __shared__ float scnt[4];
    __shared__ int sbase;
    const int tid = threadIdx.x;
    const int e = blockIdx.x * 256 + tid;
    if (tid == 0) sbase = sg[blockIdx.x * 256];
    if (tid < 80) { sadj[tid / 20][tid % 20] = 0.f; sla[tid / 20][tid % 20] = 0.f; }
    if (tid < 4) scnt[tid] = 0.f;
    __syncthreads();
    if (e < E) {
        int s = sg[e];
        int ls = s - sbase;
        bool local = (ls >= 0 && ls < 4);
        float y = label[e];
        if (local) atomicAdd(&scnt[ls], 1.f); else atomicAdd(&cnt[s], 1.f);
#pragma unroll
        for (int k = 0; k < 20; ++k) {
            float t = lt[(size_t)e * 20 + k];
            float sp = fmaxf(-t, 0.f) + log1pf(expf(-fabsf(t)));  // softplus(-t)
            float adj = sp + (1.f - y) * t;
            float lav = la[(size_t)e * 20 + k];
            if (local) { atomicAdd(&sadj[ls][k], adj); atomicAdd(&sla[ls][k], lav); }
            else       { atomicAdd(&radj[s * 20 + k], adj); atomicAdd(&rla[s * 20 + k], lav); }
        }
    }
    __syncthreads();
    if (tid < 80) {
        int ls = tid / 20, k = tid % 20;
        int s = sbase + ls;
        if (s < S) {
            float v = sadj[ls][k], v2 = sla[ls][k];
            if (v  != 0.f) atomicAdd(&radj[s * 20 + k], v);
            if (v2 != 0.f) atomicAdd(&rla[s * 20 + k], v2);
        }
    }
    if (tid < 4) {
        int s = sbase + tid;
        if (s < S && scnt[tid] != 0.f) atomicAdd(&cnt[s], scnt[tid]);
    }
}

// ---------------------------------------------------------------------------
// Final reduction: log_softmax(rla/cnt), logsumexp(-radj + lsm), bc sums, mean.
// One block of S=512 threads.
// ---------------------------------------------------------------------------
__global__ void final_kernel(const float* __restrict__ radj, const float* __restrict__ rla,
                             const float* __restrict__ cnt, const int* __restrict__ bc_idx,
                             float* __restrict__ out)
{
    __shared__ float bcl[16], bcc[16];
    const int s = threadIdx.x;
    if (s < 16) { bcl[s] = 0.f; bcc[s] = 0.f; }
    __syncthreads();
    float c = cnt[s];
    float x[20];
    float mx = -1e30f;
#pragma unroll
    for (int k = 0; k < 20; ++k) { x[k] = rla[s * 20 + k] / c; mx = fmaxf(mx, x[k]); }
    float se = 0.f;
#pragma unroll
    for (int k = 0; k < 20; ++k) se += expf(x[k] - mx);
    float lse = mx + logf(se);
    float t[20];
    float m2 = -1e30f;
#pragma unroll
    for (int k = 0; k < 20; ++k) { t[k] = -radj[s * 20 + k] + x[k] - lse; m2 = fmaxf(m2, t[k]); }
    float s2 = 0.f;
#pragma unroll
    for (int k = 0; k < 20; ++k) s2 += expf(t[k] - m2);
    float lp = m2 + logf(s2);
    atomicAdd(&bcl[bc_idx[s]], lp);
    atomicAdd(&bcc[bc_idx[s]], c);
    __syncthreads();
    if (s == 0) {
        float a = 0.f;
        for (int b = 0; b < 16; ++b) a += bcl[b] / bcc[b];
        out[0] = -a / 16.f;
    }
}

// ---------------------------------------------------------------------------
extern "C" void kernel_launch(void* const* d_in, const int* in_sizes, int n_in,
                              void* d_out, int out_size, void* d_ws, size_t ws_size,
                              hipStream_t stream)
{
    const float* node_feat = (const float*)d_in[0];
    const int*   edge      = (const int*)  d_in[1];
    const float* edge_feat = (const float*)d_in[2];
    const int*   gnn_idx   = (const int*)  d_in[3];
    const float* label     = (const float*)d_in[4];
    const int*   sg_idx    = (const int*)  d_in[5];
    const int*   bc_idx    = (const int*)  d_in[6];
    const float* dec_W  = (const float*)d_in[7];
    const float* dec_b  = (const float*)d_in[8];
    const float* msg_W1 = (const float*)d_in[9];
    const float* msg_b1 = (const float*)d_in[10];
    const float* msg_W2 = (const float*)d_in[11];
    const float* msg_b2 = (const float*)d_in[12];
    const float* att_W1 = (const float*)d_in[13];
    const float* att_b1 = (const float*)d_in[14];
    const float* att_W2 = (const float*)d_in[15];
    const float* att_b2 = (const float*)d_in[16];
    const float* gru_Wih = (const float*)d_in[17];
    const float* gru_bih = (const float*)d_in[18];
    const float* gru_Whh = (const float*)d_in[19];
    const float* gru_bhh = (const float*)d_in[20];
    const float* th_W1 = (const float*)d_in[21];
    const float* th_b1 = (const float*)d_in[22];
    const float* th_W2 = (const float*)d_in[23];
    const float* th_b2 = (const float*)d_in[24];
    const float* th_W3 = (const float*)d_in[25];
    const float* th_b3 = (const float*)d_in[26];
    const float* al_W1 = (const float*)d_in[27];
    const float* al_b1 = (const float*)d_in[28];
    const float* al_W2 = (const float*)d_in[29];
    const float* al_b2 = (const float*)d_in[30];
    const float* al_W3 = (const float*)d_in[31];
    const float* al_b3 = (const float*)d_in[32];

    const int N = in_sizes[0] / 512;
    const int M = in_sizes[1] / 2;
    const int E = in_sizes[3] / 2;
    const int S = in_sizes[6];   // 512

    // ---- workspace layout (floats) ----
    float* ws = (float*)d_ws;
    size_t o = 0;
    float* bufS  = ws + o; o += (size_t)N * 128;   // state
    float* bufR  = ws + o; o += (size_t)N * 128;   // relu(state) / copy
    float* agg   = ws + o; o += (size_t)N * 128;
    float* projm = ws + o; o += (size_t)N * 128;
    float* proja = ws + o; o += (size_t)N * 128;
    size_t bigsz = (size_t)M * 128;
    if ((size_t)N * 384 > bigsz) bigsz = (size_t)N * 384;
    if ((size_t)E * 128 > bigsz) bigsz = (size_t)E * 128;
    float* big   = ws + o; o += bigsz;             // msgbuf | gi | h1
    float* lt    = ws + o; o += (size_t)E * 20;
    float* la    = ws + o; o += (size_t)E * 20;
    float* radj  = ws + o; o += (size_t)S * 20;
    float* rla   = ws + o; o += (size_t)S * 20;
    float* cnt   = ws + o; o += (size_t)S;
    float* h2 = bufR;  // E*128 == 4*N*128 here: spans bufR..proja (all dead by then)

    const dim3 blk(256);
    const int gN = (N + 255) / 256;
    const int gM = (M + 255) / 256;
    const int gE = (E + 255) / 256;

    // zero loss accumulators (radj, rla, cnt contiguous)
    hipMemsetAsync(radj, 0, (size_t)(S * 20 * 2 + S) * sizeof(float), stream);

    // decoder: state = node_feat @ dec_W^T + dec_b
    gemm_rt<128, 0, false><<<gN, blk, 0, stream>>>(node_feat, nullptr, dec_W, 512, dec_b,
                                                   bufS, 128, N, 512);

    for (int l = 0; l < 3; ++l) {
        act_copy_kernel<<<(N * 128 / 4 + 255) / 256, blk, 0, stream>>>(
            (const float4*)bufS, (float4*)bufR, N * 128 / 4, l > 0 ? 1 : 0);
        // proj = sIn @ W1a^T  (first 128 cols of W1; K-section [0,128) of wstride-256 rows)
        gemm_rt<128, 0, false><<<gN, blk, 0, stream>>>(bufR, nullptr,
            msg_W1 + (size_t)l * 128 * 256, 256, nullptr, projm, 128, N, 128);
        gemm_rt<128, 0, false><<<gN, blk, 0, stream>>>(bufR, nullptr,
            att_W1 + (size_t)l * 128 * 256, 256, nullptr, proja, 128, N, 128);
        hipMemsetAsync(agg, 0, (size_t)N * 128 * sizeof(float), stream);
        edge_msg_kernel<<<gM, blk, 0, stream>>>(projm, edge, edge_feat,
            msg_W1 + (size_t)l * 128 * 256 + 128, msg_b1 + l * 128,
            msg_W2 + (size_t)l * 128 * 128, msg_b2 + l * 128, big, M);
        edge_att_kernel<<<gM, blk, 0, stream>>>(proja, edge, edge_feat,
            att_W1 + (size_t)l * 128 * 256 + 128, att_b1 + l * 128,
            att_W2 + (size_t)l * 128 * 128, att_b2 + l * 128, big, agg, M);
        // gi = agg @ Wih^T + bih  (3 x 128-out slabs into N x 384 buffer)
        for (int p = 0; p < 3; ++p) {
            gemm_rt<128, 0, false><<<gN, blk, 0, stream>>>(agg, nullptr,
                gru_Wih + (size_t)l * 384 * 128 + (size_t)p * 128 * 128, 128,
                gru_bih + l * 384 + p * 128, big + p * 128, 384, N, 128);
        }
        gru_kernel<<<gN, blk, 0, stream>>>(bufR, big,
            gru_Whh + (size_t)l * 384 * 128, gru_bhh + l * 384, bufS, N);
    }

    // theta MLP: d2 -> h1 -> h2 -> lt
    gemm_rt<128, 1, true ><<<gE, blk, 0, stream>>>(bufS, gnn_idx, th_W1, 128, th_b1, big, 128, E, 128);
    gemm_rt<128, 1, false><<<gE, blk, 0, stream>>>(big, nullptr, th_W2, 128, th_b2, h2, 128, E, 128);
    gemm_rt< 20, 0, false><<<gE, blk, 0, stream>>>(h2, nullptr, th_W3, 128, th_b3, lt, 20, E, 128);
    // alpha MLP
    gemm_rt<128, 1, true ><<<gE, blk, 0, stream>>>(bufS, gnn_idx, al_W1, 128, al_b1, big, 128, E, 128);
    gemm_rt<128, 1, false><<<gE, blk, 0, stream>>>(big, nullptr, al_W2, 128, al_b2, h2, 128, E, 128);
    gemm_rt< 20, 0, false><<<gE, blk, 0, stream>>>(h2, nullptr, al_W3, 128, al_b3, la, 20, E, 128);

    loss_kernel<<<gE, blk, 0, stream>>>(lt, la, label, sg_idx, radj, rla, cnt, E, S);
    final_kernel<<<1, S, 0, stream>>>(radj, rla, cnt, bc_idx, (float*)d_out);
}

// Round 2
// 2434.795 us; speedup vs baseline: 5.3512x; 5.3512x over previous
//
#include <hip/hip_runtime.h>
#include <cstdint>
#include <cstddef>

// GRAN mixture-Bernoulli forward — R2: bf16 MFMA everywhere.
// Sizes: N=50000, M=250000, E=200000, MAXN=512, H=EF=ATT=128, K=20, L=3, S=512.
//
// All GEMMs run "transposed": D^T[out][row] = mfma(A=W-frag(LDS,swizzled),
// B=activation-frag(global bf16 rows)). Lane then holds 4 consecutive out-dims
// per fragment -> 8B packed stores (LDS hidden tiles / global outputs).
// LDS tiles use XOR swizzle: 16B-unit ^= (row&7)  (G4 bank-conflict fix).

typedef __bf16 bf16x8 __attribute__((ext_vector_type(8)));
typedef short  s16x8  __attribute__((ext_vector_type(8)));
typedef short  s16x4  __attribute__((ext_vector_type(4)));
typedef float  f32x4  __attribute__((ext_vector_type(4)));

__device__ inline unsigned short f2bf(float f) {           // RNE fp32->bf16
    unsigned int u = __float_as_uint(f);
    u += 0x7FFFu + ((u >> 16) & 1u);
    return (unsigned short)(u >> 16);
}
__device__ inline float bf2f(unsigned short b) {
    return __uint_as_float(((unsigned int)b) << 16);
}

__device__ inline f32x4 MFMA(bf16x8 a, bf16x8 b, f32x4 c) {
    return __builtin_amdgcn_mfma_f32_16x16x32_bf16(a, b, c, 0, 0, 0);
}

// Swizzled LDS tile: row-major [rows][128 bf16] = 256B/row, 16B unit u stored
// at u ^ (row&7).
__device__ inline bf16x8 ld_swz(const char* lds, int row, int unit) {
    return *(const bf16x8*)(lds + row * 256 + ((unit ^ (row & 7)) << 4));
}

// Stage W (fp32 global, row-major, rowstride floats) -> LDS bf16 swizzled.
// rowsTot multiple of 16; rows >= rowsValid zero-filled. 256 threads.
__device__ inline void stage_w(char* lds, const float* __restrict__ W,
                               int wstride, int rowsValid, int rowsTot) {
    int t = threadIdx.x;
    for (int p = 0; p < rowsTot / 16; ++p) {
        int row = p * 16 + (t >> 4), u = t & 15;
        float4 a = make_float4(0.f, 0.f, 0.f, 0.f), b = a;
        if (row < rowsValid) {
            a = *(const float4*)&W[(size_t)row * wstride + u * 8];
            b = *(const float4*)&W[(size_t)row * wstride + u * 8 + 4];
        }
        s16x8 s;
        s[0] = f2bf(a.x); s[1] = f2bf(a.y); s[2] = f2bf(a.z); s[3] = f2bf(a.w);
        s[4] = f2bf(b.x); s[5] = f2bf(b.y); s[6] = f2bf(b.z); s[7] = f2bf(b.w);
        *(s16x8*)(lds + row * 256 + ((u ^ (row & 7)) << 4)) = s;
    }
}

__device__ inline bf16x8 ld_f32_frag(const float* __restrict__ p) {
    float4 a = *(const float4*)p, b = *(const float4*)(p + 4);
    s16x8 s;
    s[0] = f2bf(a.x); s[1] = f2bf(a.y); s[2] = f2bf(a.z); s[3] = f2bf(a.w);
    s[4] = f2bf(b.x); s[5] = f2bf(b.y); s[6] = f2bf(b.z); s[7] = f2bf(b.w);
    return __builtin_bit_cast(bf16x8, s);
}

// Write one D^T fragment (4 consecutive out-dims of one row) into swizzled HID.
__device__ inline void hid_write(char* HID, int h0, int erow, s16x4 s4) {
    int unit = h0 >> 3;
    *(s16x4*)(HID + erow * 256 + ((unit ^ (erow & 7)) << 4) + ((h0 & 4) << 1)) = s4;
}

// ---------------------------------------------------------------------------
// Generic transposed GEMM: Out[row][c] = B[row][:] . W[c][:] + bias[c]
// (computed as D^T = W @ B^T). 128 rows/block, 4 waves; out-dim chunks of 128.
// B: global rows (bf16 or fp32->cvt), W: fp32 [out][K] rowstride wstride.
// ---------------------------------------------------------------------------
template<int B_FP32, int OUT_BF16>
__global__ __launch_bounds__(256, 2)
void mm_t(const void* __restrict__ Bact, int ldb, int R,
          const float* __restrict__ W, int wstride, int K,
          const float* __restrict__ bias,
          void* __restrict__ Out, int ostride, int nchunk)
{
    __shared__ char Wl[32768];
    const int tid = threadIdx.x, l = tid & 63, w = tid >> 6;
    const int rb = blockIdx.x * 128;

    for (int p = 0; p < nchunk; ++p) {
        f32x4 acc[2][8] = {};
        for (int kc = 0; kc < K; kc += 128) {
            __syncthreads();
            stage_w(Wl, W + (size_t)(p * 128) * wstride + kc, wstride, 128, 128);
            __syncthreads();
#pragma unroll
            for (int ks = 0; ks < 4; ++ks) {
                bf16x8 bfr[8];
#pragma unroll
                for (int n = 0; n < 8; ++n) {
                    int row = rb + 16 * n + (l & 15); if (row >= R) row = R - 1;
                    int koff = kc + ks * 32 + (l >> 4) * 8;
                    if (B_FP32)
                        bfr[n] = ld_f32_frag((const float*)Bact + (size_t)row * ldb + koff);
                    else
                        bfr[n] = *(const bf16x8*)((const short*)Bact + (size_t)row * ldb + koff);
                }
#pragma unroll
                for (int mt = 0; mt < 2; ++mt) {
                    bf16x8 a = ld_swz(Wl, 32 * w + 16 * mt + (l & 15), ks * 4 + (l >> 4));
#pragma unroll
                    for (int n = 0; n < 8; ++n) acc[mt][n] = MFMA(a, bfr[n], acc[mt][n]);
                }
            }
        }
#pragma unroll
        for (int mt = 0; mt < 2; ++mt) {
            int c0 = 32 * w + 16 * mt + ((l >> 4) << 2);
            float4 bv = make_float4(0.f, 0.f, 0.f, 0.f);
            if (bias) bv = *(const float4*)&bias[p * 128 + c0];
#pragma unroll
            for (int n = 0; n < 8; ++n) {
                int row = rb + 16 * n + (l & 15);
                if (row < R) {
                    f32x4 v = acc[mt][n];
                    v[0] += bv.x; v[1] += bv.y; v[2] += bv.z; v[3] += bv.w;
                    if (OUT_BF16) {
                        s16x4 s4; s4[0] = f2bf(v[0]); s4[1] = f2bf(v[1]);
                        s4[2] = f2bf(v[2]); s4[3] = f2bf(v[3]);
                        *(s16x4*)((short*)Out + (size_t)row * ostride + p * 128 + c0) = s4;
                    } else {
                        *(f32x4*)((float*)Out + (size_t)row * ostride + p * 128 + c0) = v;
                    }
                }
            }
        }
    }
}

// ---------------------------------------------------------------------------
// Fused edge MLPs: for msg and att:
//   hid = relu(ef@W1b^T + (proj[src]-proj[dst]) + b1) ;  out = hid@W2^T + b2
// then msgatt[e] = sigmoid(att)*msg  (bf16). 128 edges/block.
// ---------------------------------------------------------------------------
__global__ __launch_bounds__(256, 2)
void edge_fused(const short* __restrict__ ef, const int* __restrict__ edge,
                const float* __restrict__ projm, const float* __restrict__ proja,
                const float* __restrict__ mW1b, const float* __restrict__ mb1,
                const float* __restrict__ mW2,  const float* __restrict__ mb2,
                const float* __restrict__ aW1b, const float* __restrict__ ab1,
                const float* __restrict__ aW2,  const float* __restrict__ ab2,
                short* __restrict__ msgatt, int M)
{
    __shared__ char Wl[32768];
    __shared__ char HID[32768];
    const int tid = threadIdx.x, l = tid & 63, w = tid >> 6;
    const int eb = blockIdx.x * 128;

    int srcv[8], dstv[8];
#pragma unroll
    for (int n = 0; n < 8; ++n) {
        int e = eb + 16 * n + (l & 15); if (e >= M) e = M - 1;
        int2 sd = *(const int2*)&edge[2 * (size_t)e];
        srcv[n] = sd.x; dstv[n] = sd.y;
    }

    f32x4 msgv[2][8];

    for (int half = 0; half < 2; ++half) {
        const float* W1b = half ? aW1b : mW1b;
        const float* b1  = half ? ab1  : mb1;
        const float* W2  = half ? aW2  : mW2;
        const float* b2  = half ? ab2  : mb2;
        const float* proj = half ? proja : projm;

        __syncthreads();                       // prev readers of Wl/HID done
        stage_w(Wl, W1b, 256, 128, 128);
        __syncthreads();

        f32x4 acc[2][8] = {};
#pragma unroll
        for (int ks = 0; ks < 4; ++ks) {
            bf16x8 bfr[8];
#pragma unroll
            for (int n = 0; n < 8; ++n) {
                int e = eb + 16 * n + (l & 15); if (e >= M) e = M - 1;
                bfr[n] = *(const bf16x8*)(ef + (size_t)e * 128 + ks * 32 + (l >> 4) * 8);
            }
#pragma unroll
            for (int mt = 0; mt < 2; ++mt) {
                bf16x8 a = ld_swz(Wl, 32 * w + 16 * mt + (l & 15), ks * 4 + (l >> 4));
#pragma unroll
                for (int n = 0; n < 8; ++n) acc[mt][n] = MFMA(a, bfr[n], acc[mt][n]);
            }
        }
        // epilogue: + b1 + proj[src]-proj[dst], relu, pack -> HID (row-major)
#pragma unroll
        for (int mt = 0; mt < 2; ++mt) {
            int h0 = 32 * w + 16 * mt + ((l >> 4) << 2);
            float4 bv = *(const float4*)&b1[h0];
#pragma unroll
            for (int n = 0; n < 8; ++n) {
                f32x4 v = acc[mt][n];
                const float* ps = proj + (size_t)srcv[n] * 128 + h0;
                const float* pd = proj + (size_t)dstv[n] * 128 + h0;
                v[0] += bv.x + ps[0] - pd[0];
                v[1] += bv.y + ps[1] - pd[1];
                v[2] += bv.z + ps[2] - pd[2];
                v[3] += bv.w + ps[3] - pd[3];
                s16x4 s4;
                s4[0] = f2bf(fmaxf(v[0], 0.f)); s4[1] = f2bf(fmaxf(v[1], 0.f));
                s4[2] = f2bf(fmaxf(v[2], 0.f)); s4[3] = f2bf(fmaxf(v[3], 0.f));
                hid_write(HID, h0, 16 * n + (l & 15), s4);
            }
        }
        __syncthreads();                       // HID visible; Wl reads done
        stage_w(Wl, W2, 128, 128, 128);
        __syncthreads();

        f32x4 acc2[2][8] = {};
#pragma unroll
        for (int ks = 0; ks < 4; ++ks) {
            bf16x8 bfr[8];
#pragma unroll
            for (int n = 0; n < 8; ++n)
                bfr[n] = ld_swz(HID, 16 * n + (l & 15), ks * 4 + (l >> 4));
#pragma unroll
            for (int mt = 0; mt < 2; ++mt) {
                bf16x8 a = ld_swz(Wl, 32 * w + 16 * mt + (l & 15), ks * 4 + (l >> 4));
#pragma unroll
                for (int n = 0; n < 8; ++n) acc2[mt][n] = MFMA(a, bfr[n], acc2[mt][n]);
            }
        }
        if (!half) {
#pragma unroll
            for (int mt = 0; mt < 2; ++mt) {
                int c0 = 32 * w + 16 * mt + ((l >> 4) << 2);
                float4 bv = *(const float4*)&b2[c0];
#pragma unroll
                for (int n = 0; n < 8; ++n) {
                    msgv[mt][n] = acc2[mt][n];
                    msgv[mt][n][0] += bv.x; msgv[mt][n][1] += bv.y;
                    msgv[mt][n][2] += bv.z; msgv[mt][n][3] += bv.w;
                }
            }
        } else {
#pragma unroll
            for (int mt = 0; mt < 2; ++mt) {
                int c0 = 32 * w + 16 * mt + ((l >> 4) << 2);
                float4 bv = *(const float4*)&b2[c0];
#pragma unroll
                for (int n = 0; n < 8; ++n) {
                    int e = eb + 16 * n + (l & 15);
                    if (e < M) {
                        f32x4 v = acc2[mt][n];
                        float o0 = msgv[mt][n][0] / (1.f + expf(-(v[0] + bv.x)));
                        float o1 = msgv[mt][n][1] / (1.f + expf(-(v[1] + bv.y)));
                        float o2 = msgv[mt][n][2] / (1.f + expf(-(v[2] + bv.z)));
                        float o3 = msgv[mt][n][3] / (1.f + expf(-(v[3] + bv.w)));
                        s16x4 s4;
                        s4[0] = f2bf(o0); s4[1] = f2bf(o1);
                        s4[2] = f2bf(o2); s4[3] = f2bf(o3);
                        *(s16x4*)(msgatt + (size_t)e * 128 + c0) = s4;
                    }
                }
            }
        }
    }
}

// ---------------------------------------------------------------------------
// Fused 3-layer output MLP (theta / alpha): d2 -> relu W1 -> relu W2 -> W3(20)
// ---------------------------------------------------------------------------
__global__ __launch_bounds__(256, 2)
void mlp3_fused(const short* __restrict__ d2,
                const float* __restrict__ W1, const float* __restrict__ b1,
                const float* __restrict__ W2, const float* __restrict__ b2,
                const float* __restrict__ W3, const float* __restrict__ b3,
                float* __restrict__ out20, int E)
{
    __shared__ char Wl[32768];
    __shared__ char HID[32768];
    const int tid = threadIdx.x, l = tid & 63, w = tid >> 6;
    const int eb = blockIdx.x * 128;

    // stage 1: h1 = relu(d2@W1^T + b1) -> HID
    stage_w(Wl, W1, 128, 128, 128);
    __syncthreads();
    {
        f32x4 acc[2][8] = {};
#pragma unroll
        for (int ks = 0; ks < 4; ++ks) {
            bf16x8 bfr[8];
#pragma unroll
            for (int n = 0; n < 8; ++n) {
                int e = eb + 16 * n + (l & 15); if (e >= E) e = E - 1;
                bfr[n] = *(const bf16x8*)(d2 + (size_t)e * 128 + ks * 32 + (l >> 4) * 8);
            }
#pragma unroll
            for (int mt = 0; mt < 2; ++mt) {
                bf16x8 a = ld_swz(Wl, 32 * w + 16 * mt + (l & 15), ks * 4 + (l >> 4));
#pragma unroll
                for (int n = 0; n < 8; ++n) acc[mt][n] = MFMA(a, bfr[n], acc[mt][n]);
            }
        }
#pragma unroll
        for (int mt = 0; mt < 2; ++mt) {
            int h0 = 32 * w + 16 * mt + ((l >> 4) << 2);
            float4 bv = *(const float4*)&b1[h0];
#pragma unroll
            for (int n = 0; n < 8; ++n) {
                f32x4 v = acc[mt][n];
                s16x4 s4;
                s4[0] = f2bf(fmaxf(v[0] + bv.x, 0.f));
                s4[1] = f2bf(fmaxf(v[1] + bv.y, 0.f));
                s4[2] = f2bf(fmaxf(v[2] + bv.z, 0.f));
                s4[3] = f2bf(fmaxf(v[3] + bv.w, 0.f));
                hid_write(HID, h0, 16 * n + (l & 15), s4);
            }
        }
    }
    __syncthreads();
    stage_w(Wl, W2, 128, 128, 128);
    __syncthreads();
    // stage 2: h2 = relu(h1@W2^T + b2) -> regs, then HID
    f32x4 acc2[2][8] = {};
#pragma unroll
    for (int ks = 0; ks < 4; ++ks) {
        bf16x8 bfr[8];
#pragma unroll
        for (int n = 0; n < 8; ++n)
            bfr[n] = ld_swz(HID, 16 * n + (l & 15), ks * 4 + (l >> 4));
#pragma unroll
        for (int mt = 0; mt < 2; ++mt) {
            bf16x8 a = ld_swz(Wl, 32 * w + 16 * mt + (l & 15), ks * 4 + (l >> 4));
#pragma unroll
            for (int n = 0; n < 8; ++n) acc2[mt][n] = MFMA(a, bfr[n], acc2[mt][n]);
        }
    }
    __syncthreads();                  // all HID(h1) reads done
#pragma unroll
    for (int mt = 0; mt < 2; ++mt) {
        int h0 = 32 * w + 16 * mt + ((l >> 4) << 2);
        float4 bv = *(const float4*)&b2[h0];
#pragma unroll
        for (int n = 0; n < 8; ++n) {
            f32x4 v = acc2[mt][n];
            s16x4 s4;
            s4[0] = f2bf(fmaxf(v[0] + bv.x, 0.f));
            s4[1] = f2bf(fmaxf(v[1] + bv.y, 0.f));
            s4[2] = f2bf(fmaxf(v[2] + bv.z, 0.f));
            s4[3] = f2bf(fmaxf(v[3] + bv.w, 0.f));
            hid_write(HID, h0, 16 * n + (l & 15), s4);
        }
    }
    __syncthreads();
    stage_w(Wl, W3, 128, 20, 32);     // 20 valid rows, padded to 32
    __syncthreads();
    // stage 3: out = h2@W3^T + b3. Waves split edge-fragments: n = 2w+j.
    f32x4 acc3[2][2] = {};
#pragma unroll
    for (int ks = 0; ks < 4; ++ks) {
        bf16x8 bfr[2];
#pragma unroll
        for (int j = 0; j < 2; ++j)
            bfr[j] = ld_swz(HID, 16 * (2 * w + j) + (l & 15), ks * 4 + (l >> 4));
#pragma unroll
        for (int mt = 0; mt < 2; ++mt) {
            bf16x8 a = ld_swz(Wl, 16 * mt + (l & 15), ks * 4 + (l >> 4));
#pragma unroll
            for (int j = 0; j < 2; ++j) acc3[mt][j] = MFMA(a, bfr[j], acc3[mt][j]);
        }
    }
#pragma unroll
    for (int mt = 0; mt < 2; ++mt) {
        int c0 = 16 * mt + ((l >> 4) << 2);
#pragma unroll
        for (int j = 0; j < 2; ++j) {
            int e = eb + 16 * (2 * w + j) + (l & 15);
            if (e < E) {
#pragma unroll
                for (int q = 0; q < 4; ++q) {
                    int c = c0 + q;
                    if (c < 20) out20[(size_t)e * 20 + c] = acc3[mt][j][q] + b3[c];
                }
            }
        }
    }
}

// ---------------------------------------------------------------------------
// CSR build (dst is fixed across layers) + gather-sum aggregation
// ---------------------------------------------------------------------------
__global__ void csr_count(const int* __restrict__ edge, int* __restrict__ cnt, int M) {
    int e = blockIdx.x * 256 + threadIdx.x;
    if (e < M) atomicAdd(&cnt[edge[2 * (size_t)e + 1]], 1);
}

__global__ void csr_scan(const int* __restrict__ cnt, int* __restrict__ rowptr,
                         int* __restrict__ wofs, int N)
{
    __shared__ int part[1024];
    int t = threadIdx.x;
    int chunk = (N + 1023) / 1024;
    int b0 = t * chunk, b1 = b0 + chunk; if (b1 > N) b1 = N; if (b0 > N) b0 = N;
    int s = 0;
    for (int i = b0; i < b1; ++i) s += cnt[i];
    part[t] = s;
    __syncthreads();
    for (int off = 1; off < 1024; off <<= 1) {
        int v = (t >= off) ? part[t - off] : 0;
        __syncthreads();
        part[t] += v;
        __syncthreads();
    }
    int run = (t ? part[t - 1] : 0);
    for (int i = b0; i < b1; ++i) { rowptr[i] = run; wofs[i] = run; run += cnt[i]; }
    if (t == 1023) rowptr[N] = run;
}

__global__ void csr_scatter(const int* __restrict__ edge, int* __restrict__ wofs,
                            int* __restrict__ eidx, int M)
{
    int e = blockIdx.x * 256 + threadIdx.x;
    if (e < M) { int p = atomicAdd(&wofs[edge[2 * (size_t)e + 1]], 1); eidx[p] = e; }
}

__global__ __launch_bounds__(256)
void agg_gather(const short* __restrict__ msgatt, const int* __restrict__ rowptr,
                const int* __restrict__ eidx, float* __restrict__ agg, int N)
{
    int v = (blockIdx.x * 256 + threadIdx.x) >> 6;
    int l = threadIdx.x & 63;
    if (v >= N) return;
    int b = rowptr[v], e = rowptr[v + 1];
    float sx = 0.f, sy = 0.f;
    for (int i = b; i < e; ++i) {
        unsigned int u = *(const unsigned int*)(msgatt + (size_t)eidx[i] * 128 + 2 * l);
        sx += bf2f((unsigned short)(u & 0xffffu));
        sy += bf2f((unsigned short)(u >> 16));
    }
    float2 r = make_float2(sx, sy);
    *(float2*)&agg[(size_t)v * 128 + 2 * l] = r;
}

// ---------------------------------------------------------------------------
__global__ void gru_gates(const float* __restrict__ gi, const float* __restrict__ gh,
                          const short* __restrict__ sUse,
                          short* __restrict__ sPost, short* __restrict__ sNext, int N)
{
    int i = blockIdx.x * 256 + threadIdx.x;
    if (i >= N * 32) return;
    int n = i >> 5, c = (i & 31) * 4;
    const float* gir = gi + (size_t)n * 384 + c;
    const float* ghr = gh + (size_t)n * 384 + c;
    float4 ir = *(const float4*)gir, iz = *(const float4*)(gir + 128), in_ = *(const float4*)(gir + 256);
    float4 hr = *(const float4*)ghr, hz = *(const float4*)(ghr + 128), hn = *(const float4*)(ghr + 256);
    s16x4 sv = *(const s16x4*)(sUse + (size_t)n * 128 + c);
    float irv[4] = {ir.x, ir.y, ir.z, ir.w}, izv[4] = {iz.x, iz.y, iz.z, iz.w};
    float inv[4] = {in_.x, in_.y, in_.z, in_.w};
    float hrv[4] = {hr.x, hr.y, hr.z, hr.w}, hzv[4] = {hz.x, hz.y, hz.z, hz.w};
    float hnv[4] = {hn.x, hn.y, hn.z, hn.w};
    s16x4 po, ne;
#pragma unroll
    for (int j = 0; j < 4; ++j) {
        float s = bf2f((unsigned short)sv[j]);
        float r = 1.f / (1.f + expf(-(irv[j] + hrv[j])));
        float z = 1.f / (1.f + expf(-(izv[j] + hzv[j])));
        float nn = tanhf(inv[j] + r * hnv[j]);
        float o = (1.f - z) * nn + z * s;
        po[j] = f2bf(o);
        ne[j] = f2bf(fmaxf(o, 0.f));
    }
    *(s16x4*)(sPost + (size_t)n * 128 + c) = po;
    *(s16x4*)(sNext + (size_t)n * 128 + c) = ne;
}

__global__ void cvt_bf16(const float* __restrict__ in, short* __restrict__ out, long n8) {
    long i = (long)blockIdx.x * 256 + threadIdx.x;
    if (i >= n8) return;
    float4 a = *(const float4*)(in + i * 8), b = *(const float4*)(in + i * 8 + 4);
    s16x8 s;
    s[0] = f2bf(a.x); s[1] = f2bf(a.y); s[2] = f2bf(a.z); s[3] = f2bf(a.w);
    s[4] = f2bf(b.x); s[5] = f2bf(b.y); s[6] = f2bf(b.z); s[7] = f2bf(b.w);
    *(s16x8*)(out + i * 8) = s;
}

__global__ void d2_gather(const short* __restrict__ s, const int* __restrict__ gidx,
                          short* __restrict__ d2, int E)
{
    long i = (long)blockIdx.x * 256 + threadIdx.x;
    if (i >= (long)E * 16) return;
    int e = (int)(i >> 4), u = (int)(i & 15);
    int2 ab = *(const int2*)&gidx[2 * (size_t)e];
    s16x8 x = *(const s16x8*)(s + (size_t)ab.x * 128 + u * 8);
    s16x8 y = *(const s16x8*)(s + (size_t)ab.y * 128 + u * 8);
    s16x8 r;
#pragma unroll
    for (int j = 0; j < 8; ++j)
        r[j] = f2bf(bf2f((unsigned short)x[j]) - bf2f((unsigned short)y[j]));
    *(s16x8*)(d2 + (size_t)e * 128 + u * 8) = r;
}

// ---------------------------------------------------------------------------
// Loss accumulation + final reduction (fp32, from R1 — passed)
// ---------------------------------------------------------------------------
__global__ __launch_bounds__(256)
void loss_kernel(const float* __restrict__ lt, const float* __restrict__ la,
                 const float* __restrict__ label, const int* __restrict__ sg,
                 float* __restrict__ radj, float* __restrict__ rla,
                 float* __restrict__ cnt, int E, int S)
{
    __shared__ float sadj[4][20];
    __shared__ float sla[4][20];
    __shared__ float scnt[4];
    __shared__ int sbase;
    const int tid = threadIdx.x;
    const int e = blockIdx.x * 256 + tid;
    if (tid == 0) sbase = sg[blockIdx.x * 256];
    if (tid < 80) { sadj[tid / 20][tid % 20] = 0.f; sla[tid / 20][tid % 20] = 0.f; }
    if (tid < 4) scnt[tid] = 0.f;
    __syncthreads();
    if (e < E) {
        int s = sg[e];
        int ls = s - sbase;
        bool local = (ls >= 0 && ls < 4);
        float y = label[e];
        if (local) atomicAdd(&scnt[ls], 1.f); else atomicAdd(&cnt[s], 1.f);
#pragma unroll
        for (int k = 0; k < 20; ++k) {
            float t = lt[(size_t)e * 20 + k];
            float sp = fmaxf(-t, 0.f) + log1pf(expf(-fabsf(t)));
            float adj = sp + (1.f - y) * t;
            float lav = la[(size_t)e * 20 + k];
            if (local) { atomicAdd(&sadj[ls][k], adj); atomicAdd(&sla[ls][k], lav); }
            else       { atomicAdd(&radj[s * 20 + k], adj); atomicAdd(&rla[s * 20 + k], lav); }
        }
    }
    __syncthreads();
    if (tid < 80) {
        int ls = tid / 20, k = tid % 20;
        int s = sbase + ls;
        if (s < S) {
            float v = sadj[ls][k], v2 = sla[ls][k];
            if (v  != 0.f) atomicAdd(&radj[s * 20 + k], v);
            if (v2 != 0.f) atomicAdd(&rla[s * 20 + k], v2);
        }
    }
    if (tid < 4) {
        int s = sbase + tid;
        if (s < S && scnt[tid] != 0.f) atomicAdd(&cnt[s], scnt[tid]);
    }
}

__global__ void final_kernel(const float* __restrict__ radj, const float* __restrict__ rla,
                             const float* __restrict__ cnt, const int* __restrict__ bc_idx,
                             float* __restrict__ out)
{
    __shared__ float bcl[16], bcc[16];
    const int s = threadIdx.x;
    if (s < 16) { bcl[s] = 0.f; bcc[s] = 0.f; }
    __syncthreads();
    float c = cnt[s];
    float x[20];
    float mx = -1e30f;
#pragma unroll
    for (int k = 0; k < 20; ++k) { x[k] = rla[s * 20 + k] / c; mx = fmaxf(mx, x[k]); }
    float se = 0.f;
#pragma unroll
    for (int k = 0; k < 20; ++k) se += expf(x[k] - mx);
    float lse = mx + logf(se);
    float t[20];
    float m2 = -1e30f;
#pragma unroll
    for (int k = 0; k < 20; ++k) { t[k] = -radj[s * 20 + k] + x[k] - lse; m2 = fmaxf(m2, t[k]); }
    float s2 = 0.f;
#pragma unroll
    for (int k = 0; k < 20; ++k) s2 += expf(t[k] - m2);
    float lp = m2 + logf(s2);
    atomicAdd(&bcl[bc_idx[s]], lp);
    atomicAdd(&bcc[bc_idx[s]], c);
    __syncthreads();
    if (s == 0) {
        float a = 0.f;
        for (int b = 0; b < 16; ++b) a += bcl[b] / bcc[b];
        out[0] = -a / 16.f;
    }
}

// ---------------------------------------------------------------------------
extern "C" void kernel_launch(void* const* d_in, const int* in_sizes, int n_in,
                              void* d_out, int out_size, void* d_ws, size_t ws_size,
                              hipStream_t stream)
{
    const float* node_feat = (const float*)d_in[0];
    const int*   edge      = (const int*)  d_in[1];
    const float* edge_feat = (const float*)d_in[2];
    const int*   gnn_idx   = (const int*)  d_in[3];
    const float* label     = (const float*)d_in[4];
    const int*   sg_idx    = (const int*)  d_in[5];
    const int*   bc_idx    = (const int*)  d_in[6];
    const float* dec_W  = (const float*)d_in[7];
    const float* dec_b  = (const float*)d_in[8];
    const float* msg_W1 = (const float*)d_in[9];
    const float* msg_b1 = (const float*)d_in[10];
    const float* msg_W2 = (const float*)d_in[11];
    const float* msg_b2 = (const float*)d_in[12];
    const float* att_W1 = (const float*)d_in[13];
    const float* att_b1 = (const float*)d_in[14];
    const float* att_W2 = (const float*)d_in[15];
    const float* att_b2 = (const float*)d_in[16];
    const float* gru_Wih = (const float*)d_in[17];
    const float* gru_bih = (const float*)d_in[18];
    const float* gru_Whh = (const float*)d_in[19];
    const float* gru_bhh = (const float*)d_in[20];
    const float* th_W1 = (const float*)d_in[21];
    const float* th_b1 = (const float*)d_in[22];
    const float* th_W2 = (const float*)d_in[23];
    const float* th_b2 = (const float*)d_in[24];
    const float* th_W3 = (const float*)d_in[25];
    const float* th_b3 = (const float*)d_in[26];
    const float* al_W1 = (const float*)d_in[27];
    const float* al_b1 = (const float*)d_in[28];
    const float* al_W2 = (const float*)d_in[29];
    const float* al_b2 = (const float*)d_in[30];
    const float* al_W3 = (const float*)d_in[31];
    const float* al_b3 = (const float*)d_in[32];

    const int N = in_sizes[0] / 512;
    const int M = in_sizes[1] / 2;
    const int E = in_sizes[3] / 2;
    const int S = in_sizes[6];

    // ---- workspace (256B-aligned slabs) ----
    size_t off = 0;
    auto alloc = [&](size_t bytes) {
        char* p = (char*)d_ws + off;
        off += (bytes + 255) & ~(size_t)255;
        return p;
    };
    short* sA     = (short*)alloc((size_t)N * 128 * 2);
    short* sB     = (short*)alloc((size_t)N * 128 * 2);
    short* sP     = (short*)alloc((size_t)N * 128 * 2);
    short* efb    = (short*)alloc((size_t)M * 128 * 2);
    short* msgatt = (short*)alloc((size_t)M * 128 * 2);
    float* projm  = (float*)alloc((size_t)N * 128 * 4);
    float* proja  = (float*)alloc((size_t)N * 128 * 4);
    float* agg    = (float*)alloc((size_t)N * 128 * 4);
    float* gi     = (float*)alloc((size_t)N * 384 * 4);
    float* gh     = (float*)alloc((size_t)N * 384 * 4);
    int*   cntN   = (int*)  alloc((size_t)N * 4);
    int*   wofs   = (int*)  alloc((size_t)N * 4);
    int*   rowptr = (int*)  alloc((size_t)(N + 1) * 4);
    int*   eidx   = (int*)  alloc((size_t)M * 4);
    float* radj   = (float*)alloc((size_t)S * 20 * 4);
    float* rla    = (float*)alloc((size_t)S * 20 * 4);
    float* cntS   = (float*)alloc((size_t)S * 4);
    // overlays (dead by the time they're used)
    short* d2 = (short*)gi;            // E*128*2 = 51.2MB <= N*384*4
    float* lt = gh;                    // E*20*4 = 16MB
    float* la = gh + (size_t)E * 20;   // +16MB  (<= N*384*4 total)

    const dim3 blk(256);
    const int gN  = (N + 127) / 128;
    const int gM  = (M + 127) / 128;
    const int gE  = (E + 127) / 128;
    const int gMt = (M + 255) / 256;
    const int gEl = (E + 255) / 256;

    hipMemsetAsync(radj, 0, (size_t)(S * 20 * 2 + S) * 4, stream);
    hipMemsetAsync(cntN, 0, (size_t)N * 4, stream);

    // CSR build (dst fixed for all layers)
    csr_count  <<<gMt, blk, 0, stream>>>(edge, cntN, M);
    csr_scan   <<<1, 1024, 0, stream>>>(cntN, rowptr, wofs, N);
    csr_scatter<<<gMt, blk, 0, stream>>>(edge, wofs, eidx, M);

    // edge_feat -> bf16
    cvt_bf16<<<(int)(((long)M * 16 + 255) / 256), blk, 0, stream>>>(edge_feat, efb, (long)M * 16);

    // decoder: s = node_feat @ dec_W^T + dec_b   (bf16 out)
    mm_t<1, 1><<<gN, blk, 0, stream>>>(node_feat, 512, N, dec_W, 512, 512, dec_b, sA, 128, 1);

    short* bufs[2] = { sA, sB };
    for (int l = 0; l < 3; ++l) {
        short* sin  = bufs[l & 1];
        short* snxt = bufs[(l + 1) & 1];
        // proj = sin @ W1a^T  (first 128 cols of W1, rowstride 256)
        mm_t<0, 0><<<gN, blk, 0, stream>>>(sin, 128, N, msg_W1 + (size_t)l * 128 * 256, 256, 128,
                                           nullptr, projm, 128, 1);
        mm_t<0, 0><<<gN, blk, 0, stream>>>(sin, 128, N, att_W1 + (size_t)l * 128 * 256, 256, 128,
                                           nullptr, proja, 128, 1);
        edge_fused<<<gM, blk, 0, stream>>>(efb, edge, projm, proja,
            msg_W1 + (size_t)l * 128 * 256 + 128, msg_b1 + l * 128,
            msg_W2 + (size_t)l * 128 * 128,       msg_b2 + l * 128,
            att_W1 + (size_t)l * 128 * 256 + 128, att_b1 + l * 128,
            att_W2 + (size_t)l * 128 * 128,       att_b2 + l * 128,
            msgatt, M);
        agg_gather<<<(N * 64 + 255) / 256, blk, 0, stream>>>(msgatt, rowptr, eidx, agg, N);
        // gi = agg @ Wih^T + bih ; gh = sin @ Whh^T + bhh   (384 out = 3 chunks)
        mm_t<1, 0><<<gN, blk, 0, stream>>>(agg, 128, N, gru_Wih + (size_t)l * 384 * 128, 128, 128,
                                           gru_bih + l * 384, gi, 384, 3);
        mm_t<0, 0><<<gN, blk, 0, stream>>>(sin, 128, N, gru_Whh + (size_t)l * 384 * 128, 128, 128,
                                           gru_bhh + l * 384, gh, 384, 3);
        gru_gates<<<(N * 32 + 255) / 256, blk, 0, stream>>>(gi, gh, sin, sP, snxt, N);
    }

    // d2 = sP[i0] - sP[i1]  (bf16)
    d2_gather<<<(int)(((long)E * 16 + 255) / 256), blk, 0, stream>>>(sP, gnn_idx, d2, E);

    mlp3_fused<<<gE, blk, 0, stream>>>(d2, th_W1, th_b1, th_W2, th_b2, th_W3, th_b3, lt, E);
    mlp3_fused<<<gE, blk, 0, stream>>>(d2, al_W1, al_b1, al_W2, al_b2, al_W3, al_b3, la, E);

    loss_kernel<<<gEl, blk, 0, stream>>>(lt, la, label, sg_idx, radj, rla, cntS, E, S);
    final_kernel<<<1, S, 0, stream>>>(radj, rla, cntS, bc_idx, (float*)d_out);
}

// Round 3
// 2217.572 us; speedup vs baseline: 5.8754x; 1.0980x over previous
//
#include <hip/hip_runtime.h>
#include <cstdint>
#include <cstddef>

// GRAN mixture-Bernoulli forward — R3: bf16 everywhere + coalesced stores.
// Sizes: N=50000, M=250000, E=200000, MAXN=512, H=EF=ATT=128, K=20, L=3, S=512.
//
// R3 deltas vs R2 (traffic-bound per rocprof):
//  - proj stored bf16 (halves the scattered per-edge gather volume)
//  - every tile store routed through LDS repack -> full-line coalesced b128
//  - gi/gh bf16 (halves GRU pre-activation traffic)

typedef __bf16 bf16x8 __attribute__((ext_vector_type(8)));
typedef short  s16x8  __attribute__((ext_vector_type(8)));
typedef short  s16x4  __attribute__((ext_vector_type(4)));
typedef float  f32x4  __attribute__((ext_vector_type(4)));

__device__ inline unsigned short f2bf(float f) {           // RNE fp32->bf16
    unsigned int u = __float_as_uint(f);
    u += 0x7FFFu + ((u >> 16) & 1u);
    return (unsigned short)(u >> 16);
}
__device__ inline float bf2f(unsigned short b) {
    return __uint_as_float(((unsigned int)b) << 16);
}

__device__ inline f32x4 MFMA(bf16x8 a, bf16x8 b, f32x4 c) {
    return __builtin_amdgcn_mfma_f32_16x16x32_bf16(a, b, c, 0, 0, 0);
}

// Swizzled LDS tile: row-major [rows][128 bf16] = 256B/row, 16B unit u at u^(row&7).
__device__ inline bf16x8 ld_swz(const char* lds, int row, int unit) {
    return *(const bf16x8*)(lds + row * 256 + ((unit ^ (row & 7)) << 4));
}

// Stage W (fp32 global, rowstride floats) -> LDS bf16 swizzled. 256 threads.
__device__ inline void stage_w(char* lds, const float* __restrict__ W,
                               int wstride, int rowsValid, int rowsTot) {
    int t = threadIdx.x;
    for (int p = 0; p < rowsTot / 16; ++p) {
        int row = p * 16 + (t >> 4), u = t & 15;
        float4 a = make_float4(0.f, 0.f, 0.f, 0.f), b = a;
        if (row < rowsValid) {
            a = *(const float4*)&W[(size_t)row * wstride + u * 8];
            b = *(const float4*)&W[(size_t)row * wstride + u * 8 + 4];
        }
        s16x8 s;
        s[0] = f2bf(a.x); s[1] = f2bf(a.y); s[2] = f2bf(a.z); s[3] = f2bf(a.w);
        s[4] = f2bf(b.x); s[5] = f2bf(b.y); s[6] = f2bf(b.z); s[7] = f2bf(b.w);
        *(s16x8*)(lds + row * 256 + ((u ^ (row & 7)) << 4)) = s;
    }
}

__device__ inline bf16x8 ld_f32_frag(const float* __restrict__ p) {
    float4 a = *(const float4*)p, b = *(const float4*)(p + 4);
    s16x8 s;
    s[0] = f2bf(a.x); s[1] = f2bf(a.y); s[2] = f2bf(a.z); s[3] = f2bf(a.w);
    s[4] = f2bf(b.x); s[5] = f2bf(b.y); s[6] = f2bf(b.z); s[7] = f2bf(b.w);
    return __builtin_bit_cast(bf16x8, s);
}

// Write one D^T fragment (4 consecutive out-dims of one row) into swizzled tile.
__device__ inline void hid_write(char* HID, int h0, int erow, s16x4 s4) {
    int unit = h0 >> 3;
    *(s16x4*)(HID + erow * 256 + ((unit ^ (erow & 7)) << 4) + ((h0 & 4) << 1)) = s4;
}

// ---------------------------------------------------------------------------
// Transposed GEMM: Out[row][c] = B[row][:] . W[c][:] + bias[c], bf16 out.
// 128 rows/block, 4 waves; out-dim chunks of 128; stores via LDS repack.
// ---------------------------------------------------------------------------
template<int B_FP32>
__global__ __launch_bounds__(256, 2)
void mm_t(const void* __restrict__ Bact, int ldb, int R,
          const float* __restrict__ W, int wstride, int K,
          const float* __restrict__ bias,
          short* __restrict__ Out, int ostride, int nchunk)
{
    __shared__ char Wl[32768];
    const int tid = threadIdx.x, l = tid & 63, w = tid >> 6;
    const int rb = blockIdx.x * 128;

    for (int p = 0; p < nchunk; ++p) {
        f32x4 acc[2][8] = {};
        for (int kc = 0; kc < K; kc += 128) {
            __syncthreads();
            stage_w(Wl, W + (size_t)(p * 128) * wstride + kc, wstride, 128, 128);
            __syncthreads();
#pragma unroll
            for (int ks = 0; ks < 4; ++ks) {
                bf16x8 bfr[8];
#pragma unroll
                for (int n = 0; n < 8; ++n) {
                    int row = rb + 16 * n + (l & 15); if (row >= R) row = R - 1;
                    int koff = kc + ks * 32 + (l >> 4) * 8;
                    if (B_FP32)
                        bfr[n] = ld_f32_frag((const float*)Bact + (size_t)row * ldb + koff);
                    else
                        bfr[n] = *(const bf16x8*)((const short*)Bact + (size_t)row * ldb + koff);
                }
#pragma unroll
                for (int mt = 0; mt < 2; ++mt) {
                    bf16x8 a = ld_swz(Wl, 32 * w + 16 * mt + (l & 15), ks * 4 + (l >> 4));
#pragma unroll
                    for (int n = 0; n < 8; ++n) acc[mt][n] = MFMA(a, bfr[n], acc[mt][n]);
                }
            }
        }
        // epilogue: +bias, bf16, repack via Wl (swizzled) -> coalesced store
        __syncthreads();
#pragma unroll
        for (int mt = 0; mt < 2; ++mt) {
            int c0 = 32 * w + 16 * mt + ((l >> 4) << 2);
            float4 bv = make_float4(0.f, 0.f, 0.f, 0.f);
            if (bias) bv = *(const float4*)&bias[p * 128 + c0];
#pragma unroll
            for (int n = 0; n < 8; ++n) {
                f32x4 v = acc[mt][n];
                s16x4 s4;
                s4[0] = f2bf(v[0] + bv.x); s4[1] = f2bf(v[1] + bv.y);
                s4[2] = f2bf(v[2] + bv.z); s4[3] = f2bf(v[3] + bv.w);
                hid_write(Wl, c0, 16 * n + (l & 15), s4);
            }
        }
        __syncthreads();
#pragma unroll
        for (int p2 = 0; p2 < 8; ++p2) {
            int row = p2 * 16 + (tid >> 4);
            int r = rb + row;
            if (r < R) {
                bf16x8 v = ld_swz(Wl, row, tid & 15);
                *(s16x8*)(Out + (size_t)r * ostride + p * 128 + (tid & 15) * 8) =
                    __builtin_bit_cast(s16x8, v);
            }
        }
    }
}

// ---------------------------------------------------------------------------
// Fused edge MLPs (msg then att), proj in bf16; msgatt stored via LDS repack.
// ---------------------------------------------------------------------------
__global__ __launch_bounds__(256, 2)
void edge_fused(const short* __restrict__ ef, const int* __restrict__ edge,
                const short* __restrict__ projm, const short* __restrict__ proja,
                const float* __restrict__ mW1b, const float* __restrict__ mb1,
                const float* __restrict__ mW2,  const float* __restrict__ mb2,
                const float* __restrict__ aW1b, const float* __restrict__ ab1,
                const float* __restrict__ aW2,  const float* __restrict__ ab2,
                short* __restrict__ msgatt, int M)
{
    __shared__ char Wl[32768];
    __shared__ char HID[32768];
    const int tid = threadIdx.x, l = tid & 63, w = tid >> 6;
    const int eb = blockIdx.x * 128;

    int srcv[8], dstv[8];
#pragma unroll
    for (int n = 0; n < 8; ++n) {
        int e = eb + 16 * n + (l & 15); if (e >= M) e = M - 1;
        int2 sd = *(const int2*)&edge[2 * (size_t)e];
        srcv[n] = sd.x; dstv[n] = sd.y;
    }

    f32x4 msgv[2][8];

    for (int half = 0; half < 2; ++half) {
        const float* W1b = half ? aW1b : mW1b;
        const float* b1  = half ? ab1  : mb1;
        const float* W2  = half ? aW2  : mW2;
        const float* b2  = half ? ab2  : mb2;
        const short* proj = half ? proja : projm;

        __syncthreads();                       // prev readers of Wl/HID done
        stage_w(Wl, W1b, 256, 128, 128);
        __syncthreads();

        f32x4 acc[2][8] = {};
#pragma unroll
        for (int ks = 0; ks < 4; ++ks) {
            bf16x8 bfr[8];
#pragma unroll
            for (int n = 0; n < 8; ++n) {
                int e = eb + 16 * n + (l & 15); if (e >= M) e = M - 1;
                bfr[n] = *(const bf16x8*)(ef + (size_t)e * 128 + ks * 32 + (l >> 4) * 8);
            }
#pragma unroll
            for (int mt = 0; mt < 2; ++mt) {
                bf16x8 a = ld_swz(Wl, 32 * w + 16 * mt + (l & 15), ks * 4 + (l >> 4));
#pragma unroll
                for (int n = 0; n < 8; ++n) acc[mt][n] = MFMA(a, bfr[n], acc[mt][n]);
            }
        }
        // epilogue: + b1 + proj[src]-proj[dst] (bf16 gathers), relu -> HID
#pragma unroll
        for (int mt = 0; mt < 2; ++mt) {
            int h0 = 32 * w + 16 * mt + ((l >> 4) << 2);
            float4 bv = *(const float4*)&b1[h0];
#pragma unroll
            for (int n = 0; n < 8; ++n) {
                s16x4 ps = *(const s16x4*)(proj + (size_t)srcv[n] * 128 + h0);
                s16x4 pd = *(const s16x4*)(proj + (size_t)dstv[n] * 128 + h0);
                f32x4 v = acc[mt][n];
                v[0] += bv.x + bf2f((unsigned short)ps[0]) - bf2f((unsigned short)pd[0]);
                v[1] += bv.y + bf2f((unsigned short)ps[1]) - bf2f((unsigned short)pd[1]);
                v[2] += bv.z + bf2f((unsigned short)ps[2]) - bf2f((unsigned short)pd[2]);
                v[3] += bv.w + bf2f((unsigned short)ps[3]) - bf2f((unsigned short)pd[3]);
                s16x4 s4;
                s4[0] = f2bf(fmaxf(v[0], 0.f)); s4[1] = f2bf(fmaxf(v[1], 0.f));
                s4[2] = f2bf(fmaxf(v[2], 0.f)); s4[3] = f2bf(fmaxf(v[3], 0.f));
                hid_write(HID, h0, 16 * n + (l & 15), s4);
            }
        }
        __syncthreads();                       // HID visible; Wl reads done
        stage_w(Wl, W2, 128, 128, 128);
        __syncthreads();

        f32x4 acc2[2][8] = {};
#pragma unroll
        for (int ks = 0; ks < 4; ++ks) {
            bf16x8 bfr[8];
#pragma unroll
            for (int n = 0; n < 8; ++n)
                bfr[n] = ld_swz(HID, 16 * n + (l & 15), ks * 4 + (l >> 4));
#pragma unroll
            for (int mt = 0; mt < 2; ++mt) {
                bf16x8 a = ld_swz(Wl, 32 * w + 16 * mt + (l & 15), ks * 4 + (l >> 4));
#pragma unroll
                for (int n = 0; n < 8; ++n) acc2[mt][n] = MFMA(a, bfr[n], acc2[mt][n]);
            }
        }
        if (!half) {
#pragma unroll
            for (int mt = 0; mt < 2; ++mt) {
                int c0 = 32 * w + 16 * mt + ((l >> 4) << 2);
                float4 bv = *(const float4*)&b2[c0];
#pragma unroll
                for (int n = 0; n < 8; ++n) {
                    msgv[mt][n] = acc2[mt][n];
                    msgv[mt][n][0] += bv.x; msgv[mt][n][1] += bv.y;
                    msgv[mt][n][2] += bv.z; msgv[mt][n][3] += bv.w;
                }
            }
        } else {
            __syncthreads();                   // HID(hid) reads done
#pragma unroll
            for (int mt = 0; mt < 2; ++mt) {
                int c0 = 32 * w + 16 * mt + ((l >> 4) << 2);
                float4 bv = *(const float4*)&b2[c0];
#pragma unroll
                for (int n = 0; n < 8; ++n) {
                    f32x4 v = acc2[mt][n];
                    float o0 = msgv[mt][n][0] / (1.f + expf(-(v[0] + bv.x)));
                    float o1 = msgv[mt][n][1] / (1.f + expf(-(v[1] + bv.y)));
                    float o2 = msgv[mt][n][2] / (1.f + expf(-(v[2] + bv.z)));
                    float o3 = msgv[mt][n][3] / (1.f + expf(-(v[3] + bv.w)));
                    s16x4 s4;
                    s4[0] = f2bf(o0); s4[1] = f2bf(o1);
                    s4[2] = f2bf(o2); s4[3] = f2bf(o3);
                    hid_write(HID, c0, 16 * n + (l & 15), s4);
                }
            }
            __syncthreads();                   // out tile visible
#pragma unroll
            for (int p2 = 0; p2 < 8; ++p2) {
                int row = p2 * 16 + (tid >> 4);
                int e = eb + row;
                if (e < M) {
                    bf16x8 v = ld_swz(HID, row, tid & 15);
                    *(s16x8*)(msgatt + (size_t)e * 128 + (tid & 15) * 8) =
                        __builtin_bit_cast(s16x8, v);
                }
            }
        }
    }
}

// ---------------------------------------------------------------------------
// Fused 3-layer output MLP (theta / alpha): d2 -> relu W1 -> relu W2 -> W3(20)
// ---------------------------------------------------------------------------
__global__ __launch_bounds__(256, 2)
void mlp3_fused(const short* __restrict__ d2,
                const float* __restrict__ W1, const float* __restrict__ b1,
                const float* __restrict__ W2, const float* __restrict__ b2,
                const float* __restrict__ W3, const float* __restrict__ b3,
                float* __restrict__ out20, int E)
{
    __shared__ char Wl[32768];
    __shared__ char HID[32768];
    const int tid = threadIdx.x, l = tid & 63, w = tid >> 6;
    const int eb = blockIdx.x * 128;

    stage_w(Wl, W1, 128, 128, 128);
    __syncthreads();
    {
        f32x4 acc[2][8] = {};
#pragma unroll
        for (int ks = 0; ks < 4; ++ks) {
            bf16x8 bfr[8];
#pragma unroll
            for (int n = 0; n < 8; ++n) {
                int e = eb + 16 * n + (l & 15); if (e >= E) e = E - 1;
                bfr[n] = *(const bf16x8*)(d2 + (size_t)e * 128 + ks * 32 + (l >> 4) * 8);
            }
#pragma unroll
            for (int mt = 0; mt < 2; ++mt) {
                bf16x8 a = ld_swz(Wl, 32 * w + 16 * mt + (l & 15), ks * 4 + (l >> 4));
#pragma unroll
                for (int n = 0; n < 8; ++n) acc[mt][n] = MFMA(a, bfr[n], acc[mt][n]);
            }
        }
#pragma unroll
        for (int mt = 0; mt < 2; ++mt) {
            int h0 = 32 * w + 16 * mt + ((l >> 4) << 2);
            float4 bv = *(const float4*)&b1[h0];
#pragma unroll
            for (int n = 0; n < 8; ++n) {
                f32x4 v = acc[mt][n];
                s16x4 s4;
                s4[0] = f2bf(fmaxf(v[0] + bv.x, 0.f));
                s4[1] = f2bf(fmaxf(v[1] + bv.y, 0.f));
                s4[2] = f2bf(fmaxf(v[2] + bv.z, 0.f));
                s4[3] = f2bf(fmaxf(v[3] + bv.w, 0.f));
                hid_write(HID, h0, 16 * n + (l & 15), s4);
            }
        }
    }
    __syncthreads();
    stage_w(Wl, W2, 128, 128, 128);
    __syncthreads();
    f32x4 acc2[2][8] = {};
#pragma unroll
    for (int ks = 0; ks < 4; ++ks) {
        bf16x8 bfr[8];
#pragma unroll
        for (int n = 0; n < 8; ++n)
            bfr[n] = ld_swz(HID, 16 * n + (l & 15), ks * 4 + (l >> 4));
#pragma unroll
        for (int mt = 0; mt < 2; ++mt) {
            bf16x8 a = ld_swz(Wl, 32 * w + 16 * mt + (l & 15), ks * 4 + (l >> 4));
#pragma unroll
            for (int n = 0; n < 8; ++n) acc2[mt][n] = MFMA(a, bfr[n], acc2[mt][n]);
        }
    }
    __syncthreads();
#pragma unroll
    for (int mt = 0; mt < 2; ++mt) {
        int h0 = 32 * w + 16 * mt + ((l >> 4) << 2);
        float4 bv = *(const float4*)&b2[h0];
#pragma unroll
        for (int n = 0; n < 8; ++n) {
            f32x4 v = acc2[mt][n];
            s16x4 s4;
            s4[0] = f2bf(fmaxf(v[0] + bv.x, 0.f));
            s4[1] = f2bf(fmaxf(v[1] + bv.y, 0.f));
            s4[2] = f2bf(fmaxf(v[2] + bv.z, 0.f));
            s4[3] = f2bf(fmaxf(v[3] + bv.w, 0.f));
            hid_write(HID, h0, 16 * n + (l & 15), s4);
        }
    }
    __syncthreads();
    stage_w(Wl, W3, 128, 20, 32);
    __syncthreads();
    f32x4 acc3[2][2] = {};
#pragma unroll
    for (int ks = 0; ks < 4; ++ks) {
        bf16x8 bfr[2];
#pragma unroll
        for (int j = 0; j < 2; ++j)
            bfr[j] = ld_swz(HID, 16 * (2 * w + j) + (l & 15), ks * 4 + (l >> 4));
#pragma unroll
        for (int mt = 0; mt < 2; ++mt) {
            bf16x8 a = ld_swz(Wl, 16 * mt + (l & 15), ks * 4 + (l >> 4));
#pragma unroll
            for (int j = 0; j < 2; ++j) acc3[mt][j] = MFMA(a, bfr[j], acc3[mt][j]);
        }
    }
#pragma unroll
    for (int mt = 0; mt < 2; ++mt) {
        int c0 = 16 * mt + ((l >> 4) << 2);
#pragma unroll
        for (int j = 0; j < 2; ++j) {
            int e = eb + 16 * (2 * w + j) + (l & 15);
            if (e < E) {
#pragma unroll
                for (int q = 0; q < 4; ++q) {
                    int c = c0 + q;
                    if (c < 20) out20[(size_t)e * 20 + c] = acc3[mt][j][q] + b3[c];
                }
            }
        }
    }
}

// ---------------------------------------------------------------------------
// CSR build + gather-sum aggregation
// ---------------------------------------------------------------------------
__global__ void csr_count(const int* __restrict__ edge, int* __restrict__ cnt, int M) {
    int e = blockIdx.x * 256 + threadIdx.x;
    if (e < M) atomicAdd(&cnt[edge[2 * (size_t)e + 1]], 1);
}

__global__ void csr_scan(const int* __restrict__ cnt, int* __restrict__ rowptr,
                         int* __restrict__ wofs, int N)
{
    __shared__ int part[1024];
    int t = threadIdx.x;
    int chunk = (N + 1023) / 1024;
    int b0 = t * chunk, b1 = b0 + chunk; if (b1 > N) b1 = N; if (b0 > N) b0 = N;
    int s = 0;
    for (int i = b0; i < b1; ++i) s += cnt[i];
    part[t] = s;
    __syncthreads();
    for (int off = 1; off < 1024; off <<= 1) {
        int v = (t >= off) ? part[t - off] : 0;
        __syncthreads();
        part[t] += v;
        __syncthreads();
    }
    int run = (t ? part[t - 1] : 0);
    for (int i = b0; i < b1; ++i) { rowptr[i] = run; wofs[i] = run; run += cnt[i]; }
    if (t == 1023) rowptr[N] = run;
}

__global__ void csr_scatter(const int* __restrict__ edge, int* __restrict__ wofs,
                            int* __restrict__ eidx, int M)
{
    int e = blockIdx.x * 256 + threadIdx.x;
    if (e < M) { int p = atomicAdd(&wofs[edge[2 * (size_t)e + 1]], 1); eidx[p] = e; }
}

__global__ __launch_bounds__(256)
void agg_gather(const short* __restrict__ msgatt, const int* __restrict__ rowptr,
                const int* __restrict__ eidx, float* __restrict__ agg, int N)
{
    int v = (blockIdx.x * 256 + threadIdx.x) >> 6;
    int l = threadIdx.x & 63;
    if (v >= N) return;
    int b = rowptr[v], e = rowptr[v + 1];
    float sx = 0.f, sy = 0.f;
    for (int i = b; i < e; ++i) {
        unsigned int u = *(const unsigned int*)(msgatt + (size_t)eidx[i] * 128 + 2 * l);
        sx += bf2f((unsigned short)(u & 0xffffu));
        sy += bf2f((unsigned short)(u >> 16));
    }
    *(float2*)&agg[(size_t)v * 128 + 2 * l] = make_float2(sx, sy);
}

// ---------------------------------------------------------------------------
// GRU gates: gi/gh bf16 (N x 384). One thread = 8 cols.
// ---------------------------------------------------------------------------
__global__ void gru_gates(const short* __restrict__ gi, const short* __restrict__ gh,
                          const short* __restrict__ sUse,
                          short* __restrict__ sPost, short* __restrict__ sNext, int N)
{
    long i = (long)blockIdx.x * 256 + threadIdx.x;
    if (i >= (long)N * 16) return;
    int n = (int)(i >> 4), c = (int)(i & 15) * 8;
    const short* gir = gi + (size_t)n * 384 + c;
    const short* ghr = gh + (size_t)n * 384 + c;
    s16x8 ir = *(const s16x8*)gir, iz = *(const s16x8*)(gir + 128), in_ = *(const s16x8*)(gir + 256);
    s16x8 hr = *(const s16x8*)ghr, hz = *(const s16x8*)(ghr + 128), hn = *(const s16x8*)(ghr + 256);
    s16x8 sv = *(const s16x8*)(sUse + (size_t)n * 128 + c);
    s16x8 po, ne;
#pragma unroll
    for (int j = 0; j < 8; ++j) {
        float s = bf2f((unsigned short)sv[j]);
        float r = 1.f / (1.f + expf(-(bf2f((unsigned short)ir[j]) + bf2f((unsigned short)hr[j]))));
        float z = 1.f / (1.f + expf(-(bf2f((unsigned short)iz[j]) + bf2f((unsigned short)hz[j]))));
        float nn = tanhf(bf2f((unsigned short)in_[j]) + r * bf2f((unsigned short)hn[j]));
        float o = (1.f - z) * nn + z * s;
        po[j] = f2bf(o);
        ne[j] = f2bf(fmaxf(o, 0.f));
    }
    *(s16x8*)(sPost + (size_t)n * 128 + c) = po;
    *(s16x8*)(sNext + (size_t)n * 128 + c) = ne;
}

__global__ void cvt_bf16(const float* __restrict__ in, short* __restrict__ out, long n8) {
    long i = (long)blockIdx.x * 256 + threadIdx.x;
    if (i >= n8) return;
    float4 a = *(const float4*)(in + i * 8), b = *(const float4*)(in + i * 8 + 4);
    s16x8 s;
    s[0] = f2bf(a.x); s[1] = f2bf(a.y); s[2] = f2bf(a.z); s[3] = f2bf(a.w);
    s[4] = f2bf(b.x); s[5] = f2bf(b.y); s[6] = f2bf(b.z); s[7] = f2bf(b.w);
    *(s16x8*)(out + i * 8) = s;
}

__global__ void d2_gather(const short* __restrict__ s, const int* __restrict__ gidx,
                          short* __restrict__ d2, int E)
{
    long i = (long)blockIdx.x * 256 + threadIdx.x;
    if (i >= (long)E * 16) return;
    int e = (int)(i >> 4), u = (int)(i & 15);
    int2 ab = *(const int2*)&gidx[2 * (size_t)e];
    s16x8 x = *(const s16x8*)(s + (size_t)ab.x * 128 + u * 8);
    s16x8 y = *(const s16x8*)(s + (size_t)ab.y * 128 + u * 8);
    s16x8 r;
#pragma unroll
    for (int j = 0; j < 8; ++j)
        r[j] = f2bf(bf2f((unsigned short)x[j]) - bf2f((unsigned short)y[j]));
    *(s16x8*)(d2 + (size_t)e * 128 + u * 8) = r;
}

// ---------------------------------------------------------------------------
// Loss accumulation + final reduction (fp32)
// ---------------------------------------------------------------------------
__global__ __launch_bounds__(256)
void loss_kernel(const float* __restrict__ lt, const float* __restrict__ la,
                 const float* __restrict__ label, const int* __restrict__ sg,
                 float* __restrict__ radj, float* __restrict__ rla,
                 float* __restrict__ cnt, int E, int S)
{
    __shared__ float sadj[4][20];
    __shared__ float sla[4][20];
    __shared__ float scnt[4];
    __shared__ int sbase;
    const int tid = threadIdx.x;
    const int e = blockIdx.x * 256 + tid;
    if (tid == 0) sbase = sg[blockIdx.x * 256];
    if (tid < 80) { sadj[tid / 20][tid % 20] = 0.f; sla[tid / 20][tid % 20] = 0.f; }
    if (tid < 4) scnt[tid] = 0.f;
    __syncthreads();
    if (e < E) {
        int s = sg[e];
        int ls = s - sbase;
        bool local = (ls >= 0 && ls < 4);
        float y = label[e];
        if (local) atomicAdd(&scnt[ls], 1.f); else atomicAdd(&cnt[s], 1.f);
#pragma unroll
        for (int k = 0; k < 20; ++k) {
            float t = lt[(size_t)e * 20 + k];
            float sp = fmaxf(-t, 0.f) + log1pf(expf(-fabsf(t)));
            float adj = sp + (1.f - y) * t;
            float lav = la[(size_t)e * 20 + k];
            if (local) { atomicAdd(&sadj[ls][k], adj); atomicAdd(&sla[ls][k], lav); }
            else       { atomicAdd(&radj[s * 20 + k], adj); atomicAdd(&rla[s * 20 + k], lav); }
        }
    }
    __syncthreads();
    if (tid < 80) {
        int ls = tid / 20, k = tid % 20;
        int s = sbase + ls;
        if (s < S) {
            float v = sadj[ls][k], v2 = sla[ls][k];
            if (v  != 0.f) atomicAdd(&radj[s * 20 + k], v);
            if (v2 != 0.f) atomicAdd(&rla[s * 20 + k], v2);
        }
    }
    if (tid < 4) {
        int s = sbase + tid;
        if (s < S && scnt[tid] != 0.f) atomicAdd(&cnt[s], scnt[tid]);
    }
}

__global__ void final_kernel(const float* __restrict__ radj, const float* __restrict__ rla,
                             const float* __restrict__ cnt, const int* __restrict__ bc_idx,
                             float* __restrict__ out)
{
    __shared__ float bcl[16], bcc[16];
    const int s = threadIdx.x;
    if (s < 16) { bcl[s] = 0.f; bcc[s] = 0.f; }
    __syncthreads();
    float c = cnt[s];
    float x[20];
    float mx = -1e30f;
#pragma unroll
    for (int k = 0; k < 20; ++k) { x[k] = rla[s * 20 + k] / c; mx = fmaxf(mx, x[k]); }
    float se = 0.f;
#pragma unroll
    for (int k = 0; k < 20; ++k) se += expf(x[k] - mx);
    float lse = mx + logf(se);
    float t[20];
    float m2 = -1e30f;
#pragma unroll
    for (int k = 0; k < 20; ++k) { t[k] = -radj[s * 20 + k] + x[k] - lse; m2 = fmaxf(m2, t[k]); }
    float s2 = 0.f;
#pragma unroll
    for (int k = 0; k < 20; ++k) s2 += expf(t[k] - m2);
    float lp = m2 + logf(s2);
    atomicAdd(&bcl[bc_idx[s]], lp);
    atomicAdd(&bcc[bc_idx[s]], c);
    __syncthreads();
    if (s == 0) {
        float a = 0.f;
        for (int b = 0; b < 16; ++b) a += bcl[b] / bcc[b];
        out[0] = -a / 16.f;
    }
}

// ---------------------------------------------------------------------------
extern "C" void kernel_launch(void* const* d_in, const int* in_sizes, int n_in,
                              void* d_out, int out_size, void* d_ws, size_t ws_size,
                              hipStream_t stream)
{
    const float* node_feat = (const float*)d_in[0];
    const int*   edge      = (const int*)  d_in[1];
    const float* edge_feat = (const float*)d_in[2];
    const int*   gnn_idx   = (const int*)  d_in[3];
    const float* label     = (const float*)d_in[4];
    const int*   sg_idx    = (const int*)  d_in[5];
    const int*   bc_idx    = (const int*)  d_in[6];
    const float* dec_W  = (const float*)d_in[7];
    const float* dec_b  = (const float*)d_in[8];
    const float* msg_W1 = (const float*)d_in[9];
    const float* msg_b1 = (const float*)d_in[10];
    const float* msg_W2 = (const float*)d_in[11];
    const float* msg_b2 = (const float*)d_in[12];
    const float* att_W1 = (const float*)d_in[13];
    const float* att_b1 = (const float*)d_in[14];
    const float* att_W2 = (const float*)d_in[15];
    const float* att_b2 = (const float*)d_in[16];
    const float* gru_Wih = (const float*)d_in[17];
    const float* gru_bih = (const float*)d_in[18];
    const float* gru_Whh = (const float*)d_in[19];
    const float* gru_bhh = (const float*)d_in[20];
    const float* th_W1 = (const float*)d_in[21];
    const float* th_b1 = (const float*)d_in[22];
    const float* th_W2 = (const float*)d_in[23];
    const float* th_b2 = (const float*)d_in[24];
    const float* th_W3 = (const float*)d_in[25];
    const float* th_b3 = (const float*)d_in[26];
    const float* al_W1 = (const float*)d_in[27];
    const float* al_b1 = (const float*)d_in[28];
    const float* al_W2 = (const float*)d_in[29];
    const float* al_b2 = (const float*)d_in[30];
    const float* al_W3 = (const float*)d_in[31];
    const float* al_b3 = (const float*)d_in[32];

    const int N = in_sizes[0] / 512;
    const int M = in_sizes[1] / 2;
    const int E = in_sizes[3] / 2;
    const int S = in_sizes[6];

    // ---- workspace (256B-aligned slabs) ----
    size_t off = 0;
    auto alloc = [&](size_t bytes) {
        char* p = (char*)d_ws + off;
        off += (bytes + 255) & ~(size_t)255;
        return p;
    };
    short* sA     = (short*)alloc((size_t)N * 128 * 2);
    short* sB     = (short*)alloc((size_t)N * 128 * 2);
    short* sP     = (short*)alloc((size_t)N * 128 * 2);
    short* efb    = (short*)alloc((size_t)M * 128 * 2);
    short* msgatt = (short*)alloc((size_t)M * 128 * 2);
    short* projm  = (short*)alloc((size_t)N * 128 * 2);
    short* proja  = (short*)alloc((size_t)N * 128 * 2);
    float* agg    = (float*)alloc((size_t)N * 128 * 4);
    short* gi     = (short*)alloc((size_t)N * 384 * 2);
    short* gh     = (short*)alloc((size_t)N * 384 * 2);
    int*   cntN   = (int*)  alloc((size_t)N * 4);
    int*   wofs   = (int*)  alloc((size_t)N * 4);
    int*   rowptr = (int*)  alloc((size_t)(N + 1) * 4);
    int*   eidx   = (int*)  alloc((size_t)M * 4);
    float* radj   = (float*)alloc((size_t)S * 20 * 4);
    float* rla    = (float*)alloc((size_t)S * 20 * 4);
    float* cntS   = (float*)alloc((size_t)S * 4);
    // overlays (provably dead regions by the time they're used):
    short* d2 = gi;                    // E*128*2 = 51.2MB <= gi+gh (76.8MB), dead after GRU
    float* lt = (float*)efb;           // E*20*4 = 16MB  ┐ efb (64MB) dead after layer 3
    float* la = (float*)efb + (size_t)E * 20;  //  16MB  ┘

    const dim3 blk(256);
    const int gN  = (N + 127) / 128;
    const int gM  = (M + 127) / 128;
    const int gE  = (E + 127) / 128;
    const int gMt = (M + 255) / 256;
    const int gEl = (E + 255) / 256;

    hipMemsetAsync(radj, 0, (size_t)(S * 20 * 2 + S) * 4, stream);
    hipMemsetAsync(cntN, 0, (size_t)N * 4, stream);

    csr_count  <<<gMt, blk, 0, stream>>>(edge, cntN, M);
    csr_scan   <<<1, 1024, 0, stream>>>(cntN, rowptr, wofs, N);
    csr_scatter<<<gMt, blk, 0, stream>>>(edge, wofs, eidx, M);

    cvt_bf16<<<(int)(((long)M * 16 + 255) / 256), blk, 0, stream>>>(edge_feat, efb, (long)M * 16);

    // decoder: state = node_feat @ dec_W^T + dec_b
    mm_t<1><<<gN, blk, 0, stream>>>(node_feat, 512, N, dec_W, 512, 512, dec_b, sA, 128, 1);

    short* bufs[2] = { sA, sB };
    for (int l = 0; l < 3; ++l) {
        short* sin  = bufs[l & 1];
        short* snxt = bufs[(l + 1) & 1];
        mm_t<0><<<gN, blk, 0, stream>>>(sin, 128, N, msg_W1 + (size_t)l * 128 * 256, 256, 128,
                                        nullptr, projm, 128, 1);
        mm_t<0><<<gN, blk, 0, stream>>>(sin, 128, N, att_W1 + (size_t)l * 128 * 256, 256, 128,
                                        nullptr, proja, 128, 1);
        edge_fused<<<gM, blk, 0, stream>>>(efb, edge, projm, proja,
            msg_W1 + (size_t)l * 128 * 256 + 128, msg_b1 + l * 128,
            msg_W2 + (size_t)l * 128 * 128,       msg_b2 + l * 128,
            att_W1 + (size_t)l * 128 * 256 + 128, att_b1 + l * 128,
            att_W2 + (size_t)l * 128 * 128,       att_b2 + l * 128,
            msgatt, M);
        agg_gather<<<(N * 64 + 255) / 256, blk, 0, stream>>>(msgatt, rowptr, eidx, agg, N);
        mm_t<1><<<gN, blk, 0, stream>>>(agg, 128, N, gru_Wih + (size_t)l * 384 * 128, 128, 128,
                                        gru_bih + l * 384, gi, 384, 3);
        mm_t<0><<<gN, blk, 0, stream>>>(sin, 128, N, gru_Whh + (size_t)l * 384 * 128, 128, 128,
                                        gru_bhh + l * 384, gh, 384, 3);
        gru_gates<<<(int)(((long)N * 16 + 255) / 256), blk, 0, stream>>>(gi, gh, sin, sP, snxt, N);
    }

    d2_gather<<<(int)(((long)E * 16 + 255) / 256), blk, 0, stream>>>(sP, gnn_idx, d2, E);

    mlp3_fused<<<gE, blk, 0, stream>>>(d2, th_W1, th_b1, th_W2, th_b2, th_W3, th_b3, lt, E);
    mlp3_fused<<<gE, blk, 0, stream>>>(d2, al_W1, al_b1, al_W2, al_b2, al_W3, al_b3, la, E);

    loss_kernel<<<gEl, blk, 0, stream>>>(lt, la, label, sg_idx, radj, rla, cntS, E, S);
    final_kernel<<<1, S, 0, stream>>>(radj, rla, cntS, bc_idx, (float*)d_out);
}

// Round 4
// 1535.864 us; speedup vs baseline: 8.4833x; 1.4439x over previous
//
#include <hip/hip_runtime.h>
#include <cstdint>
#include <cstddef>

// GRAN mixture-Bernoulli forward — R4: direct-from-global bf16 weights
// (prepacked once), CSR-ordered edge processing, small-LDS high-occupancy
// kernels. Sizes: N=50000, M=250000, E=200000, H=EF=ATT=128, K=20, L=3, S=512.

typedef __bf16 bf16x8 __attribute__((ext_vector_type(8)));
typedef short  s16x8  __attribute__((ext_vector_type(8)));
typedef short  s16x4  __attribute__((ext_vector_type(4)));
typedef float  f32x4  __attribute__((ext_vector_type(4)));

__device__ inline unsigned short f2bf(float f) {
    unsigned int u = __float_as_uint(f);
    u += 0x7FFFu + ((u >> 16) & 1u);
    return (unsigned short)(u >> 16);
}
__device__ inline float bf2f(unsigned short b) {
    return __uint_as_float(((unsigned int)b) << 16);
}
__device__ inline f32x4 MFMA(bf16x8 a, bf16x8 b, f32x4 c) {
    return __builtin_amdgcn_mfma_f32_16x16x32_bf16(a, b, c, 0, 0, 0);
}

// Swizzled LDS tile: [rows][128 bf16] = 256B/row, 16B unit u stored at u^(row&7).
__device__ inline bf16x8 ld_swz(const char* lds, int row, int unit) {
    return *(const bf16x8*)(lds + row * 256 + ((unit ^ (row & 7)) << 4));
}
__device__ inline void hid_write(char* HID, int h0, int erow, s16x4 s4) {
    int unit = h0 >> 3;
    *(s16x4*)(HID + erow * 256 + ((unit ^ (erow & 7)) << 4) + ((h0 & 4) << 1)) = s4;
}

// Direct-from-global weight A-fragment (bf16 [out][K] row-major).
__device__ inline bf16x8 ldA(const short* __restrict__ Wb, int K, int row, int koff) {
    return *(const bf16x8*)(Wb + (size_t)row * K + koff);
}

__device__ inline bf16x8 ld_f32_frag(const float* __restrict__ p) {
    float4 a = *(const float4*)p, b = *(const float4*)(p + 4);
    s16x8 s;
    s[0] = f2bf(a.x); s[1] = f2bf(a.y); s[2] = f2bf(a.z); s[3] = f2bf(a.w);
    s[4] = f2bf(b.x); s[5] = f2bf(b.y); s[6] = f2bf(b.z); s[7] = f2bf(b.w);
    return __builtin_bit_cast(bf16x8, s);
}

// ---------------------------------------------------------------------------
// Weight prepack: fp32 [rows][srcStride] -> bf16 [rowsTot][cols] (zero-pad).
// ---------------------------------------------------------------------------
#define NPACK 31
struct PrepackArgs {
    const float* src[NPACK];
    short*       dst[NPACK];
    int stride[NPACK];
    int rows[NPACK];
    int rowsTot[NPACK];
    int cols[NPACK];
};

__global__ void prepack(PrepackArgs a) {
    int e = blockIdx.y;
    int row = blockIdx.x;
    if (row >= a.rowsTot[e]) return;
    int c8 = threadIdx.x;
    if (c8 * 8 >= a.cols[e]) return;
    s16x8 s = {};
    if (row < a.rows[e]) {
        const float* p = a.src[e] + (size_t)row * a.stride[e] + c8 * 8;
        float4 x = *(const float4*)p, y = *(const float4*)(p + 4);
        s[0] = f2bf(x.x); s[1] = f2bf(x.y); s[2] = f2bf(x.z); s[3] = f2bf(x.w);
        s[4] = f2bf(y.x); s[5] = f2bf(y.y); s[6] = f2bf(y.z); s[7] = f2bf(y.w);
    }
    *(s16x8*)(a.dst[e] + (size_t)row * a.cols[e] + c8 * 8) = s;
}

// ---------------------------------------------------------------------------
// Transposed GEMM, direct global bf16 weights: Out[r][c] = B[r][:].W[c][:]+bias.
// 128 rows/block; LDS only for the 32KB output repack tile.
// ---------------------------------------------------------------------------
template<int B_FP32>
__global__ __launch_bounds__(256, 4)
void mm_bf(const void* __restrict__ Bact, int ldb, int R,
           const short* __restrict__ Wb, int K,
           const float* __restrict__ bias,
           short* __restrict__ Out, int ostride, int nchunk)
{
    __shared__ char RP[32768];
    const int tid = threadIdx.x, l = tid & 63, w = tid >> 6;
    const int rb = blockIdx.x * 128;

    const char* brow[8];
#pragma unroll
    for (int n = 0; n < 8; ++n) {
        int row = rb + 16 * n + (l & 15); if (row >= R) row = R - 1;
        brow[n] = (const char*)Bact + (size_t)row * ldb * (B_FP32 ? 4 : 2);
    }

    for (int p = 0; p < nchunk; ++p) {
        f32x4 acc[2][8] = {};
        for (int kc = 0; kc < K; kc += 128) {
#pragma unroll
            for (int ks = 0; ks < 4; ++ks) {
                int koff = kc + ks * 32 + (l >> 4) * 8;
                bf16x8 a0 = ldA(Wb, K, p * 128 + 32 * w + (l & 15), koff);
                bf16x8 a1 = ldA(Wb, K, p * 128 + 32 * w + 16 + (l & 15), koff);
#pragma unroll
                for (int n = 0; n < 8; ++n) {
                    bf16x8 b;
                    if (B_FP32) b = ld_f32_frag((const float*)(brow[n] + koff * 4));
                    else        b = *(const bf16x8*)(brow[n] + koff * 2);
                    acc[0][n] = MFMA(a0, b, acc[0][n]);
                    acc[1][n] = MFMA(a1, b, acc[1][n]);
                }
            }
        }
        __syncthreads();            // prior repack-tile readers done
#pragma unroll
        for (int mt = 0; mt < 2; ++mt) {
            int c0 = 32 * w + 16 * mt + ((l >> 4) << 2);
            float4 bv = make_float4(0.f, 0.f, 0.f, 0.f);
            if (bias) bv = *(const float4*)&bias[p * 128 + c0];
#pragma unroll
            for (int n = 0; n < 8; ++n) {
                f32x4 v = acc[mt][n];
                s16x4 s4;
                s4[0] = f2bf(v[0] + bv.x); s4[1] = f2bf(v[1] + bv.y);
                s4[2] = f2bf(v[2] + bv.z); s4[3] = f2bf(v[3] + bv.w);
                hid_write(RP, c0, 16 * n + (l & 15), s4);
            }
        }
        __syncthreads();
#pragma unroll
        for (int p2 = 0; p2 < 8; ++p2) {
            int row = p2 * 16 + (tid >> 4);
            int r = rb + row;
            if (r < R) {
                bf16x8 v = ld_swz(RP, row, tid & 15);
                *(s16x8*)(Out + (size_t)r * ostride + p * 128 + (tid & 15) * 8) =
                    __builtin_bit_cast(s16x8, v);
            }
        }
    }
}

// ---------------------------------------------------------------------------
// Fused edge MLPs, CSR order, msg+att combined GEMMs, 64 edges/block.
//   hid_{m,a} = relu(efc@W1b^T + proj[src]-proj[dst] + b1)
//   msgatt = (hid_m@mW2^T + mb2) * sigmoid(hid_a@aW2^T + ab2)
// ---------------------------------------------------------------------------
__global__ __launch_bounds__(256, 4)
void edge_fused2(const short* __restrict__ efc,
                 const int* __restrict__ srcs, const int* __restrict__ dsts,
                 const short* __restrict__ proj,    // N x 256: [0:128) msg, [128:256) att
                 const short* __restrict__ mW1b, const short* __restrict__ mW2,
                 const short* __restrict__ aW1b, const short* __restrict__ aW2,
                 const float* __restrict__ mb1, const float* __restrict__ mb2,
                 const float* __restrict__ ab1, const float* __restrict__ ab2,
                 short* __restrict__ msgatt, int M, int ntiles)
{
    __shared__ char HIDm[16384];
    __shared__ char HIDa[16384];
    const int tid = threadIdx.x, l = tid & 63, w = tid >> 6;
    // bijective XCD-aware swizzle: consecutive tiles (sorted dst) share L2
    int q = ntiles >> 3, r = ntiles & 7;
    int xcd = blockIdx.x & 7, o = blockIdx.x >> 3;
    int tile = (xcd < r ? xcd * (q + 1) : r * (q + 1) + (xcd - r) * q) + o;
    const int pb = tile * 64;

    int srcv[4], dstv[4];
    const char* erow[4];
#pragma unroll
    for (int n = 0; n < 4; ++n) {
        int pos = pb + 16 * n + (l & 15); if (pos >= M) pos = M - 1;
        srcv[n] = srcs[pos]; dstv[n] = dsts[pos];
        erow[n] = (const char*)(efc + (size_t)pos * 128);
    }

    // GEMM1 combined
    f32x4 accm[2][4] = {}, acca[2][4] = {};
#pragma unroll
    for (int ks = 0; ks < 4; ++ks) {
        int koff = ks * 32 + (l >> 4) * 8;
        bf16x8 am0 = ldA(mW1b, 128, 32 * w + (l & 15), koff);
        bf16x8 am1 = ldA(mW1b, 128, 32 * w + 16 + (l & 15), koff);
        bf16x8 aa0 = ldA(aW1b, 128, 32 * w + (l & 15), koff);
        bf16x8 aa1 = ldA(aW1b, 128, 32 * w + 16 + (l & 15), koff);
#pragma unroll
        for (int n = 0; n < 4; ++n) {
            bf16x8 b = *(const bf16x8*)(erow[n] + koff * 2);
            accm[0][n] = MFMA(am0, b, accm[0][n]);
            accm[1][n] = MFMA(am1, b, accm[1][n]);
            acca[0][n] = MFMA(aa0, b, acca[0][n]);
            acca[1][n] = MFMA(aa1, b, acca[1][n]);
        }
    }
    // epilogue 1: bias + proj diff (bf16 gathers), relu -> HID tiles
#pragma unroll
    for (int mt = 0; mt < 2; ++mt) {
        int h0 = 32 * w + 16 * mt + ((l >> 4) << 2);
        float4 bm = *(const float4*)&mb1[h0];
        float4 ba = *(const float4*)&ab1[h0];
#pragma unroll
        for (int n = 0; n < 4; ++n) {
            const short* ps = proj + (size_t)srcv[n] * 256;
            const short* pd = proj + (size_t)dstv[n] * 256;
            s16x4 psm = *(const s16x4*)(ps + h0),      pdm = *(const s16x4*)(pd + h0);
            s16x4 psa = *(const s16x4*)(ps + 128 + h0), pda = *(const s16x4*)(pd + 128 + h0);
            f32x4 vm = accm[mt][n], va = acca[mt][n];
            vm[0] += bm.x + bf2f((unsigned short)psm[0]) - bf2f((unsigned short)pdm[0]);
            vm[1] += bm.y + bf2f((unsigned short)psm[1]) - bf2f((unsigned short)pdm[1]);
            vm[2] += bm.z + bf2f((unsigned short)psm[2]) - bf2f((unsigned short)pdm[2]);
            vm[3] += bm.w + bf2f((unsigned short)psm[3]) - bf2f((unsigned short)pdm[3]);
            va[0] += ba.x + bf2f((unsigned short)psa[0]) - bf2f((unsigned short)pda[0]);
            va[1] += ba.y + bf2f((unsigned short)psa[1]) - bf2f((unsigned short)pda[1]);
            va[2] += ba.z + bf2f((unsigned short)psa[2]) - bf2f((unsigned short)pda[2]);
            va[3] += ba.w + bf2f((unsigned short)psa[3]) - bf2f((unsigned short)pda[3]);
            s16x4 sm, sa;
            sm[0] = f2bf(fmaxf(vm[0], 0.f)); sm[1] = f2bf(fmaxf(vm[1], 0.f));
            sm[2] = f2bf(fmaxf(vm[2], 0.f)); sm[3] = f2bf(fmaxf(vm[3], 0.f));
            sa[0] = f2bf(fmaxf(va[0], 0.f)); sa[1] = f2bf(fmaxf(va[1], 0.f));
            sa[2] = f2bf(fmaxf(va[2], 0.f)); sa[3] = f2bf(fmaxf(va[3], 0.f));
            hid_write(HIDm, h0, 16 * n + (l & 15), sm);
            hid_write(HIDa, h0, 16 * n + (l & 15), sa);
        }
    }
    __syncthreads();

    // GEMM2 combined
    f32x4 acc2m[2][4] = {}, acc2a[2][4] = {};
#pragma unroll
    for (int ks = 0; ks < 4; ++ks) {
        int koff = ks * 32 + (l >> 4) * 8;
        bf16x8 wm0 = ldA(mW2, 128, 32 * w + (l & 15), koff);
        bf16x8 wm1 = ldA(mW2, 128, 32 * w + 16 + (l & 15), koff);
        bf16x8 wa0 = ldA(aW2, 128, 32 * w + (l & 15), koff);
        bf16x8 wa1 = ldA(aW2, 128, 32 * w + 16 + (l & 15), koff);
#pragma unroll
        for (int n = 0; n < 4; ++n) {
            bf16x8 bm = ld_swz(HIDm, 16 * n + (l & 15), ks * 4 + (l >> 4));
            bf16x8 ba = ld_swz(HIDa, 16 * n + (l & 15), ks * 4 + (l >> 4));
            acc2m[0][n] = MFMA(wm0, bm, acc2m[0][n]);
            acc2m[1][n] = MFMA(wm1, bm, acc2m[1][n]);
            acc2a[0][n] = MFMA(wa0, ba, acc2a[0][n]);
            acc2a[1][n] = MFMA(wa1, ba, acc2a[1][n]);
        }
    }
    __syncthreads();                // HID reads done; reuse HIDm for output
    // epilogue 2: o = (msg+b2) * sigmoid(att+b2)
#pragma unroll
    for (int mt = 0; mt < 2; ++mt) {
        int c0 = 32 * w + 16 * mt + ((l >> 4) << 2);
        float4 bm2 = *(const float4*)&mb2[c0];
        float4 ba2 = *(const float4*)&ab2[c0];
#pragma unroll
        for (int n = 0; n < 4; ++n) {
            f32x4 m_ = acc2m[mt][n], a_ = acc2a[mt][n];
            float o0 = (m_[0] + bm2.x) / (1.f + expf(-(a_[0] + ba2.x)));
            float o1 = (m_[1] + bm2.y) / (1.f + expf(-(a_[1] + ba2.y)));
            float o2 = (m_[2] + bm2.z) / (1.f + expf(-(a_[2] + ba2.z)));
            float o3 = (m_[3] + bm2.w) / (1.f + expf(-(a_[3] + ba2.w)));
            s16x4 s4;
            s4[0] = f2bf(o0); s4[1] = f2bf(o1); s4[2] = f2bf(o2); s4[3] = f2bf(o3);
            hid_write(HIDm, c0, 16 * n + (l & 15), s4);
        }
    }
    __syncthreads();
    // coalesced store (CSR position order)
#pragma unroll
    for (int p2 = 0; p2 < 4; ++p2) {
        int row = p2 * 16 + (tid >> 4);
        int pos = pb + row;
        if (pos < M) {
            bf16x8 v = ld_swz(HIDm, row, tid & 15);
            *(s16x8*)(msgatt + (size_t)pos * 128 + (tid & 15) * 8) =
                __builtin_bit_cast(s16x8, v);
        }
    }
}

// ---------------------------------------------------------------------------
// Fused 3-layer output MLP: d2 -> relu W1 -> relu W2 -> W3 (20 outs, padded 32)
// ---------------------------------------------------------------------------
__global__ __launch_bounds__(256, 4)
void mlp3_fused2(const short* __restrict__ d2,
                 const short* __restrict__ W1b, const short* __restrict__ W2b,
                 const short* __restrict__ W3b,
                 const float* __restrict__ b1, const float* __restrict__ b2,
                 const float* __restrict__ b3,
                 float* __restrict__ out20, int E)
{
    __shared__ char HID[32768];
    const int tid = threadIdx.x, l = tid & 63, w = tid >> 6;
    const int eb = blockIdx.x * 128;

    const char* erow[8];
#pragma unroll
    for (int n = 0; n < 8; ++n) {
        int e = eb + 16 * n + (l & 15); if (e >= E) e = E - 1;
        erow[n] = (const char*)(d2 + (size_t)e * 128);
    }
    {
        f32x4 acc[2][8] = {};
#pragma unroll
        for (int ks = 0; ks < 4; ++ks) {
            int koff = ks * 32 + (l >> 4) * 8;
            bf16x8 a0 = ldA(W1b, 128, 32 * w + (l & 15), koff);
            bf16x8 a1 = ldA(W1b, 128, 32 * w + 16 + (l & 15), koff);
#pragma unroll
            for (int n = 0; n < 8; ++n) {
                bf16x8 b = *(const bf16x8*)(erow[n] + koff * 2);
                acc[0][n] = MFMA(a0, b, acc[0][n]);
                acc[1][n] = MFMA(a1, b, acc[1][n]);
            }
        }
#pragma unroll
        for (int mt = 0; mt < 2; ++mt) {
            int h0 = 32 * w + 16 * mt + ((l >> 4) << 2);
            float4 bv = *(const float4*)&b1[h0];
#pragma unroll
            for (int n = 0; n < 8; ++n) {
                f32x4 v = acc[mt][n];
                s16x4 s4;
                s4[0] = f2bf(fmaxf(v[0] + bv.x, 0.f));
                s4[1] = f2bf(fmaxf(v[1] + bv.y, 0.f));
                s4[2] = f2bf(fmaxf(v[2] + bv.z, 0.f));
                s4[3] = f2bf(fmaxf(v[3] + bv.w, 0.f));
                hid_write(HID, h0, 16 * n + (l & 15), s4);
            }
        }
    }
    __syncthreads();
    f32x4 acc2[2][8] = {};
#pragma unroll
    for (int ks = 0; ks < 4; ++ks) {
        int koff = ks * 32 + (l >> 4) * 8;
        bf16x8 a0 = ldA(W2b, 128, 32 * w + (l & 15), koff);
        bf16x8 a1 = ldA(W2b, 128, 32 * w + 16 + (l & 15), koff);
#pragma unroll
        for (int n = 0; n < 8; ++n) {
            bf16x8 b = ld_swz(HID, 16 * n + (l & 15), ks * 4 + (l >> 4));
            acc2[0][n] = MFMA(a0, b, acc2[0][n]);
            acc2[1][n] = MFMA(a1, b, acc2[1][n]);
        }
    }
    __syncthreads();
#pragma unroll
    for (int mt = 0; mt < 2; ++mt) {
        int h0 = 32 * w + 16 * mt + ((l >> 4) << 2);
        float4 bv = *(const float4*)&b2[h0];
#pragma unroll
        for (int n = 0; n < 8; ++n) {
            f32x4 v = acc2[mt][n];
            s16x4 s4;
            s4[0] = f2bf(fmaxf(v[0] + bv.x, 0.f));
            s4[1] = f2bf(fmaxf(v[1] + bv.y, 0.f));
            s4[2] = f2bf(fmaxf(v[2] + bv.z, 0.f));
            s4[3] = f2bf(fmaxf(v[3] + bv.w, 0.f));
            hid_write(HID, h0, 16 * n + (l & 15), s4);
        }
    }
    __syncthreads();
    f32x4 acc3[2][2] = {};
#pragma unroll
    for (int ks = 0; ks < 4; ++ks) {
        int koff = ks * 32 + (l >> 4) * 8;
        bf16x8 a0 = ldA(W3b, 128, (l & 15), koff);
        bf16x8 a1 = ldA(W3b, 128, 16 + (l & 15), koff);
#pragma unroll
        for (int j = 0; j < 2; ++j) {
            bf16x8 b = ld_swz(HID, 16 * (2 * w + j) + (l & 15), ks * 4 + (l >> 4));
            acc3[0][j] = MFMA(a0, b, acc3[0][j]);
            acc3[1][j] = MFMA(a1, b, acc3[1][j]);
        }
    }
#pragma unroll
    for (int mt = 0; mt < 2; ++mt) {
        int c0 = 16 * mt + ((l >> 4) << 2);
#pragma unroll
        for (int j = 0; j < 2; ++j) {
            int e = eb + 16 * (2 * w + j) + (l & 15);
            if (e < E) {
#pragma unroll
                for (int qq = 0; qq < 4; ++qq) {
                    int c = c0 + qq;
                    if (c < 20) out20[(size_t)e * 20 + c] = acc3[mt][j][qq] + b3[c];
                }
            }
        }
    }
}

// ---------------------------------------------------------------------------
// CSR build + CSR-ordered gathers
// ---------------------------------------------------------------------------
__global__ void csr_count(const int* __restrict__ edge, int* __restrict__ cnt, int M) {
    int e = blockIdx.x * 256 + threadIdx.x;
    if (e < M) atomicAdd(&cnt[edge[2 * (size_t)e + 1]], 1);
}

__global__ void csr_scan(const int* __restrict__ cnt, int* __restrict__ rowptr,
                         int* __restrict__ wofs, int N)
{
    __shared__ int part[1024];
    int t = threadIdx.x;
    int chunk = (N + 1023) / 1024;
    int b0 = t * chunk, b1 = b0 + chunk; if (b1 > N) b1 = N; if (b0 > N) b0 = N;
    int s = 0;
    for (int i = b0; i < b1; ++i) s += cnt[i];
    part[t] = s;
    __syncthreads();
    for (int off = 1; off < 1024; off <<= 1) {
        int v = (t >= off) ? part[t - off] : 0;
        __syncthreads();
        part[t] += v;
        __syncthreads();
    }
    int run = (t ? part[t - 1] : 0);
    for (int i = b0; i < b1; ++i) { rowptr[i] = run; wofs[i] = run; run += cnt[i]; }
    if (t == 1023) rowptr[N] = run;
}

__global__ void csr_scatter2(const int* __restrict__ edge, int* __restrict__ wofs,
                             int* __restrict__ eidx, int* __restrict__ srcs,
                             int* __restrict__ dsts, int M)
{
    int e = blockIdx.x * 256 + threadIdx.x;
    if (e < M) {
        int2 sd = *(const int2*)&edge[2 * (size_t)e];
        int p = atomicAdd(&wofs[sd.y], 1);
        eidx[p] = e; srcs[p] = sd.x; dsts[p] = sd.y;
    }
}

__global__ void ef_gather(const float* __restrict__ ef, const int* __restrict__ eidx,
                          short* __restrict__ efc, int M)
{
    long i = (long)blockIdx.x * 256 + threadIdx.x;
    if (i >= (long)M * 16) return;
    int p = (int)(i >> 4), u = (int)(i & 15);
    int e = eidx[p];
    const float* sp = ef + (size_t)e * 128 + u * 8;
    float4 a = *(const float4*)sp, b = *(const float4*)(sp + 4);
    s16x8 s;
    s[0] = f2bf(a.x); s[1] = f2bf(a.y); s[2] = f2bf(a.z); s[3] = f2bf(a.w);
    s[4] = f2bf(b.x); s[5] = f2bf(b.y); s[6] = f2bf(b.z); s[7] = f2bf(b.w);
    *(s16x8*)(efc + (size_t)p * 128 + u * 8) = s;
}

// Sequential CSR aggregation: agg[v] = sum of msgatt rows rowptr[v]..rowptr[v+1]
__global__ __launch_bounds__(256)
void agg_gather2(const short* __restrict__ msgatt, const int* __restrict__ rowptr,
                 short* __restrict__ aggb, int N)
{
    int v = (blockIdx.x * 256 + threadIdx.x) >> 6;
    int l = threadIdx.x & 63;
    if (v >= N) return;
    int b = rowptr[v], e = rowptr[v + 1];
    float sx = 0.f, sy = 0.f;
    for (int i = b; i < e; ++i) {
        unsigned int u = *(const unsigned int*)(msgatt + (size_t)i * 128 + 2 * l);
        sx += bf2f((unsigned short)(u & 0xffffu));
        sy += bf2f((unsigned short)(u >> 16));
    }
    unsigned int o = ((unsigned int)f2bf(sy) << 16) | f2bf(sx);
    *(unsigned int*)(aggb + (size_t)v * 128 + 2 * l) = o;
}

// ---------------------------------------------------------------------------
__global__ void gru_gates(const short* __restrict__ gi, const short* __restrict__ gh,
                          const short* __restrict__ sUse,
                          short* __restrict__ sPost, short* __restrict__ sNext, int N)
{
    long i = (long)blockIdx.x * 256 + threadIdx.x;
    if (i >= (long)N * 16) return;
    int n = (int)(i >> 4), c = (int)(i & 15) * 8;
    const short* gir = gi + (size_t)n * 384 + c;
    const short* ghr = gh + (size_t)n * 384 + c;
    s16x8 ir = *(const s16x8*)gir, iz = *(const s16x8*)(gir + 128), in_ = *(const s16x8*)(gir + 256);
    s16x8 hr = *(const s16x8*)ghr, hz = *(const s16x8*)(ghr + 128), hn = *(const s16x8*)(ghr + 256);
    s16x8 sv = *(const s16x8*)(sUse + (size_t)n * 128 + c);
    s16x8 po, ne;
#pragma unroll
    for (int j = 0; j < 8; ++j) {
        float s = bf2f((unsigned short)sv[j]);
        float r = 1.f / (1.f + expf(-(bf2f((unsigned short)ir[j]) + bf2f((unsigned short)hr[j]))));
        float z = 1.f / (1.f + expf(-(bf2f((unsigned short)iz[j]) + bf2f((unsigned short)hz[j]))));
        float nn = tanhf(bf2f((unsigned short)in_[j]) + r * bf2f((unsigned short)hn[j]));
        float o = (1.f - z) * nn + z * s;
        po[j] = f2bf(o);
        ne[j] = f2bf(fmaxf(o, 0.f));
    }
    *(s16x8*)(sPost + (size_t)n * 128 + c) = po;
    *(s16x8*)(sNext + (size_t)n * 128 + c) = ne;
}

__global__ void d2_gather(const short* __restrict__ s, const int* __restrict__ gidx,
                          short* __restrict__ d2, int E)
{
    long i = (long)blockIdx.x * 256 + threadIdx.x;
    if (i >= (long)E * 16) return;
    int e = (int)(i >> 4), u = (int)(i & 15);
    int2 ab = *(const int2*)&gidx[2 * (size_t)e];
    s16x8 x = *(const s16x8*)(s + (size_t)ab.x * 128 + u * 8);
    s16x8 y = *(const s16x8*)(s + (size_t)ab.y * 128 + u * 8);
    s16x8 r;
#pragma unroll
    for (int j = 0; j < 8; ++j)
        r[j] = f2bf(bf2f((unsigned short)x[j]) - bf2f((unsigned short)y[j]));
    *(s16x8*)(d2 + (size_t)e * 128 + u * 8) = r;
}

// ---------------------------------------------------------------------------
// Loss accumulation + final reduction (fp32)
// ---------------------------------------------------------------------------
__global__ __launch_bounds__(256)
void loss_kernel(const float* __restrict__ lt, const float* __restrict__ la,
                 const float* __restrict__ label, const int* __restrict__ sg,
                 float* __restrict__ radj, float* __restrict__ rla,
                 float* __restrict__ cnt, int E, int S)
{
    __shared__ float sadj[4][20];
    __shared__ float sla[4][20];
    __shared__ float scnt[4];
    __shared__ int sbase;
    const int tid = threadIdx.x;
    const int e = blockIdx.x * 256 + tid;
    if (tid == 0) sbase = sg[blockIdx.x * 256];
    if (tid < 80) { sadj[tid / 20][tid % 20] = 0.f; sla[tid / 20][tid % 20] = 0.f; }
    if (tid < 4) scnt[tid] = 0.f;
    __syncthreads();
    if (e < E) {
        int s = sg[e];
        int ls = s - sbase;
        bool local = (ls >= 0 && ls < 4);
        float y = label[e];
        if (local) atomicAdd(&scnt[ls], 1.f); else atomicAdd(&cnt[s], 1.f);
#pragma unroll
        for (int k = 0; k < 20; ++k) {
            float t = lt[(size_t)e * 20 + k];
            float sp = fmaxf(-t, 0.f) + log1pf(expf(-fabsf(t)));
            float adj = sp + (1.f - y) * t;
            float lav = la[(size_t)e * 20 + k];
            if (local) { atomicAdd(&sadj[ls][k], adj); atomicAdd(&sla[ls][k], lav); }
            else       { atomicAdd(&radj[s * 20 + k], adj); atomicAdd(&rla[s * 20 + k], lav); }
        }
    }
    __syncthreads();
    if (tid < 80) {
        int ls = tid / 20, k = tid % 20;
        int s = sbase + ls;
        if (s < S) {
            float v = sadj[ls][k], v2 = sla[ls][k];
            if (v  != 0.f) atomicAdd(&radj[s * 20 + k], v);
            if (v2 != 0.f) atomicAdd(&rla[s * 20 + k], v2);
        }
    }
    if (tid < 4) {
        int s = sbase + tid;
        if (s < S && scnt[tid] != 0.f) atomicAdd(&cnt[s], scnt[tid]);
    }
}

__global__ void final_kernel(const float* __restrict__ radj, const float* __restrict__ rla,
                             const float* __restrict__ cnt, const int* __restrict__ bc_idx,
                             float* __restrict__ out)
{
    __shared__ float bcl[16], bcc[16];
    const int s = threadIdx.x;
    if (s < 16) { bcl[s] = 0.f; bcc[s] = 0.f; }
    __syncthreads();
    float c = cnt[s];
    float x[20];
    float mx = -1e30f;
#pragma unroll
    for (int k = 0; k < 20; ++k) { x[k] = rla[s * 20 + k] / c; mx = fmaxf(mx, x[k]); }
    float se = 0.f;
#pragma unroll
    for (int k = 0; k < 20; ++k) se += expf(x[k] - mx);
    float lse = mx + logf(se);
    float t[20];
    float m2 = -1e30f;
#pragma unroll
    for (int k = 0; k < 20; ++k) { t[k] = -radj[s * 20 + k] + x[k] - lse; m2 = fmaxf(m2, t[k]); }
    float s2 = 0.f;
#pragma unroll
    for (int k = 0; k < 20; ++k) s2 += expf(t[k] - m2);
    float lp = m2 + logf(s2);
    atomicAdd(&bcl[bc_idx[s]], lp);
    atomicAdd(&bcc[bc_idx[s]], c);
    __syncthreads();
    if (s == 0) {
        float a = 0.f;
        for (int b = 0; b < 16; ++b) a += bcl[b] / bcc[b];
        out[0] = -a / 16.f;
    }
}

// ---------------------------------------------------------------------------
extern "C" void kernel_launch(void* const* d_in, const int* in_sizes, int n_in,
                              void* d_out, int out_size, void* d_ws, size_t ws_size,
                              hipStream_t stream)
{
    const float* node_feat = (const float*)d_in[0];
    const int*   edge      = (const int*)  d_in[1];
    const float* edge_feat = (const float*)d_in[2];
    const int*   gnn_idx   = (const int*)  d_in[3];
    const float* label     = (const float*)d_in[4];
    const int*   sg_idx    = (const int*)  d_in[5];
    const int*   bc_idx    = (const int*)  d_in[6];
    const float* dec_W  = (const float*)d_in[7];
    const float* dec_b  = (const float*)d_in[8];
    const float* msg_W1 = (const float*)d_in[9];
    const float* msg_b1 = (const float*)d_in[10];
    const float* msg_W2 = (const float*)d_in[11];
    const float* msg_b2 = (const float*)d_in[12];
    const float* att_W1 = (const float*)d_in[13];
    const float* att_b1 = (const float*)d_in[14];
    const float* att_W2 = (const float*)d_in[15];
    const float* att_b2 = (const float*)d_in[16];
    const float* gru_Wih = (const float*)d_in[17];
    const float* gru_bih = (const float*)d_in[18];
    const float* gru_Whh = (const float*)d_in[19];
    const float* gru_bhh = (const float*)d_in[20];
    const float* th_W1 = (const float*)d_in[21];
    const float* th_b1 = (const float*)d_in[22];
    const float* th_W2 = (const float*)d_in[23];
    const float* th_b2 = (const float*)d_in[24];
    const float* th_W3 = (const float*)d_in[25];
    const float* th_b3 = (const float*)d_in[26];
    const float* al_W1 = (const float*)d_in[27];
    const float* al_b1 = (const float*)d_in[28];
    const float* al_W2 = (const float*)d_in[29];
    const float* al_b2 = (const float*)d_in[30];
    const float* al_W3 = (const float*)d_in[31];
    const float* al_b3 = (const float*)d_in[32];

    const int N = in_sizes[0] / 512;
    const int M = in_sizes[1] / 2;
    const int E = in_sizes[3] / 2;
    const int S = in_sizes[6];

    size_t off = 0;
    auto alloc = [&](size_t bytes) {
        char* p = (char*)d_ws + off;
        off += (bytes + 255) & ~(size_t)255;
        return p;
    };
    // bf16 weight slabs
    short* decWb  = (short*)alloc((size_t)128 * 512 * 2);
    short* projWb = (short*)alloc((size_t)3 * 256 * 128 * 2);
    short* mW1bB  = (short*)alloc((size_t)3 * 128 * 128 * 2);
    short* aW1bB  = (short*)alloc((size_t)3 * 128 * 128 * 2);
    short* mW2B   = (short*)alloc((size_t)3 * 128 * 128 * 2);
    short* aW2B   = (short*)alloc((size_t)3 * 128 * 128 * 2);
    short* gihB   = (short*)alloc((size_t)3 * 384 * 128 * 2);
    short* ghhB   = (short*)alloc((size_t)3 * 384 * 128 * 2);
    short* thW1B  = (short*)alloc((size_t)128 * 128 * 2);
    short* thW2B  = (short*)alloc((size_t)128 * 128 * 2);
    short* thW3B  = (short*)alloc((size_t)32 * 128 * 2);
    short* alW1B  = (short*)alloc((size_t)128 * 128 * 2);
    short* alW2B  = (short*)alloc((size_t)128 * 128 * 2);
    short* alW3B  = (short*)alloc((size_t)32 * 128 * 2);
    // activations
    short* sA     = (short*)alloc((size_t)N * 128 * 2);
    short* sB     = (short*)alloc((size_t)N * 128 * 2);
    short* sP     = (short*)alloc((size_t)N * 128 * 2);
    short* efc    = (short*)alloc((size_t)M * 128 * 2);
    short* msgatt = (short*)alloc((size_t)M * 128 * 2);
    short* proj   = (short*)alloc((size_t)N * 256 * 2);
    short* aggb   = (short*)alloc((size_t)N * 128 * 2);
    short* gi     = (short*)alloc((size_t)N * 384 * 2);
    short* gh     = (short*)alloc((size_t)N * 384 * 2);
    int*   cntN   = (int*)  alloc((size_t)N * 4);
    int*   wofs   = (int*)  alloc((size_t)N * 4);
    int*   rowptr = (int*)  alloc((size_t)(N + 1) * 4);
    int*   eidx   = (int*)  alloc((size_t)M * 4);
    int*   srcs   = (int*)  alloc((size_t)M * 4);
    int*   dsts   = (int*)  alloc((size_t)M * 4);
    float* radj   = (float*)alloc((size_t)S * 20 * 4);
    float* rla    = (float*)alloc((size_t)S * 20 * 4);
    float* cntS   = (float*)alloc((size_t)S * 4);
    // overlays: d2 on gi+gh (contiguous, dead after GRU); lt/la on efc
    short* d2 = gi;
    float* lt = (float*)efc;
    float* la = (float*)efc + (size_t)E * 20;

    // ---- prepack descriptor table ----
    PrepackArgs pa;
    int ei = 0;
    auto add = [&](const float* s, short* d, int stride, int rows, int rowsTot, int cols) {
        pa.src[ei] = s; pa.dst[ei] = d; pa.stride[ei] = stride;
        pa.rows[ei] = rows; pa.rowsTot[ei] = rowsTot; pa.cols[ei] = cols; ++ei;
    };
    add(dec_W, decWb, 512, 128, 128, 512);
    for (int l = 0; l < 3; ++l) {
        add(msg_W1 + (size_t)l * 128 * 256,       projWb + (size_t)l * 256 * 128,          256, 128, 128, 128);
        add(att_W1 + (size_t)l * 128 * 256,       projWb + (size_t)l * 256 * 128 + 16384,  256, 128, 128, 128);
        add(msg_W1 + (size_t)l * 128 * 256 + 128, mW1bB + (size_t)l * 16384,               256, 128, 128, 128);
        add(att_W1 + (size_t)l * 128 * 256 + 128, aW1bB + (size_t)l * 16384,               256, 128, 128, 128);
        add(msg_W2 + (size_t)l * 16384,           mW2B + (size_t)l * 16384,                128, 128, 128, 128);
        add(att_W2 + (size_t)l * 16384,           aW2B + (size_t)l * 16384,                128, 128, 128, 128);
        add(gru_Wih + (size_t)l * 49152,          gihB + (size_t)l * 49152,                128, 384, 384, 128);
        add(gru_Whh + (size_t)l * 49152,          ghhB + (size_t)l * 49152,                128, 384, 384, 128);
    }
    add(th_W1, thW1B, 128, 128, 128, 128);
    add(th_W2, thW2B, 128, 128, 128, 128);
    add(th_W3, thW3B, 128, 20, 32, 128);
    add(al_W1, alW1B, 128, 128, 128, 128);
    add(al_W2, alW2B, 128, 128, 128, 128);
    add(al_W3, alW3B, 128, 20, 32, 128);

    const dim3 blk(256);
    const int gN  = (N + 127) / 128;
    const int gE  = (E + 127) / 128;
    const int gMt = (M + 255) / 256;
    const int gEl = (E + 255) / 256;
    const int ntilesM = (M + 63) / 64;

    hipMemsetAsync(radj, 0, (size_t)(S * 20 * 2 + S) * 4, stream);
    hipMemsetAsync(cntN, 0, (size_t)N * 4, stream);

    prepack<<<dim3(384, NPACK), dim3(64), 0, stream>>>(pa);

    csr_count   <<<gMt, blk, 0, stream>>>(edge, cntN, M);
    csr_scan    <<<1, 1024, 0, stream>>>(cntN, rowptr, wofs, N);
    csr_scatter2<<<gMt, blk, 0, stream>>>(edge, wofs, eidx, srcs, dsts, M);
    ef_gather   <<<(int)(((long)M * 16 + 255) / 256), blk, 0, stream>>>(edge_feat, eidx, efc, M);

    // decoder: state = node_feat @ dec_W^T + dec_b
    mm_bf<1><<<gN, blk, 0, stream>>>(node_feat, 512, N, decWb, 512, dec_b, sA, 128, 1);

    short* bufs[2] = { sA, sB };
    for (int l = 0; l < 3; ++l) {
        short* sin  = bufs[l & 1];
        short* snxt = bufs[(l + 1) & 1];
        // proj (msg cols 0-127, att cols 128-255)
        mm_bf<0><<<gN, blk, 0, stream>>>(sin, 128, N, projWb + (size_t)l * 256 * 128, 128,
                                         nullptr, proj, 256, 2);
        edge_fused2<<<ntilesM, blk, 0, stream>>>(efc, srcs, dsts, proj,
            mW1bB + (size_t)l * 16384, mW2B + (size_t)l * 16384,
            aW1bB + (size_t)l * 16384, aW2B + (size_t)l * 16384,
            msg_b1 + l * 128, msg_b2 + l * 128,
            att_b1 + l * 128, att_b2 + l * 128,
            msgatt, M, ntilesM);
        agg_gather2<<<(N * 64 + 255) / 256, blk, 0, stream>>>(msgatt, rowptr, aggb, N);
        mm_bf<0><<<gN, blk, 0, stream>>>(aggb, 128, N, gihB + (size_t)l * 49152, 128,
                                         gru_bih + l * 384, gi, 384, 3);
        mm_bf<0><<<gN, blk, 0, stream>>>(sin, 128, N, ghhB + (size_t)l * 49152, 128,
                                         gru_bhh + l * 384, gh, 384, 3);
        gru_gates<<<(int)(((long)N * 16 + 255) / 256), blk, 0, stream>>>(gi, gh, sin, sP, snxt, N);
    }

    d2_gather<<<(int)(((long)E * 16 + 255) / 256), blk, 0, stream>>>(sP, gnn_idx, d2, E);

    mlp3_fused2<<<gE, blk, 0, stream>>>(d2, thW1B, thW2B, thW3B, th_b1, th_b2, th_b3, lt, E);
    mlp3_fused2<<<gE, blk, 0, stream>>>(d2, alW1B, alW2B, alW3B, al_b1, al_b2, al_b3, la, E);

    loss_kernel<<<gEl, blk, 0, stream>>>(lt, la, label, sg_idx, radj, rla, cntS, E, S);
    final_kernel<<<1, S, 0, stream>>>(radj, rla, cntS, bc_idx, (float*)d_out);
}

// Round 5
// 1453.398 us; speedup vs baseline: 8.9646x; 1.0567x over previous
//
#include <hip/hip_runtime.h>
#include <cstdint>
#include <cstddef>

// GRAN mixture-Bernoulli forward — R5: heavy fusion.
//  - node_fused: gi+gh GEMMs + GRU gates + next-layer proj GEMM (one kernel)
//  - dec_proj:   decoder GEMM + proj0 GEMM
//  - mlp_loss:   d2 gather + theta MLP + alpha MLP + loss segment-reduce
//  - proj stored interleaved ([4 msg|4 att] per 8 cols) -> 16B edge gathers
//  - native __bf16 casts instead of manual RNE bit-twiddle
// Sizes: N=50000, M=250000, E=200000, H=EF=ATT=128, K=20, L=3, S=512.

typedef __bf16 bf16x8 __attribute__((ext_vector_type(8)));
typedef short  s16x8  __attribute__((ext_vector_type(8)));
typedef short  s16x4  __attribute__((ext_vector_type(4)));
typedef float  f32x4  __attribute__((ext_vector_type(4)));

__device__ inline unsigned short f2bf(float f) {
    return __builtin_bit_cast(unsigned short, (__bf16)f);
}
__device__ inline float bf2f(unsigned short b) {
    return __uint_as_float(((unsigned int)b) << 16);
}
__device__ inline unsigned int pk2(float a, float b) {
    return ((unsigned int)f2bf(b) << 16) | f2bf(a);
}
__device__ inline f32x4 MFMA(bf16x8 a, bf16x8 b, f32x4 c) {
    return __builtin_amdgcn_mfma_f32_16x16x32_bf16(a, b, c, 0, 0, 0);
}

// Swizzled LDS tile: [rows][128 bf16] = 256B/row, 16B unit u stored at u^(row&7).
__device__ inline bf16x8 ld_swz(const char* lds, int row, int unit) {
    return *(const bf16x8*)(lds + row * 256 + ((unit ^ (row & 7)) << 4));
}
__device__ inline void hid_write(char* HID, int h0, int erow, s16x4 s4) {
    int unit = h0 >> 3;
    *(s16x4*)(HID + erow * 256 + ((unit ^ (erow & 7)) << 4) + ((h0 & 4) << 1)) = s4;
}
__device__ inline bf16x8 ldA(const short* __restrict__ Wb, int K, int row, int koff) {
    return *(const bf16x8*)(Wb + (size_t)row * K + koff);
}
__device__ inline bf16x8 ld_f32_frag(const float* __restrict__ p) {
    float4 a = *(const float4*)p, b = *(const float4*)(p + 4);
    s16x8 s;
    s[0] = f2bf(a.x); s[1] = f2bf(a.y); s[2] = f2bf(a.z); s[3] = f2bf(a.w);
    s[4] = f2bf(b.x); s[5] = f2bf(b.y); s[6] = f2bf(b.z); s[7] = f2bf(b.w);
    return __builtin_bit_cast(bf16x8, s);
}

// ---------------------------------------------------------------------------
// Weight prepack: fp32 [rows][srcStride] -> bf16 [rowsTot][cols] (zero-pad).
// ---------------------------------------------------------------------------
#define NPACK 31
struct PrepackArgs {
    const float* src[NPACK];
    short*       dst[NPACK];
    int stride[NPACK];
    int rows[NPACK];
    int rowsTot[NPACK];
    int cols[NPACK];
};

__global__ void prepack(PrepackArgs a) {
    int e = blockIdx.y;
    int row = blockIdx.x;
    if (row >= a.rowsTot[e]) return;
    int c8 = threadIdx.x;
    if (c8 * 8 >= a.cols[e]) return;
    s16x8 s = {};
    if (row < a.rows[e]) {
        const float* p = a.src[e] + (size_t)row * a.stride[e] + c8 * 8;
        float4 x = *(const float4*)p, y = *(const float4*)(p + 4);
        s[0] = f2bf(x.x); s[1] = f2bf(x.y); s[2] = f2bf(x.z); s[3] = f2bf(x.w);
        s[4] = f2bf(y.x); s[5] = f2bf(y.y); s[6] = f2bf(y.z); s[7] = f2bf(y.w);
    }
    *(s16x8*)(a.dst[e] + (size_t)row * a.cols[e] + c8 * 8) = s;
}

// ---------------------------------------------------------------------------
// Proj epilogue helper: store accP frag (4 consecutive h-dims, chunk pc) to
// interleaved proj row: short index = 2*h0 + 4*pc (+q).
// ---------------------------------------------------------------------------
__device__ inline void proj_store(short* __restrict__ proj, int node, int h0,
                                  int pc, f32x4 v) {
    s16x4 s4;
    s4[0] = f2bf(v[0]); s4[1] = f2bf(v[1]); s4[2] = f2bf(v[2]); s4[3] = f2bf(v[3]);
    *(s16x4*)(proj + (size_t)node * 256 + 2 * h0 + 4 * pc) = s4;
}

// ---------------------------------------------------------------------------
// dec_proj: state0 = node_feat @ dec_W^T + dec_b (bf16 -> sOut, coalesced via
// LDS) ; proj0 = state0 @ projW^T (interleaved msg/att layout).
// ---------------------------------------------------------------------------
__global__ __launch_bounds__(256, 2)
void dec_proj(const float* __restrict__ nf, int R,
              const short* __restrict__ decWb, const float* __restrict__ bias,
              const short* __restrict__ projW,
              short* __restrict__ sOut, short* __restrict__ proj)
{
    __shared__ char ST[32768];
    const int tid = threadIdx.x, l = tid & 63, w = tid >> 6;
    const int rb = blockIdx.x * 128;

    const float* brow[8];
#pragma unroll
    for (int n = 0; n < 8; ++n) {
        int row = rb + 16 * n + (l & 15); if (row >= R) row = R - 1;
        brow[n] = nf + (size_t)row * 512;
    }

    f32x4 acc[2][8] = {};
    for (int kc = 0; kc < 512; kc += 128) {
#pragma unroll
        for (int ks = 0; ks < 4; ++ks) {
            int koff = kc + ks * 32 + (l >> 4) * 8;
            bf16x8 a0 = ldA(decWb, 512, 32 * w + (l & 15), koff);
            bf16x8 a1 = ldA(decWb, 512, 32 * w + 16 + (l & 15), koff);
#pragma unroll
            for (int n = 0; n < 8; ++n) {
                bf16x8 b = ld_f32_frag(brow[n] + koff);
                acc[0][n] = MFMA(a0, b, acc[0][n]);
                acc[1][n] = MFMA(a1, b, acc[1][n]);
            }
        }
    }
#pragma unroll
    for (int mt = 0; mt < 2; ++mt) {
        int c0 = 32 * w + 16 * mt + ((l >> 4) << 2);
        float4 bv = *(const float4*)&bias[c0];
#pragma unroll
        for (int n = 0; n < 8; ++n) {
            f32x4 v = acc[mt][n];
            s16x4 s4;
            s4[0] = f2bf(v[0] + bv.x); s4[1] = f2bf(v[1] + bv.y);
            s4[2] = f2bf(v[2] + bv.z); s4[3] = f2bf(v[3] + bv.w);
            hid_write(ST, c0, 16 * n + (l & 15), s4);
        }
    }
    __syncthreads();
#pragma unroll
    for (int p2 = 0; p2 < 8; ++p2) {
        int row = p2 * 16 + (tid >> 4);
        int r = rb + row;
        if (r < R) {
            bf16x8 v = ld_swz(ST, row, tid & 15);
            *(s16x8*)(sOut + (size_t)r * 128 + (tid & 15) * 8) =
                __builtin_bit_cast(s16x8, v);
        }
    }
    // proj GEMM from ST (no relu for layer 0)
    f32x4 accP[2][2][8] = {};
#pragma unroll
    for (int ks = 0; ks < 4; ++ks) {
        int koff = ks * 32 + (l >> 4) * 8;
        bf16x8 aw[2][2];
#pragma unroll
        for (int pc = 0; pc < 2; ++pc)
#pragma unroll
            for (int mt = 0; mt < 2; ++mt)
                aw[pc][mt] = ldA(projW, 128, pc * 128 + 32 * w + 16 * mt + (l & 15), koff);
#pragma unroll
        for (int n = 0; n < 8; ++n) {
            bf16x8 b = ld_swz(ST, 16 * n + (l & 15), ks * 4 + (l >> 4));
#pragma unroll
            for (int pc = 0; pc < 2; ++pc)
#pragma unroll
                for (int mt = 0; mt < 2; ++mt)
                    accP[pc][mt][n] = MFMA(aw[pc][mt], b, accP[pc][mt][n]);
        }
    }
#pragma unroll
    for (int pc = 0; pc < 2; ++pc)
#pragma unroll
        for (int mt = 0; mt < 2; ++mt) {
            int h0 = 32 * w + 16 * mt + ((l >> 4) << 2);
#pragma unroll
            for (int n = 0; n < 8; ++n) {
                int node = rb + 16 * n + (l & 15);
                if (node < R) proj_store(proj, node, h0, pc, accP[pc][mt][n]);
            }
        }
}

// ---------------------------------------------------------------------------
// node_fused: gi = aggb@Wih+bih, gh = sin@Whh+bhh (3 chunks each), GRU gates,
// write sOut (= relu(state) if HAS_PROJ else state); if HAS_PROJ compute
// proj_next = sOut @ projW^T (interleaved).
// ---------------------------------------------------------------------------
template<int HAS_PROJ>
__global__ __launch_bounds__(256, 2)
void node_fused(const short* __restrict__ aggb, const short* __restrict__ sin_,
                const short* __restrict__ Wih, const short* __restrict__ Whh,
                const float* __restrict__ bih, const float* __restrict__ bhh,
                const short* __restrict__ projW,
                short* __restrict__ sOut, short* __restrict__ proj, int R)
{
    __shared__ char ST[32768];
    const int tid = threadIdx.x, l = tid & 63, w = tid >> 6;
    const int rb = blockIdx.x * 128;

    const short* arow[8];
    const short* srow[8];
#pragma unroll
    for (int n = 0; n < 8; ++n) {
        int row = rb + 16 * n + (l & 15); if (row >= R) row = R - 1;
        arow[n] = aggb + (size_t)row * 128;
        srow[n] = sin_ + (size_t)row * 128;
    }

    unsigned int rpk[2][8][2], zpk[2][8][2];

    for (int p = 0; p < 3; ++p) {
        f32x4 gia[2][8] = {}, gha[2][8] = {};
#pragma unroll
        for (int ks = 0; ks < 4; ++ks) {
            int koff = ks * 32 + (l >> 4) * 8;
            bf16x8 ai0 = ldA(Wih, 128, p * 128 + 32 * w + (l & 15), koff);
            bf16x8 ai1 = ldA(Wih, 128, p * 128 + 32 * w + 16 + (l & 15), koff);
            bf16x8 ah0 = ldA(Whh, 128, p * 128 + 32 * w + (l & 15), koff);
            bf16x8 ah1 = ldA(Whh, 128, p * 128 + 32 * w + 16 + (l & 15), koff);
#pragma unroll
            for (int n = 0; n < 8; ++n) {
                bf16x8 ba = *(const bf16x8*)(arow[n] + koff);
                bf16x8 bs = *(const bf16x8*)(srow[n] + koff);
                gia[0][n] = MFMA(ai0, ba, gia[0][n]);
                gia[1][n] = MFMA(ai1, ba, gia[1][n]);
                gha[0][n] = MFMA(ah0, bs, gha[0][n]);
                gha[1][n] = MFMA(ah1, bs, gha[1][n]);
            }
        }
#pragma unroll
        for (int mt = 0; mt < 2; ++mt) {
            int c0 = 32 * w + 16 * mt + ((l >> 4) << 2);
            float4 bi = *(const float4*)&bih[p * 128 + c0];
            float4 bh = *(const float4*)&bhh[p * 128 + c0];
            float biv[4] = {bi.x, bi.y, bi.z, bi.w};
            float bhv[4] = {bh.x, bh.y, bh.z, bh.w};
#pragma unroll
            for (int n = 0; n < 8; ++n) {
                float gv[4], hv[4];
#pragma unroll
                for (int q = 0; q < 4; ++q) {
                    gv[q] = gia[mt][n][q] + biv[q];
                    hv[q] = gha[mt][n][q] + bhv[q];
                }
                if (p == 0) {
                    float r0 = 1.f / (1.f + expf(-(gv[0] + hv[0])));
                    float r1 = 1.f / (1.f + expf(-(gv[1] + hv[1])));
                    float r2 = 1.f / (1.f + expf(-(gv[2] + hv[2])));
                    float r3 = 1.f / (1.f + expf(-(gv[3] + hv[3])));
                    rpk[mt][n][0] = pk2(r0, r1); rpk[mt][n][1] = pk2(r2, r3);
                } else if (p == 1) {
                    float z0 = 1.f / (1.f + expf(-(gv[0] + hv[0])));
                    float z1 = 1.f / (1.f + expf(-(gv[1] + hv[1])));
                    float z2 = 1.f / (1.f + expf(-(gv[2] + hv[2])));
                    float z3 = 1.f / (1.f + expf(-(gv[3] + hv[3])));
                    zpk[mt][n][0] = pk2(z0, z1); zpk[mt][n][1] = pk2(z2, z3);
                } else {
                    s16x4 sv = *(const s16x4*)(srow[n] + c0);
                    s16x4 s4;
#pragma unroll
                    for (int q = 0; q < 4; ++q) {
                        unsigned int ru = rpk[mt][n][q >> 1], zu = zpk[mt][n][q >> 1];
                        float r = bf2f((unsigned short)((q & 1) ? (ru >> 16) : (ru & 0xffffu)));
                        float z = bf2f((unsigned short)((q & 1) ? (zu >> 16) : (zu & 0xffffu)));
                        float nn = tanhf(gv[q] + r * hv[q]);
                        float o = (1.f - z) * nn + z * bf2f((unsigned short)sv[q]);
                        s4[q] = f2bf(HAS_PROJ ? fmaxf(o, 0.f) : o);
                    }
                    hid_write(ST, c0, 16 * n + (l & 15), s4);
                }
            }
        }
    }
    __syncthreads();
#pragma unroll
    for (int p2 = 0; p2 < 8; ++p2) {
        int row = p2 * 16 + (tid >> 4);
        int r = rb + row;
        if (r < R) {
            bf16x8 v = ld_swz(ST, row, tid & 15);
            *(s16x8*)(sOut + (size_t)r * 128 + (tid & 15) * 8) =
                __builtin_bit_cast(s16x8, v);
        }
    }
    if (HAS_PROJ) {
        f32x4 accP[2][2][8] = {};
#pragma unroll
        for (int ks = 0; ks < 4; ++ks) {
            int koff = ks * 32 + (l >> 4) * 8;
            bf16x8 aw[2][2];
#pragma unroll
            for (int pc = 0; pc < 2; ++pc)
#pragma unroll
                for (int mt = 0; mt < 2; ++mt)
                    aw[pc][mt] = ldA(projW, 128, pc * 128 + 32 * w + 16 * mt + (l & 15), koff);
#pragma unroll
            for (int n = 0; n < 8; ++n) {
                bf16x8 b = ld_swz(ST, 16 * n + (l & 15), ks * 4 + (l >> 4));
#pragma unroll
                for (int pc = 0; pc < 2; ++pc)
#pragma unroll
                    for (int mt = 0; mt < 2; ++mt)
                        accP[pc][mt][n] = MFMA(aw[pc][mt], b, accP[pc][mt][n]);
            }
        }
#pragma unroll
        for (int pc = 0; pc < 2; ++pc)
#pragma unroll
            for (int mt = 0; mt < 2; ++mt) {
                int h0 = 32 * w + 16 * mt + ((l >> 4) << 2);
#pragma unroll
                for (int n = 0; n < 8; ++n) {
                    int node = rb + 16 * n + (l & 15);
                    if (node < R) proj_store(proj, node, h0, pc, accP[pc][mt][n]);
                }
            }
    }
}

// ---------------------------------------------------------------------------
// Fused edge MLPs, CSR order, 64 edges/block, interleaved proj (16B gathers).
// ---------------------------------------------------------------------------
__global__ __launch_bounds__(256, 4)
void edge_fused2(const short* __restrict__ efc,
                 const int* __restrict__ srcs, const int* __restrict__ dsts,
                 const short* __restrict__ proj,    // N x 256 interleaved
                 const short* __restrict__ mW1b, const short* __restrict__ mW2,
                 const short* __restrict__ aW1b, const short* __restrict__ aW2,
                 const float* __restrict__ mb1, const float* __restrict__ mb2,
                 const float* __restrict__ ab1, const float* __restrict__ ab2,
                 short* __restrict__ msgatt, int M, int ntiles)
{
    __shared__ char HIDm[16384];
    __shared__ char HIDa[16384];
    const int tid = threadIdx.x, l = tid & 63, w = tid >> 6;
    int q = ntiles >> 3, r = ntiles & 7;
    int xcd = blockIdx.x & 7, o = blockIdx.x >> 3;
    int tile = (xcd < r ? xcd * (q + 1) : r * (q + 1) + (xcd - r) * q) + o;
    const int pb = tile * 64;

    int srcv[4], dstv[4];
    const char* erow[4];
#pragma unroll
    for (int n = 0; n < 4; ++n) {
        int pos = pb + 16 * n + (l & 15); if (pos >= M) pos = M - 1;
        srcv[n] = srcs[pos]; dstv[n] = dsts[pos];
        erow[n] = (const char*)(efc + (size_t)pos * 128);
    }

    // GEMM1 combined (msg+att share ef B-operand)
    f32x4 accm[2][4] = {}, acca[2][4] = {};
#pragma unroll
    for (int ks = 0; ks < 4; ++ks) {
        int koff = ks * 32 + (l >> 4) * 8;
        bf16x8 am0 = ldA(mW1b, 128, 32 * w + (l & 15), koff);
        bf16x8 am1 = ldA(mW1b, 128, 32 * w + 16 + (l & 15), koff);
        bf16x8 aa0 = ldA(aW1b, 128, 32 * w + (l & 15), koff);
        bf16x8 aa1 = ldA(aW1b, 128, 32 * w + 16 + (l & 15), koff);
#pragma unroll
        for (int n = 0; n < 4; ++n) {
            bf16x8 b = *(const bf16x8*)(erow[n] + koff * 2);
            accm[0][n] = MFMA(am0, b, accm[0][n]);
            accm[1][n] = MFMA(am1, b, accm[1][n]);
            acca[0][n] = MFMA(aa0, b, acca[0][n]);
            acca[1][n] = MFMA(aa1, b, acca[1][n]);
        }
    }
    // epilogue 1: bias + proj diff (16B interleaved gathers), relu -> HID
#pragma unroll
    for (int mt = 0; mt < 2; ++mt) {
        int h0 = 32 * w + 16 * mt + ((l >> 4) << 2);
        float4 bm = *(const float4*)&mb1[h0];
        float4 ba = *(const float4*)&ab1[h0];
        float bmv[4] = {bm.x, bm.y, bm.z, bm.w};
        float bav[4] = {ba.x, ba.y, ba.z, ba.w};
#pragma unroll
        for (int n = 0; n < 4; ++n) {
            s16x8 ps = *(const s16x8*)(proj + (size_t)srcv[n] * 256 + 2 * h0);
            s16x8 pd = *(const s16x8*)(proj + (size_t)dstv[n] * 256 + 2 * h0);
            f32x4 vm = accm[mt][n], va = acca[mt][n];
            s16x4 sm, sa;
#pragma unroll
            for (int qq = 0; qq < 4; ++qq) {
                float m_ = vm[qq] + bmv[qq] + bf2f((unsigned short)ps[qq])
                           - bf2f((unsigned short)pd[qq]);
                float a_ = va[qq] + bav[qq] + bf2f((unsigned short)ps[qq + 4])
                           - bf2f((unsigned short)pd[qq + 4]);
                sm[qq] = f2bf(fmaxf(m_, 0.f));
                sa[qq] = f2bf(fmaxf(a_, 0.f));
            }
            hid_write(HIDm, h0, 16 * n + (l & 15), sm);
            hid_write(HIDa, h0, 16 * n + (l & 15), sa);
        }
    }
    __syncthreads();

    // GEMM2 combined
    f32x4 acc2m[2][4] = {}, acc2a[2][4] = {};
#pragma unroll
    for (int ks = 0; ks < 4; ++ks) {
        int koff = ks * 32 + (l >> 4) * 8;
        bf16x8 wm0 = ldA(mW2, 128, 32 * w + (l & 15), koff);
        bf16x8 wm1 = ldA(mW2, 128, 32 * w + 16 + (l & 15), koff);
        bf16x8 wa0 = ldA(aW2, 128, 32 * w + (l & 15), koff);
        bf16x8 wa1 = ldA(aW2, 128, 32 * w + 16 + (l & 15), koff);
#pragma unroll
        for (int n = 0; n < 4; ++n) {
            bf16x8 bm = ld_swz(HIDm, 16 * n + (l & 15), ks * 4 + (l >> 4));
            bf16x8 ba = ld_swz(HIDa, 16 * n + (l & 15), ks * 4 + (l >> 4));
            acc2m[0][n] = MFMA(wm0, bm, acc2m[0][n]);
            acc2m[1][n] = MFMA(wm1, bm, acc2m[1][n]);
            acc2a[0][n] = MFMA(wa0, ba, acc2a[0][n]);
            acc2a[1][n] = MFMA(wa1, ba, acc2a[1][n]);
        }
    }
    __syncthreads();                // HID reads done; reuse HIDm for output
#pragma unroll
    for (int mt = 0; mt < 2; ++mt) {
        int c0 = 32 * w + 16 * mt + ((l >> 4) << 2);
        float4 bm2 = *(const float4*)&mb2[c0];
        float4 ba2 = *(const float4*)&ab2[c0];
#pragma unroll
        for (int n = 0; n < 4; ++n) {
            f32x4 m_ = acc2m[mt][n], a_ = acc2a[mt][n];
            float o0 = (m_[0] + bm2.x) / (1.f + expf(-(a_[0] + ba2.x)));
            float o1 = (m_[1] + bm2.y) / (1.f + expf(-(a_[1] + ba2.y)));
            float o2 = (m_[2] + bm2.z) / (1.f + expf(-(a_[2] + ba2.z)));
            float o3 = (m_[3] + bm2.w) / (1.f + expf(-(a_[3] + ba2.w)));
            s16x4 s4;
            s4[0] = f2bf(o0); s4[1] = f2bf(o1); s4[2] = f2bf(o2); s4[3] = f2bf(o3);
            hid_write(HIDm, c0, 16 * n + (l & 15), s4);
        }
    }
    __syncthreads();
#pragma unroll
    for (int p2 = 0; p2 < 4; ++p2) {
        int row = p2 * 16 + (tid >> 4);
        int pos = pb + row;
        if (pos < M) {
            bf16x8 v = ld_swz(HIDm, row, tid & 15);
            *(s16x8*)(msgatt + (size_t)pos * 128 + (tid & 15) * 8) =
                __builtin_bit_cast(s16x8, v);
        }
    }
}

// ---------------------------------------------------------------------------
// mlp_loss: per 128 edges — d2 = sP[a]-sP[b] (LDS tile), theta & alpha 3-layer
// MLPs sharing the d2 tile, loss terms reduced via LDS + global atomics.
// ---------------------------------------------------------------------------
__global__ __launch_bounds__(256, 2)
void mlp_loss(const short* __restrict__ sP, const int* __restrict__ gidx,
              const float* __restrict__ label, const int* __restrict__ sg,
              const short* __restrict__ thW1, const short* __restrict__ thW2,
              const short* __restrict__ thW3,
              const float* __restrict__ thb1, const float* __restrict__ thb2,
              const float* __restrict__ thb3,
              const short* __restrict__ alW1, const short* __restrict__ alW2,
              const short* __restrict__ alW3,
              const float* __restrict__ alb1, const float* __restrict__ alb2,
              const float* __restrict__ alb3,
              float* __restrict__ radj, float* __restrict__ rla,
              float* __restrict__ cntS, int E, int S)
{
    __shared__ char D2T[32768];
    __shared__ char HID[32768];
    __shared__ float sadj[4][20];
    __shared__ float sla[4][20];
    __shared__ float scnt[4];
    __shared__ int sbase;
    const int tid = threadIdx.x, l = tid & 63, w = tid >> 6;
    const int eb = blockIdx.x * 128;

    if (tid == 0) sbase = sg[eb];
    if (tid < 80) { sadj[tid / 20][tid % 20] = 0.f; sla[tid / 20][tid % 20] = 0.f; }
    if (tid < 4) scnt[tid] = 0.f;

    // build d2 tile
    for (int i = tid; i < 128 * 16; i += 256) {
        int row = i >> 4, u = i & 15;
        int e = eb + row; if (e >= E) e = E - 1;
        int2 ab = *(const int2*)&gidx[2 * (size_t)e];
        s16x8 x = *(const s16x8*)(sP + (size_t)ab.x * 128 + u * 8);
        s16x8 y = *(const s16x8*)(sP + (size_t)ab.y * 128 + u * 8);
        s16x8 d;
#pragma unroll
        for (int j = 0; j < 8; ++j)
            d[j] = f2bf(bf2f((unsigned short)x[j]) - bf2f((unsigned short)y[j]));
        *(s16x8*)(D2T + row * 256 + ((u ^ (row & 7)) << 4)) = d;
    }
    __syncthreads();

    for (int pass = 0; pass < 2; ++pass) {
        const short* W1 = pass ? alW1 : thW1;
        const short* W2 = pass ? alW2 : thW2;
        const short* W3 = pass ? alW3 : thW3;
        const float* b1 = pass ? alb1 : thb1;
        const float* b2 = pass ? alb2 : thb2;
        const float* b3 = pass ? alb3 : thb3;

        // stage 1: h1 = relu(d2@W1^T + b1) -> HID
        f32x4 acc[2][8] = {};
#pragma unroll
        for (int ks = 0; ks < 4; ++ks) {
            int koff = ks * 32 + (l >> 4) * 8;
            bf16x8 a0 = ldA(W1, 128, 32 * w + (l & 15), koff);
            bf16x8 a1 = ldA(W1, 128, 32 * w + 16 + (l & 15), koff);
#pragma unroll
            for (int n = 0; n < 8; ++n) {
                bf16x8 b = ld_swz(D2T, 16 * n + (l & 15), ks * 4 + (l >> 4));
                acc[0][n] = MFMA(a0, b, acc[0][n]);
                acc[1][n] = MFMA(a1, b, acc[1][n]);
            }
        }
        __syncthreads();   // prior-pass HID readers done
#pragma unroll
        for (int mt = 0; mt < 2; ++mt) {
            int h0 = 32 * w + 16 * mt + ((l >> 4) << 2);
            float4 bv = *(const float4*)&b1[h0];
#pragma unroll
            for (int n = 0; n < 8; ++n) {
                f32x4 v = acc[mt][n];
                s16x4 s4;
                s4[0] = f2bf(fmaxf(v[0] + bv.x, 0.f));
                s4[1] = f2bf(fmaxf(v[1] + bv.y, 0.f));
                s4[2] = f2bf(fmaxf(v[2] + bv.z, 0.f));
                s4[3] = f2bf(fmaxf(v[3] + bv.w, 0.f));
                hid_write(HID, h0, 16 * n + (l & 15), s4);
            }
        }
        __syncthreads();
        // stage 2: h2 = relu(h1@W2^T + b2)
        f32x4 acc2[2][8] = {};
#pragma unroll
        for (int ks = 0; ks < 4; ++ks) {
            int koff = ks * 32 + (l >> 4) * 8;
            bf16x8 a0 = ldA(W2, 128, 32 * w + (l & 15), koff);
            bf16x8 a1 = ldA(W2, 128, 32 * w + 16 + (l & 15), koff);
#pragma unroll
            for (int n = 0; n < 8; ++n) {
                bf16x8 b = ld_swz(HID, 16 * n + (l & 15), ks * 4 + (l >> 4));
                acc2[0][n] = MFMA(a0, b, acc2[0][n]);
                acc2[1][n] = MFMA(a1, b, acc2[1][n]);
            }
        }
        __syncthreads();
#pragma unroll
        for (int mt = 0; mt < 2; ++mt) {
            int h0 = 32 * w + 16 * mt + ((l >> 4) << 2);
            float4 bv = *(const float4*)&b2[h0];
#pragma unroll
            for (int n = 0; n < 8; ++n) {
                f32x4 v = acc2[mt][n];
                s16x4 s4;
                s4[0] = f2bf(fmaxf(v[0] + bv.x, 0.f));
                s4[1] = f2bf(fmaxf(v[1] + bv.y, 0.f));
                s4[2] = f2bf(fmaxf(v[2] + bv.z, 0.f));
                s4[3] = f2bf(fmaxf(v[3] + bv.w, 0.f));
                hid_write(HID, h0, 16 * n + (l & 15), s4);
            }
        }
        __syncthreads();
        // stage 3: out = h2@W3^T + b3 ; loss accumulate
        f32x4 acc3[2][2] = {};
#pragma unroll
        for (int ks = 0; ks < 4; ++ks) {
            int koff = ks * 32 + (l >> 4) * 8;
            bf16x8 a0 = ldA(W3, 128, (l & 15), koff);
            bf16x8 a1 = ldA(W3, 128, 16 + (l & 15), koff);
#pragma unroll
            for (int j = 0; j < 2; ++j) {
                bf16x8 b = ld_swz(HID, 16 * (2 * w + j) + (l & 15), ks * 4 + (l >> 4));
                acc3[0][j] = MFMA(a0, b, acc3[0][j]);
                acc3[1][j] = MFMA(a1, b, acc3[1][j]);
            }
        }
#pragma unroll
        for (int mt = 0; mt < 2; ++mt) {
            int c0 = 16 * mt + ((l >> 4) << 2);
            if (c0 >= 20) continue;
#pragma unroll
            for (int j = 0; j < 2; ++j) {
                int e = eb + 16 * (2 * w + j) + (l & 15);
                if (e < E) {
                    int ls = sg[e] - sbase;
                    if (pass == 0) {
                        float y = label[e];
#pragma unroll
                        for (int qq = 0; qq < 4; ++qq) {
                            int k = c0 + qq;
                            if (k < 20) {
                                float t = acc3[mt][j][qq] + b3[k];
                                float sp = fmaxf(-t, 0.f) + log1pf(expf(-fabsf(t)));
                                atomicAdd(&sadj[ls][k], sp + (1.f - y) * t);
                            }
                        }
                    } else {
#pragma unroll
                        for (int qq = 0; qq < 4; ++qq) {
                            int k = c0 + qq;
                            if (k < 20)
                                atomicAdd(&sla[ls][k], acc3[mt][j][qq] + b3[k]);
                        }
                    }
                }
            }
        }
        __syncthreads();   // loss reads of HID-derived accs done before next pass
    }

    if (tid < 128) {
        int e = eb + tid;
        if (e < E) atomicAdd(&scnt[sg[e] - sbase], 1.f);
    }
    __syncthreads();
    if (tid < 80) {
        int ls = tid / 20, k = tid % 20;
        int s = sbase + ls;
        if (s < S) {
            float v = sadj[ls][k], v2 = sla[ls][k];
            if (v  != 0.f) atomicAdd(&radj[s * 20 + k], v);
            if (v2 != 0.f) atomicAdd(&rla[s * 20 + k], v2);
        }
    }
    if (tid < 4) {
        int s = sbase + tid;
        if (s < S && scnt[tid] != 0.f) atomicAdd(&cntS[s], scnt[tid]);
    }
}

// ---------------------------------------------------------------------------
// CSR build + gathers + aggregation (unchanged from R4)
// ---------------------------------------------------------------------------
__global__ void csr_count(const int* __restrict__ edge, int* __restrict__ cnt, int M) {
    int e = blockIdx.x * 256 + threadIdx.x;
    if (e < M) atomicAdd(&cnt[edge[2 * (size_t)e + 1]], 1);
}

__global__ void csr_scan(const int* __restrict__ cnt, int* __restrict__ rowptr,
                         int* __restrict__ wofs, int N)
{
    __shared__ int part[1024];
    int t = threadIdx.x;
    int chunk = (N + 1023) / 1024;
    int b0 = t * chunk, b1 = b0 + chunk; if (b1 > N) b1 = N; if (b0 > N) b0 = N;
    int s = 0;
    for (int i = b0; i < b1; ++i) s += cnt[i];
    part[t] = s;
    __syncthreads();
    for (int off = 1; off < 1024; off <<= 1) {
        int v = (t >= off) ? part[t - off] : 0;
        __syncthreads();
        part[t] += v;
        __syncthreads();
    }
    int run = (t ? part[t - 1] : 0);
    for (int i = b0; i < b1; ++i) { rowptr[i] = run; wofs[i] = run; run += cnt[i]; }
    if (t == 1023) rowptr[N] = run;
}

__global__ void csr_scatter2(const int* __restrict__ edge, int* __restrict__ wofs,
                             int* __restrict__ eidx, int* __restrict__ srcs,
                             int* __restrict__ dsts, int M)
{
    int e = blockIdx.x * 256 + threadIdx.x;
    if (e < M) {
        int2 sd = *(const int2*)&edge[2 * (size_t)e];
        int p = atomicAdd(&wofs[sd.y], 1);
        eidx[p] = e; srcs[p] = sd.x; dsts[p] = sd.y;
    }
}

__global__ void ef_gather(const float* __restrict__ ef, const int* __restrict__ eidx,
                          short* __restrict__ efc, int M)
{
    long i = (long)blockIdx.x * 256 + threadIdx.x;
    if (i >= (long)M * 16) return;
    int p = (int)(i >> 4), u = (int)(i & 15);
    int e = eidx[p];
    const float* sp = ef + (size_t)e * 128 + u * 8;
    float4 a = *(const float4*)sp, b = *(const float4*)(sp + 4);
    s16x8 s;
    s[0] = f2bf(a.x); s[1] = f2bf(a.y); s[2] = f2bf(a.z); s[3] = f2bf(a.w);
    s[4] = f2bf(b.x); s[5] = f2bf(b.y); s[6] = f2bf(b.z); s[7] = f2bf(b.w);
    *(s16x8*)(efc + (size_t)p * 128 + u * 8) = s;
}

__global__ __launch_bounds__(256)
void agg_gather2(const short* __restrict__ msgatt, const int* __restrict__ rowptr,
                 short* __restrict__ aggb, int N)
{
    int v = (blockIdx.x * 256 + threadIdx.x) >> 6;
    int l = threadIdx.x & 63;
    if (v >= N) return;
    int b = rowptr[v], e = rowptr[v + 1];
    float sx = 0.f, sy = 0.f;
    for (int i = b; i < e; ++i) {
        unsigned int u = *(const unsigned int*)(msgatt + (size_t)i * 128 + 2 * l);
        sx += bf2f((unsigned short)(u & 0xffffu));
        sy += bf2f((unsigned short)(u >> 16));
    }
    unsigned int o = ((unsigned int)f2bf(sy) << 16) | f2bf(sx);
    *(unsigned int*)(aggb + (size_t)v * 128 + 2 * l) = o;
}

// ---------------------------------------------------------------------------
__global__ void final_kernel(const float* __restrict__ radj, const float* __restrict__ rla,
                             const float* __restrict__ cnt, const int* __restrict__ bc_idx,
                             float* __restrict__ out)
{
    __shared__ float bcl[16], bcc[16];
    const int s = threadIdx.x;
    if (s < 16) { bcl[s] = 0.f; bcc[s] = 0.f; }
    __syncthreads();
    float c = cnt[s];
    float x[20];
    float mx = -1e30f;
#pragma unroll
    for (int k = 0; k < 20; ++k) { x[k] = rla[s * 20 + k] / c; mx = fmaxf(mx, x[k]); }
    float se = 0.f;
#pragma unroll
    for (int k = 0; k < 20; ++k) se += expf(x[k] - mx);
    float lse = mx + logf(se);
    float t[20];
    float m2 = -1e30f;
#pragma unroll
    for (int k = 0; k < 20; ++k) { t[k] = -radj[s * 20 + k] + x[k] - lse; m2 = fmaxf(m2, t[k]); }
    float s2 = 0.f;
#pragma unroll
    for (int k = 0; k < 20; ++k) s2 += expf(t[k] - m2);
    float lp = m2 + logf(s2);
    atomicAdd(&bcl[bc_idx[s]], lp);
    atomicAdd(&bcc[bc_idx[s]], c);
    __syncthreads();
    if (s == 0) {
        float a = 0.f;
        for (int b = 0; b < 16; ++b) a += bcl[b] / bcc[b];
        out[0] = -a / 16.f;
    }
}

// ---------------------------------------------------------------------------
extern "C" void kernel_launch(void* const* d_in, const int* in_sizes, int n_in,
                              void* d_out, int out_size, void* d_ws, size_t ws_size,
                              hipStream_t stream)
{
    const float* node_feat = (const float*)d_in[0];
    const int*   edge      = (const int*)  d_in[1];
    const float* edge_feat = (const float*)d_in[2];
    const int*   gnn_idx   = (const int*)  d_in[3];
    const float* label     = (const float*)d_in[4];
    const int*   sg_idx    = (const int*)  d_in[5];
    const int*   bc_idx    = (const int*)  d_in[6];
    const float* dec_W  = (const float*)d_in[7];
    const float* dec_b  = (const float*)d_in[8];
    const float* msg_W1 = (const float*)d_in[9];
    const float* msg_b1 = (const float*)d_in[10];
    const float* msg_W2 = (const float*)d_in[11];
    const float* msg_b2 = (const float*)d_in[12];
    const float* att_W1 = (const float*)d_in[13];
    const float* att_b1 = (const float*)d_in[14];
    const float* att_W2 = (const float*)d_in[15];
    const float* att_b2 = (const float*)d_in[16];
    const float* gru_Wih = (const float*)d_in[17];
    const float* gru_bih = (const float*)d_in[18];
    const float* gru_Whh = (const float*)d_in[19];
    const float* gru_bhh = (const float*)d_in[20];
    const float* th_W1 = (const float*)d_in[21];
    const float* th_b1 = (const float*)d_in[22];
    const float* th_W2 = (const float*)d_in[23];
    const float* th_b2 = (const float*)d_in[24];
    const float* th_W3 = (const float*)d_in[25];
    const float* th_b3 = (const float*)d_in[26];
    const float* al_W1 = (const float*)d_in[27];
    const float* al_b1 = (const float*)d_in[28];
    const float* al_W2 = (const float*)d_in[29];
    const float* al_b2 = (const float*)d_in[30];
    const float* al_W3 = (const float*)d_in[31];
    const float* al_b3 = (const float*)d_in[32];

    const int N = in_sizes[0] / 512;
    const int M = in_sizes[1] / 2;
    const int E = in_sizes[3] / 2;
    const int S = in_sizes[6];

    size_t off = 0;
    auto alloc = [&](size_t bytes) {
        char* p = (char*)d_ws + off;
        off += (bytes + 255) & ~(size_t)255;
        return p;
    };
    // bf16 weight slabs
    short* decWb  = (short*)alloc((size_t)128 * 512 * 2);
    short* projWb = (short*)alloc((size_t)3 * 256 * 128 * 2);
    short* mW1bB  = (short*)alloc((size_t)3 * 128 * 128 * 2);
    short* aW1bB  = (short*)alloc((size_t)3 * 128 * 128 * 2);
    short* mW2B   = (short*)alloc((size_t)3 * 128 * 128 * 2);
    short* aW2B   = (short*)alloc((size_t)3 * 128 * 128 * 2);
    short* gihB   = (short*)alloc((size_t)3 * 384 * 128 * 2);
    short* ghhB   = (short*)alloc((size_t)3 * 384 * 128 * 2);
    short* thW1B  = (short*)alloc((size_t)128 * 128 * 2);
    short* thW2B  = (short*)alloc((size_t)128 * 128 * 2);
    short* thW3B  = (short*)alloc((size_t)32 * 128 * 2);
    short* alW1B  = (short*)alloc((size_t)128 * 128 * 2);
    short* alW2B  = (short*)alloc((size_t)128 * 128 * 2);
    short* alW3B  = (short*)alloc((size_t)32 * 128 * 2);
    // activations
    short* sA     = (short*)alloc((size_t)N * 128 * 2);
    short* sB     = (short*)alloc((size_t)N * 128 * 2);
    short* sP     = (short*)alloc((size_t)N * 128 * 2);
    short* efc    = (short*)alloc((size_t)M * 128 * 2);
    short* msgatt = (short*)alloc((size_t)M * 128 * 2);
    short* proj   = (short*)alloc((size_t)N * 256 * 2);
    short* aggb   = (short*)alloc((size_t)N * 128 * 2);
    int*   cntN   = (int*)  alloc((size_t)N * 4);
    int*   wofs   = (int*)  alloc((size_t)N * 4);
    int*   rowptr = (int*)  alloc((size_t)(N + 1) * 4);
    int*   eidx   = (int*)  alloc((size_t)M * 4);
    int*   srcs   = (int*)  alloc((size_t)M * 4);
    int*   dsts   = (int*)  alloc((size_t)M * 4);
    float* radj   = (float*)alloc((size_t)S * 20 * 4);
    float* rla    = (float*)alloc((size_t)S * 20 * 4);
    float* cntS   = (float*)alloc((size_t)S * 4);

    // ---- prepack descriptor table ----
    PrepackArgs pa;
    int ei = 0;
    auto add = [&](const float* s, short* d, int stride, int rows, int rowsTot, int cols) {
        pa.src[ei] = s; pa.dst[ei] = d; pa.stride[ei] = stride;
        pa.rows[ei] = rows; pa.rowsTot[ei] = rowsTot; pa.cols[ei] = cols; ++ei;
    };
    add(dec_W, decWb, 512, 128, 128, 512);
    for (int l = 0; l < 3; ++l) {
        add(msg_W1 + (size_t)l * 128 * 256,       projWb + (size_t)l * 256 * 128,          256, 128, 128, 128);
        add(att_W1 + (size_t)l * 128 * 256,       projWb + (size_t)l * 256 * 128 + 16384,  256, 128, 128, 128);
        add(msg_W1 + (size_t)l * 128 * 256 + 128, mW1bB + (size_t)l * 16384,               256, 128, 128, 128);
        add(att_W1 + (size_t)l * 128 * 256 + 128, aW1bB + (size_t)l * 16384,               256, 128, 128, 128);
        add(msg_W2 + (size_t)l * 16384,           mW2B + (size_t)l * 16384,                128, 128, 128, 128);
        add(att_W2 + (size_t)l * 16384,           aW2B + (size_t)l * 16384,                128, 128, 128, 128);
        add(gru_Wih + (size_t)l * 49152,          gihB + (size_t)l * 49152,                128, 384, 384, 128);
        add(gru_Whh + (size_t)l * 49152,          ghhB + (size_t)l * 49152,                128, 384, 384, 128);
    }
    add(th_W1, thW1B, 128, 128, 128, 128);
    add(th_W2, thW2B, 128, 128, 128, 128);
    add(th_W3, thW3B, 128, 20, 32, 128);
    add(al_W1, alW1B, 128, 128, 128, 128);
    add(al_W2, alW2B, 128, 128, 128, 128);
    add(al_W3, alW3B, 128, 20, 32, 128);

    const dim3 blk(256);
    const int gN  = (N + 127) / 128;
    const int gE  = (E + 127) / 128;
    const int gMt = (M + 255) / 256;
    const int ntilesM = (M + 63) / 64;

    hipMemsetAsync(radj, 0, (size_t)(S * 20 * 2 + S) * 4, stream);
    hipMemsetAsync(cntN, 0, (size_t)N * 4, stream);

    prepack<<<dim3(384, NPACK), dim3(64), 0, stream>>>(pa);

    csr_count   <<<gMt, blk, 0, stream>>>(edge, cntN, M);
    csr_scan    <<<1, 1024, 0, stream>>>(cntN, rowptr, wofs, N);
    csr_scatter2<<<gMt, blk, 0, stream>>>(edge, wofs, eidx, srcs, dsts, M);
    ef_gather   <<<(int)(((long)M * 16 + 255) / 256), blk, 0, stream>>>(edge_feat, eidx, efc, M);

    // decoder + proj0
    dec_proj<<<gN, blk, 0, stream>>>(node_feat, N, decWb, dec_b, projWb, sA, proj);

    short* bufs[2] = { sA, sB };
    for (int l = 0; l < 3; ++l) {
        short* sin  = bufs[l & 1];
        short* sout = (l == 2) ? sP : bufs[(l + 1) & 1];
        edge_fused2<<<ntilesM, blk, 0, stream>>>(efc, srcs, dsts, proj,
            mW1bB + (size_t)l * 16384, mW2B + (size_t)l * 16384,
            aW1bB + (size_t)l * 16384, aW2B + (size_t)l * 16384,
            msg_b1 + l * 128, msg_b2 + l * 128,
            att_b1 + l * 128, att_b2 + l * 128,
            msgatt, M, ntilesM);
        agg_gather2<<<(N * 64 + 255) / 256, blk, 0, stream>>>(msgatt, rowptr, aggb, N);
        if (l < 2) {
            node_fused<1><<<gN, blk, 0, stream>>>(aggb, sin,
                gihB + (size_t)l * 49152, ghhB + (size_t)l * 49152,
                gru_bih + l * 384, gru_bhh + l * 384,
                projWb + (size_t)(l + 1) * 256 * 128, sout, proj, N);
        } else {
            node_fused<0><<<gN, blk, 0, stream>>>(aggb, sin,
                gihB + (size_t)l * 49152, ghhB + (size_t)l * 49152,
                gru_bih + l * 384, gru_bhh + l * 384,
                nullptr, sout, nullptr, N);
        }
    }

    mlp_loss<<<gE, blk, 0, stream>>>(sP, gnn_idx, label, sg_idx,
        thW1B, thW2B, thW3B, th_b1, th_b2, th_b3,
        alW1B, alW2B, alW3B, al_b1, al_b2, al_b3,
        radj, rla, cntS, E, S);
    final_kernel<<<1, S, 0, stream>>>(radj, rla, cntS, bc_idx, (float*)d_out);
}

// Round 6
// 1431.567 us; speedup vs baseline: 9.1013x; 1.0152x over previous
//
#include <hip/hip_runtime.h>
#include <cstdint>
#include <cstddef>

// GRAN mixture-Bernoulli forward — R6: 64-row tiles everywhere (occupancy),
// proj stores via LDS repack (write amplification fix), edge proj-gather
// register prefetch (latency hide).
// Sizes: N=50000, M=250000, E=200000, H=EF=ATT=128, K=20, L=3, S=512.

typedef __bf16 bf16x8 __attribute__((ext_vector_type(8)));
typedef short  s16x8  __attribute__((ext_vector_type(8)));
typedef short  s16x4  __attribute__((ext_vector_type(4)));
typedef float  f32x4  __attribute__((ext_vector_type(4)));

__device__ inline unsigned short f2bf(float f) {
    return __builtin_bit_cast(unsigned short, (__bf16)f);
}
__device__ inline float bf2f(unsigned short b) {
    return __uint_as_float(((unsigned int)b) << 16);
}
__device__ inline unsigned int pk2(float a, float b) {
    return ((unsigned int)f2bf(b) << 16) | f2bf(a);
}
__device__ inline f32x4 MFMA(bf16x8 a, bf16x8 b, f32x4 c) {
    return __builtin_amdgcn_mfma_f32_16x16x32_bf16(a, b, c, 0, 0, 0);
}

// Swizzled LDS tile: [rows][128 bf16] = 256B/row, 16B unit u stored at u^(row&7).
__device__ inline bf16x8 ld_swz(const char* lds, int row, int unit) {
    return *(const bf16x8*)(lds + row * 256 + ((unit ^ (row & 7)) << 4));
}
__device__ inline void hid_write(char* HID, int h0, int erow, s16x4 s4) {
    int unit = h0 >> 3;
    *(s16x4*)(HID + erow * 256 + ((unit ^ (erow & 7)) << 4) + ((h0 & 4) << 1)) = s4;
}
__device__ inline bf16x8 ldA(const short* __restrict__ Wb, int K, int row, int koff) {
    return *(const bf16x8*)(Wb + (size_t)row * K + koff);
}
__device__ inline bf16x8 ld_f32_frag(const float* __restrict__ p) {
    float4 a = *(const float4*)p, b = *(const float4*)(p + 4);
    s16x8 s;
    s[0] = f2bf(a.x); s[1] = f2bf(a.y); s[2] = f2bf(a.z); s[3] = f2bf(a.w);
    s[4] = f2bf(b.x); s[5] = f2bf(b.y); s[6] = f2bf(b.z); s[7] = f2bf(b.w);
    return __builtin_bit_cast(bf16x8, s);
}

// ---------------------------------------------------------------------------
// Weight prepack: fp32 [rows][srcStride] -> bf16 [rowsTot][cols] (zero-pad).
// ---------------------------------------------------------------------------
#define NPACK 31
struct PrepackArgs {
    const float* src[NPACK];
    short*       dst[NPACK];
    int stride[NPACK];
    int rows[NPACK];
    int rowsTot[NPACK];
    int cols[NPACK];
};

__global__ void prepack(PrepackArgs a) {
    int e = blockIdx.y;
    int row = blockIdx.x;
    if (row >= a.rowsTot[e]) return;
    int c8 = threadIdx.x;
    if (c8 * 8 >= a.cols[e]) return;
    s16x8 s = {};
    if (row < a.rows[e]) {
        const float* p = a.src[e] + (size_t)row * a.stride[e] + c8 * 8;
        float4 x = *(const float4*)p, y = *(const float4*)(p + 4);
        s[0] = f2bf(x.x); s[1] = f2bf(x.y); s[2] = f2bf(x.z); s[3] = f2bf(x.w);
        s[4] = f2bf(y.x); s[5] = f2bf(y.y); s[6] = f2bf(y.z); s[7] = f2bf(y.w);
    }
    *(s16x8*)(a.dst[e] + (size_t)row * a.cols[e] + c8 * 8) = s;
}

// ---------------------------------------------------------------------------
// Shared epilogue: proj GEMM from ST (swizzled state tile), repacked through
// PJ (16KB) and stored coalesced to interleaved proj (node row = 256 shorts).
// accP[pc][mt][n]; wave w covers cols [64w, 64w+64) i.e. half = w>>1.
// ---------------------------------------------------------------------------
__device__ inline void proj_gemm_store(const char* ST, char* PJ,
                                       const short* __restrict__ projW,
                                       short* __restrict__ proj,
                                       int rb, int R, int tid)
{
    const int l = tid & 63, w = tid >> 6;
    f32x4 accP[2][2][4] = {};
#pragma unroll
    for (int ks = 0; ks < 4; ++ks) {
        int koff = ks * 32 + (l >> 4) * 8;
        bf16x8 aw[2][2];
#pragma unroll
        for (int pc = 0; pc < 2; ++pc)
#pragma unroll
            for (int mt = 0; mt < 2; ++mt)
                aw[pc][mt] = ldA(projW, 128, pc * 128 + 32 * w + 16 * mt + (l & 15), koff);
#pragma unroll
        for (int n = 0; n < 4; ++n) {
            bf16x8 b = ld_swz(ST, 16 * n + (l & 15), ks * 4 + (l >> 4));
#pragma unroll
            for (int pc = 0; pc < 2; ++pc)
#pragma unroll
                for (int mt = 0; mt < 2; ++mt)
                    accP[pc][mt][n] = MFMA(aw[pc][mt], b, accP[pc][mt][n]);
        }
    }
    const int half = w >> 1;
#pragma unroll
    for (int hh = 0; hh < 2; ++hh) {
        __syncthreads();
        if (half == hh) {
#pragma unroll
            for (int pc = 0; pc < 2; ++pc)
#pragma unroll
                for (int mt = 0; mt < 2; ++mt) {
                    int h0 = 32 * w + 16 * mt + ((l >> 4) << 2);
                    int colp = 2 * h0 + 4 * pc - 128 * hh;
#pragma unroll
                    for (int n = 0; n < 4; ++n) {
                        f32x4 v = accP[pc][mt][n];
                        s16x4 s4;
                        s4[0] = f2bf(v[0]); s4[1] = f2bf(v[1]);
                        s4[2] = f2bf(v[2]); s4[3] = f2bf(v[3]);
                        hid_write(PJ, colp, 16 * n + (l & 15), s4);
                    }
                }
        }
        __syncthreads();
#pragma unroll
        for (int p2 = 0; p2 < 4; ++p2) {
            int row = p2 * 16 + (tid >> 4);
            int r = rb + row;
            if (r < R) {
                bf16x8 v = ld_swz(PJ, row, tid & 15);
                *(s16x8*)(proj + (size_t)r * 256 + hh * 128 + (tid & 15) * 8) =
                    __builtin_bit_cast(s16x8, v);
            }
        }
    }
}

// ---------------------------------------------------------------------------
// dec_proj: state0 = node_feat @ dec_W^T + dec_b ; proj0 = state0 @ projW^T.
// 64 rows/block.
// ---------------------------------------------------------------------------
__global__ __launch_bounds__(256, 3)
void dec_proj(const float* __restrict__ nf, int R,
              const short* __restrict__ decWb, const float* __restrict__ bias,
              const short* __restrict__ projW,
              short* __restrict__ sOut, short* __restrict__ proj)
{
    __shared__ char ST[16384];
    __shared__ char PJ[16384];
    const int tid = threadIdx.x, l = tid & 63, w = tid >> 6;
    const int rb = blockIdx.x * 64;

    const float* brow[4];
#pragma unroll
    for (int n = 0; n < 4; ++n) {
        int row = rb + 16 * n + (l & 15); if (row >= R) row = R - 1;
        brow[n] = nf + (size_t)row * 512;
    }

    f32x4 acc[2][4] = {};
    for (int kc = 0; kc < 512; kc += 128) {
#pragma unroll
        for (int ks = 0; ks < 4; ++ks) {
            int koff = kc + ks * 32 + (l >> 4) * 8;
            bf16x8 a0 = ldA(decWb, 512, 32 * w + (l & 15), koff);
            bf16x8 a1 = ldA(decWb, 512, 32 * w + 16 + (l & 15), koff);
#pragma unroll
            for (int n = 0; n < 4; ++n) {
                bf16x8 b = ld_f32_frag(brow[n] + koff);
                acc[0][n] = MFMA(a0, b, acc[0][n]);
                acc[1][n] = MFMA(a1, b, acc[1][n]);
            }
        }
    }
#pragma unroll
    for (int mt = 0; mt < 2; ++mt) {
        int c0 = 32 * w + 16 * mt + ((l >> 4) << 2);
        float4 bv = *(const float4*)&bias[c0];
#pragma unroll
        for (int n = 0; n < 4; ++n) {
            f32x4 v = acc[mt][n];
            s16x4 s4;
            s4[0] = f2bf(v[0] + bv.x); s4[1] = f2bf(v[1] + bv.y);
            s4[2] = f2bf(v[2] + bv.z); s4[3] = f2bf(v[3] + bv.w);
            hid_write(ST, c0, 16 * n + (l & 15), s4);
        }
    }
    __syncthreads();
#pragma unroll
    for (int p2 = 0; p2 < 4; ++p2) {
        int row = p2 * 16 + (tid >> 4);
        int r = rb + row;
        if (r < R) {
            bf16x8 v = ld_swz(ST, row, tid & 15);
            *(s16x8*)(sOut + (size_t)r * 128 + (tid & 15) * 8) =
                __builtin_bit_cast(s16x8, v);
        }
    }
    proj_gemm_store(ST, PJ, projW, proj, rb, R, tid);
}

// ---------------------------------------------------------------------------
// node_fused: gi/gh GEMMs + GRU gates (+ next-layer proj). 64 rows/block.
// ---------------------------------------------------------------------------
template<int HAS_PROJ>
__global__ __launch_bounds__(256, 3)
void node_fused(const short* __restrict__ aggb, const short* __restrict__ sin_,
                const short* __restrict__ Wih, const short* __restrict__ Whh,
                const float* __restrict__ bih, const float* __restrict__ bhh,
                const short* __restrict__ projW,
                short* __restrict__ sOut, short* __restrict__ proj, int R)
{
    __shared__ char ST[16384];
    __shared__ char PJ[16384];
    const int tid = threadIdx.x, l = tid & 63, w = tid >> 6;
    const int rb = blockIdx.x * 64;

    const short* arow[4];
    const short* srow[4];
#pragma unroll
    for (int n = 0; n < 4; ++n) {
        int row = rb + 16 * n + (l & 15); if (row >= R) row = R - 1;
        arow[n] = aggb + (size_t)row * 128;
        srow[n] = sin_ + (size_t)row * 128;
    }
    // prefetch old-state values used by the gate epilogue (p==2)
    s16x4 svv[2][4];
#pragma unroll
    for (int mt = 0; mt < 2; ++mt) {
        int c0 = 32 * w + 16 * mt + ((l >> 4) << 2);
#pragma unroll
        for (int n = 0; n < 4; ++n)
            svv[mt][n] = *(const s16x4*)(srow[n] + c0);
    }

    unsigned int rpk[2][4][2], zpk[2][4][2];

    for (int p = 0; p < 3; ++p) {
        f32x4 gia[2][4] = {}, gha[2][4] = {};
#pragma unroll
        for (int ks = 0; ks < 4; ++ks) {
            int koff = ks * 32 + (l >> 4) * 8;
            bf16x8 ai0 = ldA(Wih, 128, p * 128 + 32 * w + (l & 15), koff);
            bf16x8 ai1 = ldA(Wih, 128, p * 128 + 32 * w + 16 + (l & 15), koff);
            bf16x8 ah0 = ldA(Whh, 128, p * 128 + 32 * w + (l & 15), koff);
            bf16x8 ah1 = ldA(Whh, 128, p * 128 + 32 * w + 16 + (l & 15), koff);
#pragma unroll
            for (int n = 0; n < 4; ++n) {
                bf16x8 ba = *(const bf16x8*)(arow[n] + koff);
                bf16x8 bs = *(const bf16x8*)(srow[n] + koff);
                gia[0][n] = MFMA(ai0, ba, gia[0][n]);
                gia[1][n] = MFMA(ai1, ba, gia[1][n]);
                gha[0][n] = MFMA(ah0, bs, gha[0][n]);
                gha[1][n] = MFMA(ah1, bs, gha[1][n]);
            }
        }
#pragma unroll
        for (int mt = 0; mt < 2; ++mt) {
            int c0 = 32 * w + 16 * mt + ((l >> 4) << 2);
            float4 bi = *(const float4*)&bih[p * 128 + c0];
            float4 bh = *(const float4*)&bhh[p * 128 + c0];
            float biv[4] = {bi.x, bi.y, bi.z, bi.w};
            float bhv[4] = {bh.x, bh.y, bh.z, bh.w};
#pragma unroll
            for (int n = 0; n < 4; ++n) {
                float gv[4], hv[4];
#pragma unroll
                for (int q = 0; q < 4; ++q) {
                    gv[q] = gia[mt][n][q] + biv[q];
                    hv[q] = gha[mt][n][q] + bhv[q];
                }
                if (p == 0) {
                    rpk[mt][n][0] = pk2(1.f / (1.f + expf(-(gv[0] + hv[0]))),
                                        1.f / (1.f + expf(-(gv[1] + hv[1]))));
                    rpk[mt][n][1] = pk2(1.f / (1.f + expf(-(gv[2] + hv[2]))),
                                        1.f / (1.f + expf(-(gv[3] + hv[3]))));
                } else if (p == 1) {
                    zpk[mt][n][0] = pk2(1.f / (1.f + expf(-(gv[0] + hv[0]))),
                                        1.f / (1.f + expf(-(gv[1] + hv[1]))));
                    zpk[mt][n][1] = pk2(1.f / (1.f + expf(-(gv[2] + hv[2]))),
                                        1.f / (1.f + expf(-(gv[3] + hv[3]))));
                } else {
                    s16x4 s4;
#pragma unroll
                    for (int q = 0; q < 4; ++q) {
                        unsigned int ru = rpk[mt][n][q >> 1], zu = zpk[mt][n][q >> 1];
                        float r = bf2f((unsigned short)((q & 1) ? (ru >> 16) : (ru & 0xffffu)));
                        float z = bf2f((unsigned short)((q & 1) ? (zu >> 16) : (zu & 0xffffu)));
                        float nn = tanhf(gv[q] + r * hv[q]);
                        float o = (1.f - z) * nn + z * bf2f((unsigned short)svv[mt][n][q]);
                        s4[q] = f2bf(HAS_PROJ ? fmaxf(o, 0.f) : o);
                    }
                    hid_write(ST, c0, 16 * n + (l & 15), s4);
                }
            }
        }
    }
    __syncthreads();
#pragma unroll
    for (int p2 = 0; p2 < 4; ++p2) {
        int row = p2 * 16 + (tid >> 4);
        int r = rb + row;
        if (r < R) {
            bf16x8 v = ld_swz(ST, row, tid & 15);
            *(s16x8*)(sOut + (size_t)r * 128 + (tid & 15) * 8) =
                __builtin_bit_cast(s16x8, v);
        }
    }
    if (HAS_PROJ)
        proj_gemm_store(ST, PJ, projW, proj, rb, R, tid);
}

// ---------------------------------------------------------------------------
// Fused edge MLPs, CSR order, 64 edges/block, proj gathers register-prefetched.
// ---------------------------------------------------------------------------
__global__ __launch_bounds__(256, 3)
void edge_fused2(const short* __restrict__ efc,
                 const int* __restrict__ srcs, const int* __restrict__ dsts,
                 const short* __restrict__ proj,    // N x 256 interleaved
                 const short* __restrict__ mW1b, const short* __restrict__ mW2,
                 const short* __restrict__ aW1b, const short* __restrict__ aW2,
                 const float* __restrict__ mb1, const float* __restrict__ mb2,
                 const float* __restrict__ ab1, const float* __restrict__ ab2,
                 short* __restrict__ msgatt, int M, int ntiles)
{
    __shared__ char HIDm[16384];
    __shared__ char HIDa[16384];
    const int tid = threadIdx.x, l = tid & 63, w = tid >> 6;
    int q = ntiles >> 3, r = ntiles & 7;
    int xcd = blockIdx.x & 7, o = blockIdx.x >> 3;
    int tile = (xcd < r ? xcd * (q + 1) : r * (q + 1) + (xcd - r) * q) + o;
    const int pb = tile * 64;

    const char* erow[4];
    s16x8 psv[2][4], pdv[2][4];
    {
#pragma unroll
        for (int n = 0; n < 4; ++n) {
            int pos = pb + 16 * n + (l & 15); if (pos >= M) pos = M - 1;
            int sv = srcs[pos], dv = dsts[pos];
            erow[n] = (const char*)(efc + (size_t)pos * 128);
            // issue gather loads early — consumed after GEMM1 (latency hidden)
#pragma unroll
            for (int mt = 0; mt < 2; ++mt) {
                int off = 2 * (32 * w + 16 * mt + ((l >> 4) << 2));
                psv[mt][n] = *(const s16x8*)(proj + (size_t)sv * 256 + off);
                pdv[mt][n] = *(const s16x8*)(proj + (size_t)dv * 256 + off);
            }
        }
    }

    // GEMM1 combined (msg+att share ef B-operand)
    f32x4 accm[2][4] = {}, acca[2][4] = {};
#pragma unroll
    for (int ks = 0; ks < 4; ++ks) {
        int koff = ks * 32 + (l >> 4) * 8;
        bf16x8 am0 = ldA(mW1b, 128, 32 * w + (l & 15), koff);
        bf16x8 am1 = ldA(mW1b, 128, 32 * w + 16 + (l & 15), koff);
        bf16x8 aa0 = ldA(aW1b, 128, 32 * w + (l & 15), koff);
        bf16x8 aa1 = ldA(aW1b, 128, 32 * w + 16 + (l & 15), koff);
#pragma unroll
        for (int n = 0; n < 4; ++n) {
            bf16x8 b = *(const bf16x8*)(erow[n] + koff * 2);
            accm[0][n] = MFMA(am0, b, accm[0][n]);
            accm[1][n] = MFMA(am1, b, accm[1][n]);
            acca[0][n] = MFMA(aa0, b, acca[0][n]);
            acca[1][n] = MFMA(aa1, b, acca[1][n]);
        }
    }
    // epilogue 1: bias + prefetched proj diff, relu -> HID
#pragma unroll
    for (int mt = 0; mt < 2; ++mt) {
        int h0 = 32 * w + 16 * mt + ((l >> 4) << 2);
        float4 bm = *(const float4*)&mb1[h0];
        float4 ba = *(const float4*)&ab1[h0];
        float bmv[4] = {bm.x, bm.y, bm.z, bm.w};
        float bav[4] = {ba.x, ba.y, ba.z, ba.w};
#pragma unroll
        for (int n = 0; n < 4; ++n) {
            s16x8 ps = psv[mt][n], pd = pdv[mt][n];
            f32x4 vm = accm[mt][n], va = acca[mt][n];
            s16x4 sm, sa;
#pragma unroll
            for (int qq = 0; qq < 4; ++qq) {
                float m_ = vm[qq] + bmv[qq] + bf2f((unsigned short)ps[qq])
                           - bf2f((unsigned short)pd[qq]);
                float a_ = va[qq] + bav[qq] + bf2f((unsigned short)ps[qq + 4])
                           - bf2f((unsigned short)pd[qq + 4]);
                sm[qq] = f2bf(fmaxf(m_, 0.f));
                sa[qq] = f2bf(fmaxf(a_, 0.f));
            }
            hid_write(HIDm, h0, 16 * n + (l & 15), sm);
            hid_write(HIDa, h0, 16 * n + (l & 15), sa);
        }
    }
    __syncthreads();

    // GEMM2 combined
    f32x4 acc2m[2][4] = {}, acc2a[2][4] = {};
#pragma unroll
    for (int ks = 0; ks < 4; ++ks) {
        int koff = ks * 32 + (l >> 4) * 8;
        bf16x8 wm0 = ldA(mW2, 128, 32 * w + (l & 15), koff);
        bf16x8 wm1 = ldA(mW2, 128, 32 * w + 16 + (l & 15), koff);
        bf16x8 wa0 = ldA(aW2, 128, 32 * w + (l & 15), koff);
        bf16x8 wa1 = ldA(aW2, 128, 32 * w + 16 + (l & 15), koff);
#pragma unroll
        for (int n = 0; n < 4; ++n) {
            bf16x8 bm = ld_swz(HIDm, 16 * n + (l & 15), ks * 4 + (l >> 4));
            bf16x8 ba = ld_swz(HIDa, 16 * n + (l & 15), ks * 4 + (l >> 4));
            acc2m[0][n] = MFMA(wm0, bm, acc2m[0][n]);
            acc2m[1][n] = MFMA(wm1, bm, acc2m[1][n]);
            acc2a[0][n] = MFMA(wa0, ba, acc2a[0][n]);
            acc2a[1][n] = MFMA(wa1, ba, acc2a[1][n]);
        }
    }
    __syncthreads();                // HID reads done; reuse HIDm for output
#pragma unroll
    for (int mt = 0; mt < 2; ++mt) {
        int c0 = 32 * w + 16 * mt + ((l >> 4) << 2);
        float4 bm2 = *(const float4*)&mb2[c0];
        float4 ba2 = *(const float4*)&ab2[c0];
#pragma unroll
        for (int n = 0; n < 4; ++n) {
            f32x4 m_ = acc2m[mt][n], a_ = acc2a[mt][n];
            float o0 = (m_[0] + bm2.x) / (1.f + expf(-(a_[0] + ba2.x)));
            float o1 = (m_[1] + bm2.y) / (1.f + expf(-(a_[1] + ba2.y)));
            float o2 = (m_[2] + bm2.z) / (1.f + expf(-(a_[2] + ba2.z)));
            float o3 = (m_[3] + bm2.w) / (1.f + expf(-(a_[3] + ba2.w)));
            s16x4 s4;
            s4[0] = f2bf(o0); s4[1] = f2bf(o1); s4[2] = f2bf(o2); s4[3] = f2bf(o3);
            hid_write(HIDm, c0, 16 * n + (l & 15), s4);
        }
    }
    __syncthreads();
#pragma unroll
    for (int p2 = 0; p2 < 4; ++p2) {
        int row = p2 * 16 + (tid >> 4);
        int pos = pb + row;
        if (pos < M) {
            bf16x8 v = ld_swz(HIDm, row, tid & 15);
            *(s16x8*)(msgatt + (size_t)pos * 128 + (tid & 15) * 8) =
                __builtin_bit_cast(s16x8, v);
        }
    }
}

// ---------------------------------------------------------------------------
// mlp_loss: 64 edges/block — d2 tile, theta & alpha 3-layer MLPs, loss reduce.
// ---------------------------------------------------------------------------
__global__ __launch_bounds__(256, 4)
void mlp_loss(const short* __restrict__ sP, const int* __restrict__ gidx,
              const float* __restrict__ label, const int* __restrict__ sg,
              const short* __restrict__ thW1, const short* __restrict__ thW2,
              const short* __restrict__ thW3,
              const float* __restrict__ thb1, const float* __restrict__ thb2,
              const float* __restrict__ thb3,
              const short* __restrict__ alW1, const short* __restrict__ alW2,
              const short* __restrict__ alW3,
              const float* __restrict__ alb1, const float* __restrict__ alb2,
              const float* __restrict__ alb3,
              float* __restrict__ radj, float* __restrict__ rla,
              float* __restrict__ cntS, int E, int S)
{
    __shared__ char D2T[16384];
    __shared__ char HID[16384];
    __shared__ float sadj[2][20];
    __shared__ float sla[2][20];
    __shared__ float scnt[2];
    __shared__ int sbase;
    const int tid = threadIdx.x, l = tid & 63, w = tid >> 6;
    const int eb = blockIdx.x * 64;

    if (tid == 0) sbase = sg[eb];
    if (tid < 40) { sadj[tid / 20][tid % 20] = 0.f; sla[tid / 20][tid % 20] = 0.f; }
    if (tid < 2) scnt[tid] = 0.f;

    // build d2 tile (64 rows x 16 units)
    for (int i = tid; i < 64 * 16; i += 256) {
        int row = i >> 4, u = i & 15;
        int e = eb + row; if (e >= E) e = E - 1;
        int2 ab = *(const int2*)&gidx[2 * (size_t)e];
        s16x8 x = *(const s16x8*)(sP + (size_t)ab.x * 128 + u * 8);
        s16x8 y = *(const s16x8*)(sP + (size_t)ab.y * 128 + u * 8);
        s16x8 d;
#pragma unroll
        for (int j = 0; j < 8; ++j)
            d[j] = f2bf(bf2f((unsigned short)x[j]) - bf2f((unsigned short)y[j]));
        *(s16x8*)(D2T + row * 256 + ((u ^ (row & 7)) << 4)) = d;
    }
    __syncthreads();

    for (int pass = 0; pass < 2; ++pass) {
        const short* W1 = pass ? alW1 : thW1;
        const short* W2 = pass ? alW2 : thW2;
        const short* W3 = pass ? alW3 : thW3;
        const float* b1 = pass ? alb1 : thb1;
        const float* b2 = pass ? alb2 : thb2;
        const float* b3 = pass ? alb3 : thb3;

        // stage 1
        f32x4 acc[2][4] = {};
#pragma unroll
        for (int ks = 0; ks < 4; ++ks) {
            int koff = ks * 32 + (l >> 4) * 8;
            bf16x8 a0 = ldA(W1, 128, 32 * w + (l & 15), koff);
            bf16x8 a1 = ldA(W1, 128, 32 * w + 16 + (l & 15), koff);
#pragma unroll
            for (int n = 0; n < 4; ++n) {
                bf16x8 b = ld_swz(D2T, 16 * n + (l & 15), ks * 4 + (l >> 4));
                acc[0][n] = MFMA(a0, b, acc[0][n]);
                acc[1][n] = MFMA(a1, b, acc[1][n]);
            }
        }
        __syncthreads();   // prior-pass HID readers done
#pragma unroll
        for (int mt = 0; mt < 2; ++mt) {
            int h0 = 32 * w + 16 * mt + ((l >> 4) << 2);
            float4 bv = *(const float4*)&b1[h0];
#pragma unroll
            for (int n = 0; n < 4; ++n) {
                f32x4 v = acc[mt][n];
                s16x4 s4;
                s4[0] = f2bf(fmaxf(v[0] + bv.x, 0.f));
                s4[1] = f2bf(fmaxf(v[1] + bv.y, 0.f));
                s4[2] = f2bf(fmaxf(v[2] + bv.z, 0.f));
                s4[3] = f2bf(fmaxf(v[3] + bv.w, 0.f));
                hid_write(HID, h0, 16 * n + (l & 15), s4);
            }
        }
        __syncthreads();
        // stage 2
        f32x4 acc2[2][4] = {};
#pragma unroll
        for (int ks = 0; ks < 4; ++ks) {
            int koff = ks * 32 + (l >> 4) * 8;
            bf16x8 a0 = ldA(W2, 128, 32 * w + (l & 15), koff);
            bf16x8 a1 = ldA(W2, 128, 32 * w + 16 + (l & 15), koff);
#pragma unroll
            for (int n = 0; n < 4; ++n) {
                bf16x8 b = ld_swz(HID, 16 * n + (l & 15), ks * 4 + (l >> 4));
                acc2[0][n] = MFMA(a0, b, acc2[0][n]);
                acc2[1][n] = MFMA(a1, b, acc2[1][n]);
            }
        }
        __syncthreads();
#pragma unroll
        for (int mt = 0; mt < 2; ++mt) {
            int h0 = 32 * w + 16 * mt + ((l >> 4) << 2);
            float4 bv = *(const float4*)&b2[h0];
#pragma unroll
            for (int n = 0; n < 4; ++n) {
                f32x4 v = acc2[mt][n];
                s16x4 s4;
                s4[0] = f2bf(fmaxf(v[0] + bv.x, 0.f));
                s4[1] = f2bf(fmaxf(v[1] + bv.y, 0.f));
                s4[2] = f2bf(fmaxf(v[2] + bv.z, 0.f));
                s4[3] = f2bf(fmaxf(v[3] + bv.w, 0.f));
                hid_write(HID, h0, 16 * n + (l & 15), s4);
            }
        }
        __syncthreads();
        // stage 3: each wave owns edge-fragment n = w
        f32x4 acc3[2] = {};
#pragma unroll
        for (int ks = 0; ks < 4; ++ks) {
            int koff = ks * 32 + (l >> 4) * 8;
            bf16x8 a0 = ldA(W3, 128, (l & 15), koff);
            bf16x8 a1 = ldA(W3, 128, 16 + (l & 15), koff);
            bf16x8 b = ld_swz(HID, 16 * w + (l & 15), ks * 4 + (l >> 4));
            acc3[0] = MFMA(a0, b, acc3[0]);
            acc3[1] = MFMA(a1, b, acc3[1]);
        }
        {
            int e = eb + 16 * w + (l & 15);
            if (e < E) {
                int ls = sg[e] - sbase;
                if (ls < 0) ls = 0; if (ls > 1) ls = 1;
                float y = (pass == 0) ? label[e] : 0.f;
#pragma unroll
                for (int mt = 0; mt < 2; ++mt) {
                    int c0 = 16 * mt + ((l >> 4) << 2);
                    if (c0 < 20) {
#pragma unroll
                        for (int qq = 0; qq < 4; ++qq) {
                            int k = c0 + qq;
                            if (k < 20) {
                                float t = acc3[mt][qq] + b3[k];
                                if (pass == 0) {
                                    float sp = fmaxf(-t, 0.f) + log1pf(expf(-fabsf(t)));
                                    atomicAdd(&sadj[ls][k], sp + (1.f - y) * t);
                                } else {
                                    atomicAdd(&sla[ls][k], t);
                                }
                            }
                        }
                    }
                }
            }
        }
        __syncthreads();
    }

    if (tid < 64) {
        int e = eb + tid;
        if (e < E) {
            int ls = sg[e] - sbase;
            if (ls >= 0 && ls < 2) atomicAdd(&scnt[ls], 1.f);
        }
    }
    __syncthreads();
    if (tid < 40) {
        int ls = tid / 20, k = tid % 20;
        int s = sbase + ls;
        if (s < S) {
            float v = sadj[ls][k], v2 = sla[ls][k];
            if (v  != 0.f) atomicAdd(&radj[s * 20 + k], v);
            if (v2 != 0.f) atomicAdd(&rla[s * 20 + k], v2);
        }
    }
    if (tid < 2) {
        int s = sbase + tid;
        if (s < S && scnt[tid] != 0.f) atomicAdd(&cntS[s], scnt[tid]);
    }
}

// ---------------------------------------------------------------------------
// CSR build + gathers + aggregation
// ---------------------------------------------------------------------------
__global__ void csr_count(const int* __restrict__ edge, int* __restrict__ cnt, int M) {
    int e = blockIdx.x * 256 + threadIdx.x;
    if (e < M) atomicAdd(&cnt[edge[2 * (size_t)e + 1]], 1);
}

__global__ void csr_scan(const int* __restrict__ cnt, int* __restrict__ rowptr,
                         int* __restrict__ wofs, int N)
{
    __shared__ int part[1024];
    int t = threadIdx.x;
    int chunk = (N + 1023) / 1024;
    int b0 = t * chunk, b1 = b0 + chunk; if (b1 > N) b1 = N; if (b0 > N) b0 = N;
    int s = 0;
    for (int i = b0; i < b1; ++i) s += cnt[i];
    part[t] = s;
    __syncthreads();
    for (int off = 1; off < 1024; off <<= 1) {
        int v = (t >= off) ? part[t - off] : 0;
        __syncthreads();
        part[t] += v;
        __syncthreads();
    }
    int run = (t ? part[t - 1] : 0);
    for (int i = b0; i < b1; ++i) { rowptr[i] = run; wofs[i] = run; run += cnt[i]; }
    if (t == 1023) rowptr[N] = run;
}

__global__ void csr_scatter2(const int* __restrict__ edge, int* __restrict__ wofs,
                             int* __restrict__ eidx, int* __restrict__ srcs,
                             int* __restrict__ dsts, int M)
{
    int e = blockIdx.x * 256 + threadIdx.x;
    if (e < M) {
        int2 sd = *(const int2*)&edge[2 * (size_t)e];
        int p = atomicAdd(&wofs[sd.y], 1);
        eidx[p] = e; srcs[p] = sd.x; dsts[p] = sd.y;
    }
}

__global__ void ef_gather(const float* __restrict__ ef, const int* __restrict__ eidx,
                          short* __restrict__ efc, int M)
{
    long i = (long)blockIdx.x * 256 + threadIdx.x;
    if (i >= (long)M * 16) return;
    int p = (int)(i >> 4), u = (int)(i & 15);
    int e = eidx[p];
    const float* sp = ef + (size_t)e * 128 + u * 8;
    float4 a = *(const float4*)sp, b = *(const float4*)(sp + 4);
    s16x8 s;
    s[0] = f2bf(a.x); s[1] = f2bf(a.y); s[2] = f2bf(a.z); s[3] = f2bf(a.w);
    s[4] = f2bf(b.x); s[5] = f2bf(b.y); s[6] = f2bf(b.z); s[7] = f2bf(b.w);
    *(s16x8*)(efc + (size_t)p * 128 + u * 8) = s;
}

__global__ __launch_bounds__(256)
void agg_gather2(const short* __restrict__ msgatt, const int* __restrict__ rowptr,
                 short* __restrict__ aggb, int N)
{
    int v = (blockIdx.x * 256 + threadIdx.x) >> 6;
    int l = threadIdx.x & 63;
    if (v >= N) return;
    int b = rowptr[v], e = rowptr[v + 1];
    float sx = 0.f, sy = 0.f;
    for (int i = b; i < e; ++i) {
        unsigned int u = *(const unsigned int*)(msgatt + (size_t)i * 128 + 2 * l);
        sx += bf2f((unsigned short)(u & 0xffffu));
        sy += bf2f((unsigned short)(u >> 16));
    }
    unsigned int o = ((unsigned int)f2bf(sy) << 16) | f2bf(sx);
    *(unsigned int*)(aggb + (size_t)v * 128 + 2 * l) = o;
}

// ---------------------------------------------------------------------------
__global__ void final_kernel(const float* __restrict__ radj, const float* __restrict__ rla,
                             const float* __restrict__ cnt, const int* __restrict__ bc_idx,
                             float* __restrict__ out)
{
    __shared__ float bcl[16], bcc[16];
    const int s = threadIdx.x;
    if (s < 16) { bcl[s] = 0.f; bcc[s] = 0.f; }
    __syncthreads();
    float c = cnt[s];
    float x[20];
    float mx = -1e30f;
#pragma unroll
    for (int k = 0; k < 20; ++k) { x[k] = rla[s * 20 + k] / c; mx = fmaxf(mx, x[k]); }
    float se = 0.f;
#pragma unroll
    for (int k = 0; k < 20; ++k) se += expf(x[k] - mx);
    float lse = mx + logf(se);
    float t[20];
    float m2 = -1e30f;
#pragma unroll
    for (int k = 0; k < 20; ++k) { t[k] = -radj[s * 20 + k] + x[k] - lse; m2 = fmaxf(m2, t[k]); }
    float s2 = 0.f;
#pragma unroll
    for (int k = 0; k < 20; ++k) s2 += expf(t[k] - m2);
    float lp = m2 + logf(s2);
    atomicAdd(&bcl[bc_idx[s]], lp);
    atomicAdd(&bcc[bc_idx[s]], c);
    __syncthreads();
    if (s == 0) {
        float a = 0.f;
        for (int b = 0; b < 16; ++b) a += bcl[b] / bcc[b];
        out[0] = -a / 16.f;
    }
}

// ---------------------------------------------------------------------------
extern "C" void kernel_launch(void* const* d_in, const int* in_sizes, int n_in,
                              void* d_out, int out_size, void* d_ws, size_t ws_size,
                              hipStream_t stream)
{
    const float* node_feat = (const float*)d_in[0];
    const int*   edge      = (const int*)  d_in[1];
    const float* edge_feat = (const float*)d_in[2];
    const int*   gnn_idx   = (const int*)  d_in[3];
    const float* label     = (const float*)d_in[4];
    const int*   sg_idx    = (const int*)  d_in[5];
    const int*   bc_idx    = (const int*)  d_in[6];
    const float* dec_W  = (const float*)d_in[7];
    const float* dec_b  = (const float*)d_in[8];
    const float* msg_W1 = (const float*)d_in[9];
    const float* msg_b1 = (const float*)d_in[10];
    const float* msg_W2 = (const float*)d_in[11];
    const float* msg_b2 = (const float*)d_in[12];
    const float* att_W1 = (const float*)d_in[13];
    const float* att_b1 = (const float*)d_in[14];
    const float* att_W2 = (const float*)d_in[15];
    const float* att_b2 = (const float*)d_in[16];
    const float* gru_Wih = (const float*)d_in[17];
    const float* gru_bih = (const float*)d_in[18];
    const float* gru_Whh = (const float*)d_in[19];
    const float* gru_bhh = (const float*)d_in[20];
    const float* th_W1 = (const float*)d_in[21];
    const float* th_b1 = (const float*)d_in[22];
    const float* th_W2 = (const float*)d_in[23];
    const float* th_b2 = (const float*)d_in[24];
    const float* th_W3 = (const float*)d_in[25];
    const float* th_b3 = (const float*)d_in[26];
    const float* al_W1 = (const float*)d_in[27];
    const float* al_b1 = (const float*)d_in[28];
    const float* al_W2 = (const float*)d_in[29];
    const float* al_b2 = (const float*)d_in[30];
    const float* al_W3 = (const float*)d_in[31];
    const float* al_b3 = (const float*)d_in[32];

    const int N = in_sizes[0] / 512;
    const int M = in_sizes[1] / 2;
    const int E = in_sizes[3] / 2;
    const int S = in_sizes[6];

    size_t off = 0;
    auto alloc = [&](size_t bytes) {
        char* p = (char*)d_ws + off;
        off += (bytes + 255) & ~(size_t)255;
        return p;
    };
    // bf16 weight slabs
    short* decWb  = (short*)alloc((size_t)128 * 512 * 2);
    short* projWb = (short*)alloc((size_t)3 * 256 * 128 * 2);
    short* mW1bB  = (short*)alloc((size_t)3 * 128 * 128 * 2);
    short* aW1bB  = (short*)alloc((size_t)3 * 128 * 128 * 2);
    short* mW2B   = (short*)alloc((size_t)3 * 128 * 128 * 2);
    short* aW2B   = (short*)alloc((size_t)3 * 128 * 128 * 2);
    short* gihB   = (short*)alloc((size_t)3 * 384 * 128 * 2);
    short* ghhB   = (short*)alloc((size_t)3 * 384 * 128 * 2);
    short* thW1B  = (short*)alloc((size_t)128 * 128 * 2);
    short* thW2B  = (short*)alloc((size_t)128 * 128 * 2);
    short* thW3B  = (short*)alloc((size_t)32 * 128 * 2);
    short* alW1B  = (short*)alloc((size_t)128 * 128 * 2);
    short* alW2B  = (short*)alloc((size_t)128 * 128 * 2);
    short* alW3B  = (short*)alloc((size_t)32 * 128 * 2);
    // activations
    short* sA     = (short*)alloc((size_t)N * 128 * 2);
    short* sB     = (short*)alloc((size_t)N * 128 * 2);
    short* sP     = (short*)alloc((size_t)N * 128 * 2);
    short* efc    = (short*)alloc((size_t)M * 128 * 2);
    short* msgatt = (short*)alloc((size_t)M * 128 * 2);
    short* proj   = (short*)alloc((size_t)N * 256 * 2);
    short* aggb   = (short*)alloc((size_t)N * 128 * 2);
    int*   cntN   = (int*)  alloc((size_t)N * 4);
    int*   wofs   = (int*)  alloc((size_t)N * 4);
    int*   rowptr = (int*)  alloc((size_t)(N + 1) * 4);
    int*   eidx   = (int*)  alloc((size_t)M * 4);
    int*   srcs   = (int*)  alloc((size_t)M * 4);
    int*   dsts   = (int*)  alloc((size_t)M * 4);
    float* radj   = (float*)alloc((size_t)S * 20 * 4);
    float* rla    = (float*)alloc((size_t)S * 20 * 4);
    float* cntS   = (float*)alloc((size_t)S * 4);

    // ---- prepack descriptor table ----
    PrepackArgs pa;
    int ei = 0;
    auto add = [&](const float* s, short* d, int stride, int rows, int rowsTot, int cols) {
        pa.src[ei] = s; pa.dst[ei] = d; pa.stride[ei] = stride;
        pa.rows[ei] = rows; pa.rowsTot[ei] = rowsTot; pa.cols[ei] = cols; ++ei;
    };
    add(dec_W, decWb, 512, 128, 128, 512);
    for (int l = 0; l < 3; ++l) {
        add(msg_W1 + (size_t)l * 128 * 256,       projWb + (size_t)l * 256 * 128,          256, 128, 128, 128);
        add(att_W1 + (size_t)l * 128 * 256,       projWb + (size_t)l * 256 * 128 + 16384,  256, 128, 128, 128);
        add(msg_W1 + (size_t)l * 128 * 256 + 128, mW1bB + (size_t)l * 16384,               256, 128, 128, 128);
        add(att_W1 + (size_t)l * 128 * 256 + 128, aW1bB + (size_t)l * 16384,               256, 128, 128, 128);
        add(msg_W2 + (size_t)l * 16384,           mW2B + (size_t)l * 16384,                128, 128, 128, 128);
        add(att_W2 + (size_t)l * 16384,           aW2B + (size_t)l * 16384,                128, 128, 128, 128);
        add(gru_Wih + (size_t)l * 49152,          gihB + (size_t)l * 49152,                128, 384, 384, 128);
        add(gru_Whh + (size_t)l * 49152,          ghhB + (size_t)l * 49152,                128, 384, 384, 128);
    }
    add(th_W1, thW1B, 128, 128, 128, 128);
    add(th_W2, thW2B, 128, 128, 128, 128);
    add(th_W3, thW3B, 128, 20, 32, 128);
    add(al_W1, alW1B, 128, 128, 128, 128);
    add(al_W2, alW2B, 128, 128, 128, 128);
    add(al_W3, alW3B, 128, 20, 32, 128);

    const dim3 blk(256);
    const int gN64 = (N + 63) / 64;
    const int gE64 = (E + 63) / 64;
    const int gMt  = (M + 255) / 256;
    const int ntilesM = (M + 63) / 64;

    hipMemsetAsync(radj, 0, (size_t)(S * 20 * 2 + S) * 4, stream);
    hipMemsetAsync(cntN, 0, (size_t)N * 4, stream);

    prepack<<<dim3(384, NPACK), dim3(64), 0, stream>>>(pa);

    csr_count   <<<gMt, blk, 0, stream>>>(edge, cntN, M);
    csr_scan    <<<1, 1024, 0, stream>>>(cntN, rowptr, wofs, N);
    csr_scatter2<<<gMt, blk, 0, stream>>>(edge, wofs, eidx, srcs, dsts, M);
    ef_gather   <<<(int)(((long)M * 16 + 255) / 256), blk, 0, stream>>>(edge_feat, eidx, efc, M);

    // decoder + proj0
    dec_proj<<<gN64, blk, 0, stream>>>(node_feat, N, decWb, dec_b, projWb, sA, proj);

    short* bufs[2] = { sA, sB };
    for (int l = 0; l < 3; ++l) {
        short* sin  = bufs[l & 1];
        short* sout = (l == 2) ? sP : bufs[(l + 1) & 1];
        edge_fused2<<<ntilesM, blk, 0, stream>>>(efc, srcs, dsts, proj,
            mW1bB + (size_t)l * 16384, mW2B + (size_t)l * 16384,
            aW1bB + (size_t)l * 16384, aW2B + (size_t)l * 16384,
            msg_b1 + l * 128, msg_b2 + l * 128,
            att_b1 + l * 128, att_b2 + l * 128,
            msgatt, M, ntilesM);
        agg_gather2<<<(N * 64 + 255) / 256, blk, 0, stream>>>(msgatt, rowptr, aggb, N);
        if (l < 2) {
            node_fused<1><<<gN64, blk, 0, stream>>>(aggb, sin,
                gihB + (size_t)l * 49152, ghhB + (size_t)l * 49152,
                gru_bih + l * 384, gru_bhh + l * 384,
                projWb + (size_t)(l + 1) * 256 * 128, sout, proj, N);
        } else {
            node_fused<0><<<gN64, blk, 0, stream>>>(aggb, sin,
                gihB + (size_t)l * 49152, ghhB + (size_t)l * 49152,
                gru_bih + l * 384, gru_bhh + l * 384,
                nullptr, sout, nullptr, N);
        }
    }

    mlp_loss<<<gE64, blk, 0, stream>>>(sP, gnn_idx, label, sg_idx,
        thW1B, thW2B, thW3B, th_b1, th_b2, th_b3,
        alW1B, alW2B, alW3B, al_b1, al_b2, al_b3,
        radj, rla, cntS, E, S);
    final_kernel<<<1, S, 0, stream>>>(radj, rla, cntS, bc_idx, (float*)d_out);
}

// Round 7
// 1204.615 us; speedup vs baseline: 10.8160x; 1.1884x over previous
//
#include <hip/hip_runtime.h>
#include <cstdint>
#include <cstddef>

// GRAN mixture-Bernoulli forward — R7: fix forced register spill in node_fused
// (launch_bounds 3->2; bound-3 cap of ~168 unified regs forced accumulator
// arrays to scratch: 276MB extra HBM write per dispatch), 4-node/wave
// aggregation with 16B lane loads.
// Sizes: N=50000, M=250000, E=200000, H=EF=ATT=128, K=20, L=3, S=512.

typedef __bf16 bf16x8 __attribute__((ext_vector_type(8)));
typedef short  s16x8  __attribute__((ext_vector_type(8)));
typedef short  s16x4  __attribute__((ext_vector_type(4)));
typedef float  f32x4  __attribute__((ext_vector_type(4)));

__device__ inline unsigned short f2bf(float f) {
    return __builtin_bit_cast(unsigned short, (__bf16)f);
}
__device__ inline float bf2f(unsigned short b) {
    return __uint_as_float(((unsigned int)b) << 16);
}
__device__ inline unsigned int pk2(float a, float b) {
    return ((unsigned int)f2bf(b) << 16) | f2bf(a);
}
__device__ inline f32x4 MFMA(bf16x8 a, bf16x8 b, f32x4 c) {
    return __builtin_amdgcn_mfma_f32_16x16x32_bf16(a, b, c, 0, 0, 0);
}

// Swizzled LDS tile: [rows][128 bf16] = 256B/row, 16B unit u stored at u^(row&7).
__device__ inline bf16x8 ld_swz(const char* lds, int row, int unit) {
    return *(const bf16x8*)(lds + row * 256 + ((unit ^ (row & 7)) << 4));
}
__device__ inline void hid_write(char* HID, int h0, int erow, s16x4 s4) {
    int unit = h0 >> 3;
    *(s16x4*)(HID + erow * 256 + ((unit ^ (erow & 7)) << 4) + ((h0 & 4) << 1)) = s4;
}
__device__ inline bf16x8 ldA(const short* __restrict__ Wb, int K, int row, int koff) {
    return *(const bf16x8*)(Wb + (size_t)row * K + koff);
}
__device__ inline bf16x8 ld_f32_frag(const float* __restrict__ p) {
    float4 a = *(const float4*)p, b = *(const float4*)(p + 4);
    s16x8 s;
    s[0] = f2bf(a.x); s[1] = f2bf(a.y); s[2] = f2bf(a.z); s[3] = f2bf(a.w);
    s[4] = f2bf(b.x); s[5] = f2bf(b.y); s[6] = f2bf(b.z); s[7] = f2bf(b.w);
    return __builtin_bit_cast(bf16x8, s);
}

// ---------------------------------------------------------------------------
// Weight prepack: fp32 [rows][srcStride] -> bf16 [rowsTot][cols] (zero-pad).
// ---------------------------------------------------------------------------
#define NPACK 31
struct PrepackArgs {
    const float* src[NPACK];
    short*       dst[NPACK];
    int stride[NPACK];
    int rows[NPACK];
    int rowsTot[NPACK];
    int cols[NPACK];
};

__global__ void prepack(PrepackArgs a) {
    int e = blockIdx.y;
    int row = blockIdx.x;
    if (row >= a.rowsTot[e]) return;
    int c8 = threadIdx.x;
    if (c8 * 8 >= a.cols[e]) return;
    s16x8 s = {};
    if (row < a.rows[e]) {
        const float* p = a.src[e] + (size_t)row * a.stride[e] + c8 * 8;
        float4 x = *(const float4*)p, y = *(const float4*)(p + 4);
        s[0] = f2bf(x.x); s[1] = f2bf(x.y); s[2] = f2bf(x.z); s[3] = f2bf(x.w);
        s[4] = f2bf(y.x); s[5] = f2bf(y.y); s[6] = f2bf(y.z); s[7] = f2bf(y.w);
    }
    *(s16x8*)(a.dst[e] + (size_t)row * a.cols[e] + c8 * 8) = s;
}

// ---------------------------------------------------------------------------
// Shared epilogue: proj GEMM from ST (swizzled state tile), repacked through
// PJ (16KB) and stored coalesced to interleaved proj (node row = 256 shorts).
// ---------------------------------------------------------------------------
__device__ inline void proj_gemm_store(const char* ST, char* PJ,
                                       const short* __restrict__ projW,
                                       short* __restrict__ proj,
                                       int rb, int R, int tid)
{
    const int l = tid & 63, w = tid >> 6;
    f32x4 accP[2][2][4] = {};
#pragma unroll
    for (int ks = 0; ks < 4; ++ks) {
        int koff = ks * 32 + (l >> 4) * 8;
        bf16x8 aw[2][2];
#pragma unroll
        for (int pc = 0; pc < 2; ++pc)
#pragma unroll
            for (int mt = 0; mt < 2; ++mt)
                aw[pc][mt] = ldA(projW, 128, pc * 128 + 32 * w + 16 * mt + (l & 15), koff);
#pragma unroll
        for (int n = 0; n < 4; ++n) {
            bf16x8 b = ld_swz(ST, 16 * n + (l & 15), ks * 4 + (l >> 4));
#pragma unroll
            for (int pc = 0; pc < 2; ++pc)
#pragma unroll
                for (int mt = 0; mt < 2; ++mt)
                    accP[pc][mt][n] = MFMA(aw[pc][mt], b, accP[pc][mt][n]);
        }
    }
    const int half = w >> 1;
#pragma unroll
    for (int hh = 0; hh < 2; ++hh) {
        __syncthreads();
        if (half == hh) {
#pragma unroll
            for (int pc = 0; pc < 2; ++pc)
#pragma unroll
                for (int mt = 0; mt < 2; ++mt) {
                    int h0 = 32 * w + 16 * mt + ((l >> 4) << 2);
                    int colp = 2 * h0 + 4 * pc - 128 * hh;
#pragma unroll
                    for (int n = 0; n < 4; ++n) {
                        f32x4 v = accP[pc][mt][n];
                        s16x4 s4;
                        s4[0] = f2bf(v[0]); s4[1] = f2bf(v[1]);
                        s4[2] = f2bf(v[2]); s4[3] = f2bf(v[3]);
                        hid_write(PJ, colp, 16 * n + (l & 15), s4);
                    }
                }
        }
        __syncthreads();
#pragma unroll
        for (int p2 = 0; p2 < 4; ++p2) {
            int row = p2 * 16 + (tid >> 4);
            int r = rb + row;
            if (r < R) {
                bf16x8 v = ld_swz(PJ, row, tid & 15);
                *(s16x8*)(proj + (size_t)r * 256 + hh * 128 + (tid & 15) * 8) =
                    __builtin_bit_cast(s16x8, v);
            }
        }
    }
}

// ---------------------------------------------------------------------------
// dec_proj: state0 = node_feat @ dec_W^T + dec_b ; proj0 = state0 @ projW^T.
// 64 rows/block.
// ---------------------------------------------------------------------------
__global__ __launch_bounds__(256, 2)
void dec_proj(const float* __restrict__ nf, int R,
              const short* __restrict__ decWb, const float* __restrict__ bias,
              const short* __restrict__ projW,
              short* __restrict__ sOut, short* __restrict__ proj)
{
    __shared__ char ST[16384];
    __shared__ char PJ[16384];
    const int tid = threadIdx.x, l = tid & 63, w = tid >> 6;
    const int rb = blockIdx.x * 64;

    const float* brow[4];
#pragma unroll
    for (int n = 0; n < 4; ++n) {
        int row = rb + 16 * n + (l & 15); if (row >= R) row = R - 1;
        brow[n] = nf + (size_t)row * 512;
    }

    f32x4 acc[2][4] = {};
    for (int kc = 0; kc < 512; kc += 128) {
#pragma unroll
        for (int ks = 0; ks < 4; ++ks) {
            int koff = kc + ks * 32 + (l >> 4) * 8;
            bf16x8 a0 = ldA(decWb, 512, 32 * w + (l & 15), koff);
            bf16x8 a1 = ldA(decWb, 512, 32 * w + 16 + (l & 15), koff);
#pragma unroll
            for (int n = 0; n < 4; ++n) {
                bf16x8 b = ld_f32_frag(brow[n] + koff);
                acc[0][n] = MFMA(a0, b, acc[0][n]);
                acc[1][n] = MFMA(a1, b, acc[1][n]);
            }
        }
    }
#pragma unroll
    for (int mt = 0; mt < 2; ++mt) {
        int c0 = 32 * w + 16 * mt + ((l >> 4) << 2);
        float4 bv = *(const float4*)&bias[c0];
#pragma unroll
        for (int n = 0; n < 4; ++n) {
            f32x4 v = acc[mt][n];
            s16x4 s4;
            s4[0] = f2bf(v[0] + bv.x); s4[1] = f2bf(v[1] + bv.y);
            s4[2] = f2bf(v[2] + bv.z); s4[3] = f2bf(v[3] + bv.w);
            hid_write(ST, c0, 16 * n + (l & 15), s4);
        }
    }
    __syncthreads();
#pragma unroll
    for (int p2 = 0; p2 < 4; ++p2) {
        int row = p2 * 16 + (tid >> 4);
        int r = rb + row;
        if (r < R) {
            bf16x8 v = ld_swz(ST, row, tid & 15);
            *(s16x8*)(sOut + (size_t)r * 128 + (tid & 15) * 8) =
                __builtin_bit_cast(s16x8, v);
        }
    }
    proj_gemm_store(ST, PJ, projW, proj, rb, R, tid);
}

// ---------------------------------------------------------------------------
// node_fused: gi/gh GEMMs + GRU gates (+ next-layer proj). 64 rows/block.
// launch_bounds(256,2): peak unified reg need ~190 — bound 3 (cap 168) forced
// scratch demotion of MFMA accumulators (R6: +276MB HBM write/dispatch).
// ---------------------------------------------------------------------------
template<int HAS_PROJ>
__global__ __launch_bounds__(256, 2)
void node_fused(const short* __restrict__ aggb, const short* __restrict__ sin_,
                const short* __restrict__ Wih, const short* __restrict__ Whh,
                const float* __restrict__ bih, const float* __restrict__ bhh,
                const short* __restrict__ projW,
                short* __restrict__ sOut, short* __restrict__ proj, int R)
{
    __shared__ char ST[16384];
    __shared__ char PJ[16384];
    const int tid = threadIdx.x, l = tid & 63, w = tid >> 6;
    const int rb = blockIdx.x * 64;

    const short* arow[4];
    const short* srow[4];
#pragma unroll
    for (int n = 0; n < 4; ++n) {
        int row = rb + 16 * n + (l & 15); if (row >= R) row = R - 1;
        arow[n] = aggb + (size_t)row * 128;
        srow[n] = sin_ + (size_t)row * 128;
    }
    // prefetch old-state values used by the gate epilogue (p==2)
    s16x4 svv[2][4];
#pragma unroll
    for (int mt = 0; mt < 2; ++mt) {
        int c0 = 32 * w + 16 * mt + ((l >> 4) << 2);
#pragma unroll
        for (int n = 0; n < 4; ++n)
            svv[mt][n] = *(const s16x4*)(srow[n] + c0);
    }

    unsigned int rpk[2][4][2], zpk[2][4][2];

    for (int p = 0; p < 3; ++p) {
        f32x4 gia[2][4] = {}, gha[2][4] = {};
#pragma unroll
        for (int ks = 0; ks < 4; ++ks) {
            int koff = ks * 32 + (l >> 4) * 8;
            bf16x8 ai0 = ldA(Wih, 128, p * 128 + 32 * w + (l & 15), koff);
            bf16x8 ai1 = ldA(Wih, 128, p * 128 + 32 * w + 16 + (l & 15), koff);
            bf16x8 ah0 = ldA(Whh, 128, p * 128 + 32 * w + (l & 15), koff);
            bf16x8 ah1 = ldA(Whh, 128, p * 128 + 32 * w + 16 + (l & 15), koff);
#pragma unroll
            for (int n = 0; n < 4; ++n) {
                bf16x8 ba = *(const bf16x8*)(arow[n] + koff);
                bf16x8 bs = *(const bf16x8*)(srow[n] + koff);
                gia[0][n] = MFMA(ai0, ba, gia[0][n]);
                gia[1][n] = MFMA(ai1, ba, gia[1][n]);
                gha[0][n] = MFMA(ah0, bs, gha[0][n]);
                gha[1][n] = MFMA(ah1, bs, gha[1][n]);
            }
        }
#pragma unroll
        for (int mt = 0; mt < 2; ++mt) {
            int c0 = 32 * w + 16 * mt + ((l >> 4) << 2);
            float4 bi = *(const float4*)&bih[p * 128 + c0];
            float4 bh = *(const float4*)&bhh[p * 128 + c0];
            float biv[4] = {bi.x, bi.y, bi.z, bi.w};
            float bhv[4] = {bh.x, bh.y, bh.z, bh.w};
#pragma unroll
            for (int n = 0; n < 4; ++n) {
                float gv[4], hv[4];
#pragma unroll
                for (int q = 0; q < 4; ++q) {
                    gv[q] = gia[mt][n][q] + biv[q];
                    hv[q] = gha[mt][n][q] + bhv[q];
                }
                if (p == 0) {
                    rpk[mt][n][0] = pk2(1.f / (1.f + expf(-(gv[0] + hv[0]))),
                                        1.f / (1.f + expf(-(gv[1] + hv[1]))));
                    rpk[mt][n][1] = pk2(1.f / (1.f + expf(-(gv[2] + hv[2]))),
                                        1.f / (1.f + expf(-(gv[3] + hv[3]))));
                } else if (p == 1) {
                    zpk[mt][n][0] = pk2(1.f / (1.f + expf(-(gv[0] + hv[0]))),
                                        1.f / (1.f + expf(-(gv[1] + hv[1]))));
                    zpk[mt][n][1] = pk2(1.f / (1.f + expf(-(gv[2] + hv[2]))),
                                        1.f / (1.f + expf(-(gv[3] + hv[3]))));
                } else {
                    s16x4 s4;
#pragma unroll
                    for (int q = 0; q < 4; ++q) {
                        unsigned int ru = rpk[mt][n][q >> 1], zu = zpk[mt][n][q >> 1];
                        float r = bf2f((unsigned short)((q & 1) ? (ru >> 16) : (ru & 0xffffu)));
                        float z = bf2f((unsigned short)((q & 1) ? (zu >> 16) : (zu & 0xffffu)));
                        float nn = tanhf(gv[q] + r * hv[q]);
                        float o = (1.f - z) * nn + z * bf2f((unsigned short)svv[mt][n][q]);
                        s4[q] = f2bf(HAS_PROJ ? fmaxf(o, 0.f) : o);
                    }
                    hid_write(ST, c0, 16 * n + (l & 15), s4);
                }
            }
        }
    }
    __syncthreads();
#pragma unroll
    for (int p2 = 0; p2 < 4; ++p2) {
        int row = p2 * 16 + (tid >> 4);
        int r = rb + row;
        if (r < R) {
            bf16x8 v = ld_swz(ST, row, tid & 15);
            *(s16x8*)(sOut + (size_t)r * 128 + (tid & 15) * 8) =
                __builtin_bit_cast(s16x8, v);
        }
    }
    if (HAS_PROJ)
        proj_gemm_store(ST, PJ, projW, proj, rb, R, tid);
}

// ---------------------------------------------------------------------------
// Fused edge MLPs, CSR order, 64 edges/block, proj gathers register-prefetched.
// ---------------------------------------------------------------------------
__global__ __launch_bounds__(256, 3)
void edge_fused2(const short* __restrict__ efc,
                 const int* __restrict__ srcs, const int* __restrict__ dsts,
                 const short* __restrict__ proj,    // N x 256 interleaved
                 const short* __restrict__ mW1b, const short* __restrict__ mW2,
                 const short* __restrict__ aW1b, const short* __restrict__ aW2,
                 const float* __restrict__ mb1, const float* __restrict__ mb2,
                 const float* __restrict__ ab1, const float* __restrict__ ab2,
                 short* __restrict__ msgatt, int M, int ntiles)
{
    __shared__ char HIDm[16384];
    __shared__ char HIDa[16384];
    const int tid = threadIdx.x, l = tid & 63, w = tid >> 6;
    int q = ntiles >> 3, r = ntiles & 7;
    int xcd = blockIdx.x & 7, o = blockIdx.x >> 3;
    int tile = (xcd < r ? xcd * (q + 1) : r * (q + 1) + (xcd - r) * q) + o;
    const int pb = tile * 64;

    const char* erow[4];
    s16x8 psv[2][4], pdv[2][4];
    {
#pragma unroll
        for (int n = 0; n < 4; ++n) {
            int pos = pb + 16 * n + (l & 15); if (pos >= M) pos = M - 1;
            int sv = srcs[pos], dv = dsts[pos];
            erow[n] = (const char*)(efc + (size_t)pos * 128);
            // issue gather loads early — consumed after GEMM1 (latency hidden)
#pragma unroll
            for (int mt = 0; mt < 2; ++mt) {
                int off = 2 * (32 * w + 16 * mt + ((l >> 4) << 2));
                psv[mt][n] = *(const s16x8*)(proj + (size_t)sv * 256 + off);
                pdv[mt][n] = *(const s16x8*)(proj + (size_t)dv * 256 + off);
            }
        }
    }

    // GEMM1 combined (msg+att share ef B-operand)
    f32x4 accm[2][4] = {}, acca[2][4] = {};
#pragma unroll
    for (int ks = 0; ks < 4; ++ks) {
        int koff = ks * 32 + (l >> 4) * 8;
        bf16x8 am0 = ldA(mW1b, 128, 32 * w + (l & 15), koff);
        bf16x8 am1 = ldA(mW1b, 128, 32 * w + 16 + (l & 15), koff);
        bf16x8 aa0 = ldA(aW1b, 128, 32 * w + (l & 15), koff);
        bf16x8 aa1 = ldA(aW1b, 128, 32 * w + 16 + (l & 15), koff);
#pragma unroll
        for (int n = 0; n < 4; ++n) {
            bf16x8 b = *(const bf16x8*)(erow[n] + koff * 2);
            accm[0][n] = MFMA(am0, b, accm[0][n]);
            accm[1][n] = MFMA(am1, b, accm[1][n]);
            acca[0][n] = MFMA(aa0, b, acca[0][n]);
            acca[1][n] = MFMA(aa1, b, acca[1][n]);
        }
    }
    // epilogue 1: bias + prefetched proj diff, relu -> HID
#pragma unroll
    for (int mt = 0; mt < 2; ++mt) {
        int h0 = 32 * w + 16 * mt + ((l >> 4) << 2);
        float4 bm = *(const float4*)&mb1[h0];
        float4 ba = *(const float4*)&ab1[h0];
        float bmv[4] = {bm.x, bm.y, bm.z, bm.w};
        float bav[4] = {ba.x, ba.y, ba.z, ba.w};
#pragma unroll
        for (int n = 0; n < 4; ++n) {
            s16x8 ps = psv[mt][n], pd = pdv[mt][n];
            f32x4 vm = accm[mt][n], va = acca[mt][n];
            s16x4 sm, sa;
#pragma unroll
            for (int qq = 0; qq < 4; ++qq) {
                float m_ = vm[qq] + bmv[qq] + bf2f((unsigned short)ps[qq])
                           - bf2f((unsigned short)pd[qq]);
                float a_ = va[qq] + bav[qq] + bf2f((unsigned short)ps[qq + 4])
                           - bf2f((unsigned short)pd[qq + 4]);
                sm[qq] = f2bf(fmaxf(m_, 0.f));
                sa[qq] = f2bf(fmaxf(a_, 0.f));
            }
            hid_write(HIDm, h0, 16 * n + (l & 15), sm);
            hid_write(HIDa, h0, 16 * n + (l & 15), sa);
        }
    }
    __syncthreads();

    // GEMM2 combined
    f32x4 acc2m[2][4] = {}, acc2a[2][4] = {};
#pragma unroll
    for (int ks = 0; ks < 4; ++ks) {
        int koff = ks * 32 + (l >> 4) * 8;
        bf16x8 wm0 = ldA(mW2, 128, 32 * w + (l & 15), koff);
        bf16x8 wm1 = ldA(mW2, 128, 32 * w + 16 + (l & 15), koff);
        bf16x8 wa0 = ldA(aW2, 128, 32 * w + (l & 15), koff);
        bf16x8 wa1 = ldA(aW2, 128, 32 * w + 16 + (l & 15), koff);
#pragma unroll
        for (int n = 0; n < 4; ++n) {
            bf16x8 bm = ld_swz(HIDm, 16 * n + (l & 15), ks * 4 + (l >> 4));
            bf16x8 ba = ld_swz(HIDa, 16 * n + (l & 15), ks * 4 + (l >> 4));
            acc2m[0][n] = MFMA(wm0, bm, acc2m[0][n]);
            acc2m[1][n] = MFMA(wm1, bm, acc2m[1][n]);
            acc2a[0][n] = MFMA(wa0, ba, acc2a[0][n]);
            acc2a[1][n] = MFMA(wa1, ba, acc2a[1][n]);
        }
    }
    __syncthreads();                // HID reads done; reuse HIDm for output
#pragma unroll
    for (int mt = 0; mt < 2; ++mt) {
        int c0 = 32 * w + 16 * mt + ((l >> 4) << 2);
        float4 bm2 = *(const float4*)&mb2[c0];
        float4 ba2 = *(const float4*)&ab2[c0];
#pragma unroll
        for (int n = 0; n < 4; ++n) {
            f32x4 m_ = acc2m[mt][n], a_ = acc2a[mt][n];
            float o0 = (m_[0] + bm2.x) / (1.f + expf(-(a_[0] + ba2.x)));
            float o1 = (m_[1] + bm2.y) / (1.f + expf(-(a_[1] + ba2.y)));
            float o2 = (m_[2] + bm2.z) / (1.f + expf(-(a_[2] + ba2.z)));
            float o3 = (m_[3] + bm2.w) / (1.f + expf(-(a_[3] + ba2.w)));
            s16x4 s4;
            s4[0] = f2bf(o0); s4[1] = f2bf(o1); s4[2] = f2bf(o2); s4[3] = f2bf(o3);
            hid_write(HIDm, c0, 16 * n + (l & 15), s4);
        }
    }
    __syncthreads();
#pragma unroll
    for (int p2 = 0; p2 < 4; ++p2) {
        int row = p2 * 16 + (tid >> 4);
        int pos = pb + row;
        if (pos < M) {
            bf16x8 v = ld_swz(HIDm, row, tid & 15);
            *(s16x8*)(msgatt + (size_t)pos * 128 + (tid & 15) * 8) =
                __builtin_bit_cast(s16x8, v);
        }
    }
}

// ---------------------------------------------------------------------------
// mlp_loss: 64 edges/block — d2 tile, theta & alpha 3-layer MLPs, loss reduce.
// ---------------------------------------------------------------------------
__global__ __launch_bounds__(256, 4)
void mlp_loss(const short* __restrict__ sP, const int* __restrict__ gidx,
              const float* __restrict__ label, const int* __restrict__ sg,
              const short* __restrict__ thW1, const short* __restrict__ thW2,
              const short* __restrict__ thW3,
              const float* __restrict__ thb1, const float* __restrict__ thb2,
              const float* __restrict__ thb3,
              const short* __restrict__ alW1, const short* __restrict__ alW2,
              const short* __restrict__ alW3,
              const float* __restrict__ alb1, const float* __restrict__ alb2,
              const float* __restrict__ alb3,
              float* __restrict__ radj, float* __restrict__ rla,
              float* __restrict__ cntS, int E, int S)
{
    __shared__ char D2T[16384];
    __shared__ char HID[16384];
    __shared__ float sadj[2][20];
    __shared__ float sla[2][20];
    __shared__ float scnt[2];
    __shared__ int sbase;
    const int tid = threadIdx.x, l = tid & 63, w = tid >> 6;
    const int eb = blockIdx.x * 64;

    if (tid == 0) sbase = sg[eb];
    if (tid < 40) { sadj[tid / 20][tid % 20] = 0.f; sla[tid / 20][tid % 20] = 0.f; }
    if (tid < 2) scnt[tid] = 0.f;

    // build d2 tile (64 rows x 16 units)
    for (int i = tid; i < 64 * 16; i += 256) {
        int row = i >> 4, u = i & 15;
        int e = eb + row; if (e >= E) e = E - 1;
        int2 ab = *(const int2*)&gidx[2 * (size_t)e];
        s16x8 x = *(const s16x8*)(sP + (size_t)ab.x * 128 + u * 8);
        s16x8 y = *(const s16x8*)(sP + (size_t)ab.y * 128 + u * 8);
        s16x8 d;
#pragma unroll
        for (int j = 0; j < 8; ++j)
            d[j] = f2bf(bf2f((unsigned short)x[j]) - bf2f((unsigned short)y[j]));
        *(s16x8*)(D2T + row * 256 + ((u ^ (row & 7)) << 4)) = d;
    }
    __syncthreads();

    for (int pass = 0; pass < 2; ++pass) {
        const short* W1 = pass ? alW1 : thW1;
        const short* W2 = pass ? alW2 : thW2;
        const short* W3 = pass ? alW3 : thW3;
        const float* b1 = pass ? alb1 : thb1;
        const float* b2 = pass ? alb2 : thb2;
        const float* b3 = pass ? alb3 : thb3;

        // stage 1
        f32x4 acc[2][4] = {};
#pragma unroll
        for (int ks = 0; ks < 4; ++ks) {
            int koff = ks * 32 + (l >> 4) * 8;
            bf16x8 a0 = ldA(W1, 128, 32 * w + (l & 15), koff);
            bf16x8 a1 = ldA(W1, 128, 32 * w + 16 + (l & 15), koff);
#pragma unroll
            for (int n = 0; n < 4; ++n) {
                bf16x8 b = ld_swz(D2T, 16 * n + (l & 15), ks * 4 + (l >> 4));
                acc[0][n] = MFMA(a0, b, acc[0][n]);
                acc[1][n] = MFMA(a1, b, acc[1][n]);
            }
        }
        __syncthreads();   // prior-pass HID readers done
#pragma unroll
        for (int mt = 0; mt < 2; ++mt) {
            int h0 = 32 * w + 16 * mt + ((l >> 4) << 2);
            float4 bv = *(const float4*)&b1[h0];
#pragma unroll
            for (int n = 0; n < 4; ++n) {
                f32x4 v = acc[mt][n];
                s16x4 s4;
                s4[0] = f2bf(fmaxf(v[0] + bv.x, 0.f));
                s4[1] = f2bf(fmaxf(v[1] + bv.y, 0.f));
                s4[2] = f2bf(fmaxf(v[2] + bv.z, 0.f));
                s4[3] = f2bf(fmaxf(v[3] + bv.w, 0.f));
                hid_write(HID, h0, 16 * n + (l & 15), s4);
            }
        }
        __syncthreads();
        // stage 2
        f32x4 acc2[2][4] = {};
#pragma unroll
        for (int ks = 0; ks < 4; ++ks) {
            int koff = ks * 32 + (l >> 4) * 8;
            bf16x8 a0 = ldA(W2, 128, 32 * w + (l & 15), koff);
            bf16x8 a1 = ldA(W2, 128, 32 * w + 16 + (l & 15), koff);
#pragma unroll
            for (int n = 0; n < 4; ++n) {
                bf16x8 b = ld_swz(HID, 16 * n + (l & 15), ks * 4 + (l >> 4));
                acc2[0][n] = MFMA(a0, b, acc2[0][n]);
                acc2[1][n] = MFMA(a1, b, acc2[1][n]);
            }
        }
        __syncthreads();
#pragma unroll
        for (int mt = 0; mt < 2; ++mt) {
            int h0 = 32 * w + 16 * mt + ((l >> 4) << 2);
            float4 bv = *(const float4*)&b2[h0];
#pragma unroll
            for (int n = 0; n < 4; ++n) {
                f32x4 v = acc2[mt][n];
                s16x4 s4;
                s4[0] = f2bf(fmaxf(v[0] + bv.x, 0.f));
                s4[1] = f2bf(fmaxf(v[1] + bv.y, 0.f));
                s4[2] = f2bf(fmaxf(v[2] + bv.z, 0.f));
                s4[3] = f2bf(fmaxf(v[3] + bv.w, 0.f));
                hid_write(HID, h0, 16 * n + (l & 15), s4);
            }
        }
        __syncthreads();
        // stage 3: each wave owns edge-fragment n = w
        f32x4 acc3[2] = {};
#pragma unroll
        for (int ks = 0; ks < 4; ++ks) {
            int koff = ks * 32 + (l >> 4) * 8;
            bf16x8 a0 = ldA(W3, 128, (l & 15), koff);
            bf16x8 a1 = ldA(W3, 128, 16 + (l & 15), koff);
            bf16x8 b = ld_swz(HID, 16 * w + (l & 15), ks * 4 + (l >> 4));
            acc3[0] = MFMA(a0, b, acc3[0]);
            acc3[1] = MFMA(a1, b, acc3[1]);
        }
        {
            int e = eb + 16 * w + (l & 15);
            if (e < E) {
                int ls = sg[e] - sbase;
                if (ls < 0) ls = 0; if (ls > 1) ls = 1;
                float y = (pass == 0) ? label[e] : 0.f;
#pragma unroll
                for (int mt = 0; mt < 2; ++mt) {
                    int c0 = 16 * mt + ((l >> 4) << 2);
                    if (c0 < 20) {
#pragma unroll
                        for (int qq = 0; qq < 4; ++qq) {
                            int k = c0 + qq;
                            if (k < 20) {
                                float t = acc3[mt][qq] + b3[k];
                                if (pass == 0) {
                                    float sp = fmaxf(-t, 0.f) + log1pf(expf(-fabsf(t)));
                                    atomicAdd(&sadj[ls][k], sp + (1.f - y) * t);
                                } else {
                                    atomicAdd(&sla[ls][k], t);
                                }
                            }
                        }
                    }
                }
            }
        }
        __syncthreads();
    }

    if (tid < 64) {
        int e = eb + tid;
        if (e < E) {
            int ls = sg[e] - sbase;
            if (ls >= 0 && ls < 2) atomicAdd(&scnt[ls], 1.f);
        }
    }
    __syncthreads();
    if (tid < 40) {
        int ls = tid / 20, k = tid % 20;
        int s = sbase + ls;
        if (s < S) {
            float v = sadj[ls][k], v2 = sla[ls][k];
            if (v  != 0.f) atomicAdd(&radj[s * 20 + k], v);
            if (v2 != 0.f) atomicAdd(&rla[s * 20 + k], v2);
        }
    }
    if (tid < 2) {
        int s = sbase + tid;
        if (s < S && scnt[tid] != 0.f) atomicAdd(&cntS[s], scnt[tid]);
    }
}

// ---------------------------------------------------------------------------
// CSR build + gathers + aggregation
// ---------------------------------------------------------------------------
__global__ void csr_count(const int* __restrict__ edge, int* __restrict__ cnt, int M) {
    int e = blockIdx.x * 256 + threadIdx.x;
    if (e < M) atomicAdd(&cnt[edge[2 * (size_t)e + 1]], 1);
}

__global__ void csr_scan(const int* __restrict__ cnt, int* __restrict__ rowptr,
                         int* __restrict__ wofs, int N)
{
    __shared__ int part[1024];
    int t = threadIdx.x;
    int chunk = (N + 1023) / 1024;
    int b0 = t * chunk, b1 = b0 + chunk; if (b1 > N) b1 = N; if (b0 > N) b0 = N;
    int s = 0;
    for (int i = b0; i < b1; ++i) s += cnt[i];
    part[t] = s;
    __syncthreads();
    for (int off = 1; off < 1024; off <<= 1) {
        int v = (t >= off) ? part[t - off] : 0;
        __syncthreads();
        part[t] += v;
        __syncthreads();
    }
    int run = (t ? part[t - 1] : 0);
    for (int i = b0; i < b1; ++i) { rowptr[i] = run; wofs[i] = run; run += cnt[i]; }
    if (t == 1023) rowptr[N] = run;
}

__global__ void csr_scatter2(const int* __restrict__ edge, int* __restrict__ wofs,
                             int* __restrict__ eidx, int* __restrict__ srcs,
                             int* __restrict__ dsts, int M)
{
    int e = blockIdx.x * 256 + threadIdx.x;
    if (e < M) {
        int2 sd = *(const int2*)&edge[2 * (size_t)e];
        int p = atomicAdd(&wofs[sd.y], 1);
        eidx[p] = e; srcs[p] = sd.x; dsts[p] = sd.y;
    }
}

__global__ void ef_gather(const float* __restrict__ ef, const int* __restrict__ eidx,
                          short* __restrict__ efc, int M)
{
    long i = (long)blockIdx.x * 256 + threadIdx.x;
    if (i >= (long)M * 16) return;
    int p = (int)(i >> 4), u = (int)(i & 15);
    int e = eidx[p];
    const float* sp = ef + (size_t)e * 128 + u * 8;
    float4 a = *(const float4*)sp, b = *(const float4*)(sp + 4);
    s16x8 s;
    s[0] = f2bf(a.x); s[1] = f2bf(a.y); s[2] = f2bf(a.z); s[3] = f2bf(a.w);
    s[4] = f2bf(b.x); s[5] = f2bf(b.y); s[6] = f2bf(b.z); s[7] = f2bf(b.w);
    *(s16x8*)(efc + (size_t)p * 128 + u * 8) = s;
}

// Sequential CSR aggregation: 4 nodes/wave, 16 lanes per node, 16B lane loads.
__global__ __launch_bounds__(256)
void agg_gather3(const short* __restrict__ msgatt, const int* __restrict__ rowptr,
                 short* __restrict__ aggb, int N)
{
    int wid = blockIdx.x * 4 + (threadIdx.x >> 6);
    int l = threadIdx.x & 63;
    int v = wid * 4 + (l >> 4);
    int u = l & 15;
    if (v >= N) return;
    int b = rowptr[v], e = rowptr[v + 1];
    float acc[8] = {};
    for (int i = b; i < e; ++i) {
        s16x8 x = *(const s16x8*)(msgatt + (size_t)i * 128 + u * 8);
#pragma unroll
        for (int j = 0; j < 8; ++j) acc[j] += bf2f((unsigned short)x[j]);
    }
    s16x8 o;
#pragma unroll
    for (int j = 0; j < 8; ++j) o[j] = f2bf(acc[j]);
    *(s16x8*)(aggb + (size_t)v * 128 + u * 8) = o;
}

// ---------------------------------------------------------------------------
__global__ void final_kernel(const float* __restrict__ radj, const float* __restrict__ rla,
                             const float* __restrict__ cnt, const int* __restrict__ bc_idx,
                             float* __restrict__ out)
{
    __shared__ float bcl[16], bcc[16];
    const int s = threadIdx.x;
    if (s < 16) { bcl[s] = 0.f; bcc[s] = 0.f; }
    __syncthreads();
    float c = cnt[s];
    float x[20];
    float mx = -1e30f;
#pragma unroll
    for (int k = 0; k < 20; ++k) { x[k] = rla[s * 20 + k] / c; mx = fmaxf(mx, x[k]); }
    float se = 0.f;
#pragma unroll
    for (int k = 0; k < 20; ++k) se += expf(x[k] - mx);
    float lse = mx + logf(se);
    float t[20];
    float m2 = -1e30f;
#pragma unroll
    for (int k = 0; k < 20; ++k) { t[k] = -radj[s * 20 + k] + x[k] - lse; m2 = fmaxf(m2, t[k]); }
    float s2 = 0.f;
#pragma unroll
    for (int k = 0; k < 20; ++k) s2 += expf(t[k] - m2);
    float lp = m2 + logf(s2);
    atomicAdd(&bcl[bc_idx[s]], lp);
    atomicAdd(&bcc[bc_idx[s]], c);
    __syncthreads();
    if (s == 0) {
        float a = 0.f;
        for (int b = 0; b < 16; ++b) a += bcl[b] / bcc[b];
        out[0] = -a / 16.f;
    }
}

// ---------------------------------------------------------------------------
extern "C" void kernel_launch(void* const* d_in, const int* in_sizes, int n_in,
                              void* d_out, int out_size, void* d_ws, size_t ws_size,
                              hipStream_t stream)
{
    const float* node_feat = (const float*)d_in[0];
    const int*   edge      = (const int*)  d_in[1];
    const float* edge_feat = (const float*)d_in[2];
    const int*   gnn_idx   = (const int*)  d_in[3];
    const float* label     = (const float*)d_in[4];
    const int*   sg_idx    = (const int*)  d_in[5];
    const int*   bc_idx    = (const int*)  d_in[6];
    const float* dec_W  = (const float*)d_in[7];
    const float* dec_b  = (const float*)d_in[8];
    const float* msg_W1 = (const float*)d_in[9];
    const float* msg_b1 = (const float*)d_in[10];
    const float* msg_W2 = (const float*)d_in[11];
    const float* msg_b2 = (const float*)d_in[12];
    const float* att_W1 = (const float*)d_in[13];
    const float* att_b1 = (const float*)d_in[14];
    const float* att_W2 = (const float*)d_in[15];
    const float* att_b2 = (const float*)d_in[16];
    const float* gru_Wih = (const float*)d_in[17];
    const float* gru_bih = (const float*)d_in[18];
    const float* gru_Whh = (const float*)d_in[19];
    const float* gru_bhh = (const float*)d_in[20];
    const float* th_W1 = (const float*)d_in[21];
    const float* th_b1 = (const float*)d_in[22];
    const float* th_W2 = (const float*)d_in[23];
    const float* th_b2 = (const float*)d_in[24];
    const float* th_W3 = (const float*)d_in[25];
    const float* th_b3 = (const float*)d_in[26];
    const float* al_W1 = (const float*)d_in[27];
    const float* al_b1 = (const float*)d_in[28];
    const float* al_W2 = (const float*)d_in[29];
    const float* al_b2 = (const float*)d_in[30];
    const float* al_W3 = (const float*)d_in[31];
    const float* al_b3 = (const float*)d_in[32];

    const int N = in_sizes[0] / 512;
    const int M = in_sizes[1] / 2;
    const int E = in_sizes[3] / 2;
    const int S = in_sizes[6];

    size_t off = 0;
    auto alloc = [&](size_t bytes) {
        char* p = (char*)d_ws + off;
        off += (bytes + 255) & ~(size_t)255;
        return p;
    };
    // bf16 weight slabs
    short* decWb  = (short*)alloc((size_t)128 * 512 * 2);
    short* projWb = (short*)alloc((size_t)3 * 256 * 128 * 2);
    short* mW1bB  = (short*)alloc((size_t)3 * 128 * 128 * 2);
    short* aW1bB  = (short*)alloc((size_t)3 * 128 * 128 * 2);
    short* mW2B   = (short*)alloc((size_t)3 * 128 * 128 * 2);
    short* aW2B   = (short*)alloc((size_t)3 * 128 * 128 * 2);
    short* gihB   = (short*)alloc((size_t)3 * 384 * 128 * 2);
    short* ghhB   = (short*)alloc((size_t)3 * 384 * 128 * 2);
    short* thW1B  = (short*)alloc((size_t)128 * 128 * 2);
    short* thW2B  = (short*)alloc((size_t)128 * 128 * 2);
    short* thW3B  = (short*)alloc((size_t)32 * 128 * 2);
    short* alW1B  = (short*)alloc((size_t)128 * 128 * 2);
    short* alW2B  = (short*)alloc((size_t)128 * 128 * 2);
    short* alW3B  = (short*)alloc((size_t)32 * 128 * 2);
    // activations
    short* sA     = (short*)alloc((size_t)N * 128 * 2);
    short* sB     = (short*)alloc((size_t)N * 128 * 2);
    short* sP     = (short*)alloc((size_t)N * 128 * 2);
    short* efc    = (short*)alloc((size_t)M * 128 * 2);
    short* msgatt = (short*)alloc((size_t)M * 128 * 2);
    short* proj   = (short*)alloc((size_t)N * 256 * 2);
    short* aggb   = (short*)alloc((size_t)N * 128 * 2);
    int*   cntN   = (int*)  alloc((size_t)N * 4);
    int*   wofs   = (int*)  alloc((size_t)N * 4);
    int*   rowptr = (int*)  alloc((size_t)(N + 1) * 4);
    int*   eidx   = (int*)  alloc((size_t)M * 4);
    int*   srcs   = (int*)  alloc((size_t)M * 4);
    int*   dsts   = (int*)  alloc((size_t)M * 4);
    float* radj   = (float*)alloc((size_t)S * 20 * 4);
    float* rla    = (float*)alloc((size_t)S * 20 * 4);
    float* cntS   = (float*)alloc((size_t)S * 4);

    // ---- prepack descriptor table ----
    PrepackArgs pa;
    int ei = 0;
    auto add = [&](const float* s, short* d, int stride, int rows, int rowsTot, int cols) {
        pa.src[ei] = s; pa.dst[ei] = d; pa.stride[ei] = stride;
        pa.rows[ei] = rows; pa.rowsTot[ei] = rowsTot; pa.cols[ei] = cols; ++ei;
    };
    add(dec_W, decWb, 512, 128, 128, 512);
    for (int l = 0; l < 3; ++l) {
        add(msg_W1 + (size_t)l * 128 * 256,       projWb + (size_t)l * 256 * 128,          256, 128, 128, 128);
        add(att_W1 + (size_t)l * 128 * 256,       projWb + (size_t)l * 256 * 128 + 16384,  256, 128, 128, 128);
        add(msg_W1 + (size_t)l * 128 * 256 + 128, mW1bB + (size_t)l * 16384,               256, 128, 128, 128);
        add(att_W1 + (size_t)l * 128 * 256 + 128, aW1bB + (size_t)l * 16384,               256, 128, 128, 128);
        add(msg_W2 + (size_t)l * 16384,           mW2B + (size_t)l * 16384,                128, 128, 128, 128);
        add(att_W2 + (size_t)l * 16384,           aW2B + (size_t)l * 16384,                128, 128, 128, 128);
        add(gru_Wih + (size_t)l * 49152,          gihB + (size_t)l * 49152,                128, 384, 384, 128);
        add(gru_Whh + (size_t)l * 49152,          ghhB + (size_t)l * 49152,                128, 384, 384, 128);
    }
    add(th_W1, thW1B, 128, 128, 128, 128);
    add(th_W2, thW2B, 128, 128, 128, 128);
    add(th_W3, thW3B, 128, 20, 32, 128);
    add(al_W1, alW1B, 128, 128, 128, 128);
    add(al_W2, alW2B, 128, 128, 128, 128);
    add(al_W3, alW3B, 128, 20, 32, 128);

    const dim3 blk(256);
    const int gN64 = (N + 63) / 64;
    const int gE64 = (E + 63) / 64;
    const int gMt  = (M + 255) / 256;
    const int ntilesM = (M + 63) / 64;
    const int gAgg = (N + 15) / 16;

    hipMemsetAsync(radj, 0, (size_t)(S * 20 * 2 + S) * 4, stream);
    hipMemsetAsync(cntN, 0, (size_t)N * 4, stream);

    prepack<<<dim3(384, NPACK), dim3(64), 0, stream>>>(pa);

    csr_count   <<<gMt, blk, 0, stream>>>(edge, cntN, M);
    csr_scan    <<<1, 1024, 0, stream>>>(cntN, rowptr, wofs, N);
    csr_scatter2<<<gMt, blk, 0, stream>>>(edge, wofs, eidx, srcs, dsts, M);
    ef_gather   <<<(int)(((long)M * 16 + 255) / 256), blk, 0, stream>>>(edge_feat, eidx, efc, M);

    // decoder + proj0
    dec_proj<<<gN64, blk, 0, stream>>>(node_feat, N, decWb, dec_b, projWb, sA, proj);

    short* bufs[2] = { sA, sB };
    for (int l = 0; l < 3; ++l) {
        short* sin  = bufs[l & 1];
        short* sout = (l == 2) ? sP : bufs[(l + 1) & 1];
        edge_fused2<<<ntilesM, blk, 0, stream>>>(efc, srcs, dsts, proj,
            mW1bB + (size_t)l * 16384, mW2B + (size_t)l * 16384,
            aW1bB + (size_t)l * 16384, aW2B + (size_t)l * 16384,
            msg_b1 + l * 128, msg_b2 + l * 128,
            att_b1 + l * 128, att_b2 + l * 128,
            msgatt, M, ntilesM);
        agg_gather3<<<gAgg, blk, 0, stream>>>(msgatt, rowptr, aggb, N);
        if (l < 2) {
            node_fused<1><<<gN64, blk, 0, stream>>>(aggb, sin,
                gihB + (size_t)l * 49152, ghhB + (size_t)l * 49152,
                gru_bih + l * 384, gru_bhh + l * 384,
                projWb + (size_t)(l + 1) * 256 * 128, sout, proj, N);
        } else {
            node_fused<0><<<gN64, blk, 0, stream>>>(aggb, sin,
                gihB + (size_t)l * 49152, ghhB + (size_t)l * 49152,
                gru_bih + l * 384, gru_bhh + l * 384,
                nullptr, sout, nullptr, N);
        }
    }

    mlp_loss<<<gE64, blk, 0, stream>>>(sP, gnn_idx, label, sg_idx,
        thW1B, thW2B, thW3B, th_b1, th_b2, th_b3,
        alW1B, alW2B, alW3B, al_b1, al_b2, al_b3,
        radj, rla, cntS, E, S);
    final_kernel<<<1, S, 0, stream>>>(radj, rla, cntS, bc_idx, (float*)d_out);
}